// Round 1
// baseline (1366.219 us; speedup 1.0000x reference)
//
#include <hip/hip_runtime.h>
#include <cstdint>
#include <cstddef>

// MPNN: 4 edge-conv layers + head MLP.  N=50000, E=800000, F=64.
// Round 4: occupancy push. edge_conv was LDS-bound at 2 blocks/CU (58 KB):
//  - hbuf shrunk [4][16][72] -> [4][16][40] via two 32-col transpose passes
//    (stride 80B keeps ds_read_b128 16B-aligned, uniform 8 lanes/bank).
//  - w1s capped at 8 ksteps (32 KB); conv3/4 ksteps 8..11 read B-frags from
//    global w1f (L2-resident, coalesced, shared by all blocks).
//  - __launch_bounds__(256,4) + GRID_EC 1024 -> 4 blocks/CU (16 waves/CU).

#define NN 50000
#define NE 800000
#define GRID_EC 1024

typedef _Float16 f16;
typedef _Float16 f16x8 __attribute__((ext_vector_type(8)));
typedef _Float16 f16x4 __attribute__((ext_vector_type(4)));
typedef float    f32x4 __attribute__((ext_vector_type(4)));

// ---------------------------------------------------------------- sort build
__global__ void count_kernel(const int* __restrict__ eidx, int* __restrict__ cnt) {
  int i = blockIdx.x * 256 + threadIdx.x;
  if (i < NE) atomicAdd(&cnt[eidx[i]], 1);
}

__global__ void scan_a(const int* __restrict__ cnt, int* __restrict__ bsum) {
  __shared__ int sh[256];
  int i = blockIdx.x * 256 + threadIdx.x;
  sh[threadIdx.x] = (i < NN) ? cnt[i] : 0;
  __syncthreads();
  for (int off = 128; off > 0; off >>= 1) {
    if (threadIdx.x < off) sh[threadIdx.x] += sh[threadIdx.x + off];
    __syncthreads();
  }
  if (threadIdx.x == 0) bsum[blockIdx.x] = sh[0];
}

__global__ void scan_b(const int* __restrict__ bsum, int* __restrict__ boff, int nb) {
  __shared__ int sh[256];
  int t = threadIdx.x;
  int v = (t < nb) ? bsum[t] : 0;
  sh[t] = v; __syncthreads();
  for (int off = 1; off < 256; off <<= 1) {
    int x = (t >= off) ? sh[t - off] : 0;
    __syncthreads();
    sh[t] += x;
    __syncthreads();
  }
  if (t < nb) boff[t] = sh[t] - v;   // exclusive
}

__global__ void scan_c(const int* __restrict__ cnt, const int* __restrict__ boff,
                       int* __restrict__ start, int* __restrict__ cursor) {
  __shared__ int sh[256];
  int t = threadIdx.x;
  int i = blockIdx.x * 256 + t;
  int v = (i < NN) ? cnt[i] : 0;
  sh[t] = v; __syncthreads();
  for (int off = 1; off < 256; off <<= 1) {
    int x = (t >= off) ? sh[t - off] : 0;
    __syncthreads();
    sh[t] += x;
    __syncthreads();
  }
  if (i < NN) {
    int ex = boff[blockIdx.x] + sh[t] - v;
    start[i] = ex; cursor[i] = ex;
  }
  if (i == 0) start[NN] = NE;
}

__global__ void scatter_kernel(const int* __restrict__ eidx, const float* __restrict__ ea,
                               int* __restrict__ cursor,
                               int* __restrict__ srow, int* __restrict__ scol,
                               int* __restrict__ perm, f16* __restrict__ ea4) {
  int e = blockIdx.x * 256 + threadIdx.x;
  if (e >= NE) return;
  int r = eidx[e];
  int j = atomicAdd(&cursor[r], 1);
  srow[j] = r;
  scol[j] = eidx[NE + e];
  perm[j] = e;
  f16x4 v;
  v[0] = (f16)ea[3 * (size_t)e];
  v[1] = (f16)ea[3 * (size_t)e + 1];
  v[2] = (f16)ea[3 * (size_t)e + 2];
  v[3] = (f16)0.0f;
  *(f16x4*)&ea4[4 * (size_t)j] = v;
}

// ---------------------------------------------------------------- weight prep
// frag slot (ks,t,lane): dst[slot*8+j] = W[(ks*32+(lane>>4)*8+j)*64 + (t*16+(lane&15))]
__global__ void prep_kernel(const float* __restrict__ W1, int kreal1, int ksteps1,
                            const float* __restrict__ W2,
                            f16* __restrict__ w1f, f16* __restrict__ w2f) {
  int u = blockIdx.x * 256 + threadIdx.x;
  int total1 = ksteps1 * 256;
  const float* W; f16* dst; int kreal, slot;
  if (u < total1)            { W = W1; dst = w1f; kreal = kreal1; slot = u; }
  else if (u < total1 + 512) { W = W2; dst = w2f; kreal = 64;     slot = u - total1; }
  else return;
  int l = slot & 63, t = (slot >> 6) & 3, ks = slot >> 8;
  int n  = t * 16 + (l & 15);
  int kb = ks * 32 + ((l >> 4) * 8);
  f16x8 v;
#pragma unroll
  for (int j = 0; j < 8; ++j) {
    int k = kb + j;
    v[j] = (f16)((k < kreal) ? W[k * 64 + n] : 0.0f);
  }
  *(f16x8*)&dst[slot * 8] = v;
}

// ---------------------------------------------------------------- node segment sum
// one wave per node: sum raw f16 edge rows over [start[v], start[v+1]) -> relu(mean)
template<int F32OUT>
__global__ void node_sum_kernel(const f16* __restrict__ eout, const int* __restrict__ start,
                                void* __restrict__ xout) {
  int v = blockIdx.x * 4 + (threadIdx.x >> 6);
  int lane = threadIdx.x & 63;
  int g = lane >> 4, c4 = (lane & 15) * 4;
  int s0 = start[v], s1 = start[v + 1];
  f32x4 acc = (f32x4){0.f, 0.f, 0.f, 0.f};
  for (int i = s0 + g; i < s1; i += 4) {
    f16x4 h = *(const f16x4*)&eout[(size_t)i * 64 + c4];
#pragma unroll
    for (int q = 0; q < 4; ++q) acc[q] += (float)h[q];
  }
#pragma unroll
  for (int q = 0; q < 4; ++q) {
    acc[q] += __shfl_xor(acc[q], 16, 64);
    acc[q] += __shfl_xor(acc[q], 32, 64);
  }
  int cv = s1 - s0;
  float inv = 1.0f / (float)(cv > 0 ? cv : 1);
  if (g == 0) {
    if (F32OUT) {
      f32x4 o;
#pragma unroll
      for (int q = 0; q < 4; ++q) o[q] = fmaxf(acc[q] * inv, 0.0f);
      *(f32x4*)&((float*)xout)[(size_t)v * 64 + c4] = o;
    } else {
      f16x4 o;
#pragma unroll
      for (int q = 0; q < 4; ++q) o[q] = (f16)fmaxf(acc[q] * inv, 0.0f);
      *(f16x4*)&((f16*)xout)[(size_t)v * 64 + c4] = o;
    }
  }
}

// ---------------------------------------------------------------- edge conv
// Processes edges in SORTED order j. Writes eout[j] = RAW f16 edge output
// (relu applied by consumers). CONV==4 additionally scatters relu fp32 to
// out_e[perm[j]].
template<int CONV>
__global__ __launch_bounds__(256, 4) void edge_conv_kernel(
    const int* __restrict__ srow, const int* __restrict__ scol,
    const int* __restrict__ perm,
    const float* __restrict__ na,
    const f16* __restrict__ xA, const f16* __restrict__ xB,
    const f16* __restrict__ eA, const f16* __restrict__ eB,
    const f16* __restrict__ ea4,
    const f16* __restrict__ w1f, const f16* __restrict__ w2f,
    const float* __restrict__ b1, const float* __restrict__ b2,
    f16* __restrict__ eout, float* __restrict__ out_e)
{
  constexpr int KSTEPS = (CONV == 1) ? 1 : (CONV == 2 ? 7 : 12);
  constexpr int LDS_KS = (KSTEPS > 8) ? 8 : KSTEPS;   // B-frags staged in LDS

  __shared__ f16 w1s[LDS_KS * 2048];                  // 4KB per ks (<= 32KB)
  __shared__ __align__(16) f16 hbuf[4][16][40];       // per-wave 32-col xpose buf

  const int tid  = threadIdx.x;
  const int lane = tid & 63;
  const int wv   = tid >> 6;
  const int quad = lane >> 4;
  const int l15  = lane & 15;

  for (int u = tid; u < LDS_KS * 256; u += 256)
    *(f16x8*)&w1s[u * 8] = *(const f16x8*)&w1f[u * 8];

  float bb1[4], bb2[4];
#pragma unroll
  for (int t = 0; t < 4; ++t) { bb1[t] = b1[t * 16 + l15]; bb2[t] = b2[t * 16 + l15]; }

  f16x8 w2r[2][4];
#pragma unroll
  for (int kk = 0; kk < 2; ++kk)
#pragma unroll
    for (int t = 0; t < 4; ++t)
      w2r[kk][t] = *(const f16x8*)&w2f[((kk * 4 + t) * 64 + lane) * 8];

  __syncthreads();   // w1s visible; no further barriers

  // B-frag: LDS for ks < LDS_KS, global (L2-resident w1f) beyond.
  auto bfrag = [&](int ks, int t) -> f16x8 {
    if (ks < LDS_KS) return *(const f16x8*)&w1s[((ks * 4 + t) * 64 + lane) * 8];
    return *(const f16x8*)&w1f[((ks * 4 + t) * 64 + lane) * 8];
  };

  constexpr int NTILE = NE / 32;          // wave-tiles of 32 edges
  const int gw = blockIdx.x * 4 + wv;

  for (int jt = gw; jt < NTILE; jt += GRID_EC * 4) {
    const int jb = jt * 32;
    const int j0 = jb + l15, j1 = j0 + 16;

    f32x4 acc[2][4];
#pragma unroll
    for (int s = 0; s < 2; ++s)
#pragma unroll
      for (int t = 0; t < 4; ++t) acc[s][t] = (f32x4){0.f, 0.f, 0.f, 0.f};

    if constexpr (CONV == 1) {
      const int r0 = srow[j0], r1 = srow[j1];
      const int c0 = scol[j0], c1 = scol[j1];
      f16x8 a0, a1;
#pragma unroll
      for (int j = 0; j < 8; ++j) { a0[j] = (f16)0.0f; a1[j] = (f16)0.0f; }
      f16x4 q0 = *(const f16x4*)&ea4[4 * (size_t)j0];
      f16x4 q1 = *(const f16x4*)&ea4[4 * (size_t)j1];
      if (quad == 0) {
        a0[0] = (f16)na[r0*3];  a0[1] = (f16)na[r0*3+1];  a0[2] = (f16)na[r0*3+2];
        a0[3] = (f16)na[c0*3];  a0[4] = (f16)na[c0*3+1];  a0[5] = (f16)na[c0*3+2];
        a0[6] = q0[0];          a0[7] = q0[1];
        a1[0] = (f16)na[r1*3];  a1[1] = (f16)na[r1*3+1];  a1[2] = (f16)na[r1*3+2];
        a1[3] = (f16)na[c1*3];  a1[4] = (f16)na[c1*3+1];  a1[5] = (f16)na[c1*3+2];
        a1[6] = q1[0];          a1[7] = q1[1];
      } else if (quad == 1) {
        a0[0] = q0[2];
        a1[0] = q1[2];
      }
#pragma unroll
      for (int t = 0; t < 4; ++t) {
        f16x8 b = bfrag(0, t);
        acc[0][t] = __builtin_amdgcn_mfma_f32_16x16x32_f16(a0, b, acc[0][t], 0, 0, 0);
        acc[1][t] = __builtin_amdgcn_mfma_f32_16x16x32_f16(a1, b, acc[1][t], 0, 0, 0);
      }
    } else {
      constexpr int NREG = (CONV == 2) ? 3 : 6;
      constexpr int ERCH = (CONV == 2) ? 2 : 4;   // chunks >= ERCH are e-prev (relu)
      const int r0 = srow[j0], r1 = srow[j1];
      const int c0 = scol[j0], c1 = scol[j1];
      const f16* p0[NREG]; const f16* p1[NREG];
      if constexpr (CONV == 2) {
        p0[0] = xA + (size_t)r0 * 64;  p1[0] = xA + (size_t)r1 * 64;
        p0[1] = xA + (size_t)c0 * 64;  p1[1] = xA + (size_t)c1 * 64;
        p0[2] = eA + (size_t)j0 * 64;  p1[2] = eA + (size_t)j1 * 64;
      } else {
        p0[0] = xA + (size_t)r0 * 64;  p1[0] = xA + (size_t)r1 * 64;
        p0[1] = xB + (size_t)r0 * 64;  p1[1] = xB + (size_t)r1 * 64;
        p0[2] = xA + (size_t)c0 * 64;  p1[2] = xA + (size_t)c1 * 64;
        p0[3] = xB + (size_t)c0 * 64;  p1[3] = xB + (size_t)c1 * 64;
        p0[4] = eA + (size_t)j0 * 64;  p1[4] = eA + (size_t)j1 * 64;
        p0[5] = eB + (size_t)j0 * 64;  p1[5] = eB + (size_t)j1 * 64;
      }
#pragma unroll
      for (int ks = 0; ks < NREG * 2; ++ks) {
        const int c = ks >> 1, kk = ks & 1;
        f16x8 a0 = *(const f16x8*)(p0[c] + kk * 32 + quad * 8);
        f16x8 a1 = *(const f16x8*)(p1[c] + kk * 32 + quad * 8);
        if (c >= ERCH) {            // e-prev stored raw -> relu on load
#pragma unroll
          for (int j = 0; j < 8; ++j) {
            a0[j] = (a0[j] > (f16)0.0f) ? a0[j] : (f16)0.0f;
            a1[j] = (a1[j] > (f16)0.0f) ? a1[j] : (f16)0.0f;
          }
        }
#pragma unroll
        for (int t = 0; t < 4; ++t) {
          f16x8 b = bfrag(ks, t);
          acc[0][t] = __builtin_amdgcn_mfma_f32_16x16x32_f16(a0, b, acc[0][t], 0, 0, 0);
          acc[1][t] = __builtin_amdgcn_mfma_f32_16x16x32_f16(a1, b, acc[1][t], 0, 0, 0);
        }
      }
      if constexpr (CONV == 2) {    // tail ks 6: ea at cols 192..194
        f16x8 a0, a1;
#pragma unroll
        for (int j = 0; j < 8; ++j) { a0[j] = (f16)0.0f; a1[j] = (f16)0.0f; }
        f16x4 q0 = *(const f16x4*)&ea4[4 * (size_t)j0];
        f16x4 q1 = *(const f16x4*)&ea4[4 * (size_t)j1];
        if (quad == 0) {
          a0[0] = q0[0]; a0[1] = q0[1]; a0[2] = q0[2];
          a1[0] = q1[0]; a1[1] = q1[1]; a1[2] = q1[2];
        }
#pragma unroll
        for (int t = 0; t < 4; ++t) {
          f16x8 b = bfrag(6, t);
          acc[0][t] = __builtin_amdgcn_mfma_f32_16x16x32_f16(a0, b, acc[0][t], 0, 0, 0);
          acc[1][t] = __builtin_amdgcn_mfma_f32_16x16x32_f16(a1, b, acc[1][t], 0, 0, 0);
        }
      }
    }

    // ---- per sub-tile: GEMM2 + stores (wave-private hbuf, in-order DS).
    // hbuf holds 32 cols at a time: two {write half, read A-frag} passes.
#pragma unroll
    for (int s = 0; s < 2; ++s) {
      f32x4 a2[4];
#pragma unroll
      for (int t = 0; t < 4; ++t) a2[t] = (f32x4){0.f, 0.f, 0.f, 0.f};
#pragma unroll
      for (int kk = 0; kk < 2; ++kk) {
#pragma unroll
        for (int th = 0; th < 2; ++th) {
          const int t = kk * 2 + th;
#pragma unroll
          for (int r = 0; r < 4; ++r)
            hbuf[wv][quad * 4 + r][th * 16 + l15] = (f16)fmaxf(acc[s][t][r] + bb1[t], 0.0f);
        }
        f16x8 ah = *(const f16x8*)&hbuf[wv][l15][quad * 8];
#pragma unroll
        for (int t = 0; t < 4; ++t)
          a2[t] = __builtin_amdgcn_mfma_f32_16x16x32_f16(ah, w2r[kk][t], a2[t], 0, 0, 0);
      }

      // raw edge-out f16: two 32-col transpose passes -> coalesced row stores
      const int j = jb + s * 16 + l15;
      f16x8 oh[2];
#pragma unroll
      for (int h = 0; h < 2; ++h) {
#pragma unroll
        for (int th = 0; th < 2; ++th) {
          const int t = h * 2 + th;
#pragma unroll
          for (int r = 0; r < 4; ++r)
            hbuf[wv][quad * 4 + r][th * 16 + l15] = (f16)(a2[t][r] + bb2[t]);
        }
        oh[h] = *(const f16x8*)&hbuf[wv][l15][quad * 8];
      }
      *(f16x8*)&eout[(size_t)j * 64 + quad * 8] = oh[0];
      *(f16x8*)&eout[(size_t)j * 64 + 32 + quad * 8] = oh[1];

      if constexpr (CONV == 4) {
        // full-precision relu output, scattered to original edge order
#pragma unroll
        for (int r = 0; r < 4; ++r) {
          const int p = perm[jb + s * 16 + quad * 4 + r];
#pragma unroll
          for (int t = 0; t < 4; ++t)
            out_e[(size_t)p * 64 + t * 16 + l15] = fmaxf(a2[t][r] + bb2[t], 0.0f);
        }
      }
    }
  }
}

// ---------------------------------------------------------------- head MLP
__global__ void head_kernel(const float* __restrict__ x4,
                            const float* __restrict__ W1, const float* __restrict__ b1,
                            const float* __restrict__ W2, const float* __restrict__ b2,
                            float* __restrict__ out) {
  __shared__ float xs[4][64];
  __shared__ float hs[4][64];
  int tid = threadIdx.x;
  int i = tid >> 6, f = tid & 63;
  int nb = blockIdx.x * 4;
  xs[i][f] = x4[(size_t)(nb + i) * 64 + f];
  __syncthreads();
  float h = b1[f];
#pragma unroll
  for (int k = 0; k < 64; ++k) h += xs[i][k] * W1[k * 64 + f];
  hs[i][f] = fmaxf(h, 0.0f);
  __syncthreads();
  if (tid < 12) {
    int ii = tid / 3, j = tid % 3;
    float o = b2[j];
#pragma unroll
    for (int k = 0; k < 64; ++k) o += hs[ii][k] * W2[k * 3 + j];
    out[(size_t)(nb + ii) * 3 + j] = o;
  }
}

// ---------------------------------------------------------------- launch
extern "C" void kernel_launch(void* const* d_in, const int* in_sizes, int n_in,
                              void* d_out, int out_size, void* d_ws, size_t ws_size,
                              hipStream_t stream) {
  const float* na   = (const float*)d_in[0];
  const float* ea   = (const float*)d_in[1];
  const int*   eidx = (const int*)d_in[2];
  const float* c1W1 = (const float*)d_in[3];
  const float* c1b1 = (const float*)d_in[4];
  const float* c1W2 = (const float*)d_in[5];
  const float* c1b2 = (const float*)d_in[6];
  const float* c2W1 = (const float*)d_in[7];
  const float* c2b1 = (const float*)d_in[8];
  const float* c2W2 = (const float*)d_in[9];
  const float* c2b2 = (const float*)d_in[10];
  const float* c3W1 = (const float*)d_in[11];
  const float* c3b1 = (const float*)d_in[12];
  const float* c3W2 = (const float*)d_in[13];
  const float* c3b2 = (const float*)d_in[14];
  const float* c4W1 = (const float*)d_in[15];
  const float* c4b1 = (const float*)d_in[16];
  const float* c4W2 = (const float*)d_in[17];
  const float* c4b2 = (const float*)d_in[18];
  const float* mW1  = (const float*)d_in[19];
  const float* mb1  = (const float*)d_in[20];
  const float* mW2  = (const float*)d_in[21];
  const float* mb2  = (const float*)d_in[22];

  char* ws = (char*)d_ws;
  size_t off = 0;
  auto alloc = [&](size_t b) -> void* {
    void* p = ws + off;
    off += (b + 255) & ~(size_t)255;
    return p;
  };
  int*   cnt    = (int*)alloc((size_t)NN * 4);
  int*   bsum   = (int*)alloc(256 * 4);
  int*   boff   = (int*)alloc(256 * 4);
  int*   start  = (int*)alloc((size_t)(NN + 1) * 4);
  int*   cursor = (int*)alloc((size_t)NN * 4);
  int*   srow   = (int*)alloc((size_t)NE * 4);
  int*   scol   = (int*)alloc((size_t)NE * 4);
  int*   perm   = (int*)alloc((size_t)NE * 4);
  f16*   ea4    = (f16*)alloc((size_t)NE * 4 * 2);
  f16*   x1     = (f16*)alloc((size_t)NN * 64 * 2);
  f16*   x2     = (f16*)alloc((size_t)NN * 64 * 2);
  f16*   x3     = (f16*)alloc((size_t)NN * 64 * 2);
  float* x4     = (float*)alloc((size_t)NN * 64 * 4);
  f16*   se1    = (f16*)alloc((size_t)NE * 64 * 2);   // also reused as e4 raw
  f16*   se2    = (f16*)alloc((size_t)NE * 64 * 2);
  f16*   se3    = (f16*)alloc((size_t)NE * 64 * 2);
  f16*   w1f1 = (f16*)alloc((size_t) 1 * 2048 * 2);
  f16*   w1f2 = (f16*)alloc((size_t) 7 * 2048 * 2);
  f16*   w1f3 = (f16*)alloc((size_t)12 * 2048 * 2);
  f16*   w1f4 = (f16*)alloc((size_t)12 * 2048 * 2);
  f16*   w2f1 = (f16*)alloc((size_t)4096 * 2);
  f16*   w2f2 = (f16*)alloc((size_t)4096 * 2);
  f16*   w2f3 = (f16*)alloc((size_t)4096 * 2);
  f16*   w2f4 = (f16*)alloc((size_t)4096 * 2);

  float* out_x = (float*)d_out;
  float* out_e = out_x + (size_t)NN * 3;

  constexpr int NBS = (NN + 255) / 256;   // 196

  hipMemsetAsync(cnt, 0, (size_t)NN * 4, stream);
  count_kernel<<<NE / 256, 256, 0, stream>>>(eidx, cnt);
  scan_a<<<NBS, 256, 0, stream>>>(cnt, bsum);
  scan_b<<<1, 256, 0, stream>>>(bsum, boff, NBS);
  scan_c<<<NBS, 256, 0, stream>>>(cnt, boff, start, cursor);
  scatter_kernel<<<NE / 256, 256, 0, stream>>>(eidx, ea, cursor, srow, scol, perm, ea4);

  prep_kernel<<< 3, 256, 0, stream>>>(c1W1,   9,  1, c1W2, w1f1, w2f1);
  prep_kernel<<< 9, 256, 0, stream>>>(c2W1, 195,  7, c2W2, w1f2, w2f2);
  prep_kernel<<<14, 256, 0, stream>>>(c3W1, 384, 12, c3W2, w1f3, w2f3);
  prep_kernel<<<14, 256, 0, stream>>>(c4W1, 384, 12, c4W2, w1f4, w2f4);

  edge_conv_kernel<1><<<GRID_EC, 256, 0, stream>>>(srow, scol, nullptr, na,
      nullptr, nullptr, nullptr, nullptr, ea4, w1f1, w2f1, c1b1, c1b2, se1, nullptr);
  node_sum_kernel<0><<<NN / 4, 256, 0, stream>>>(se1, start, x1);

  edge_conv_kernel<2><<<GRID_EC, 256, 0, stream>>>(srow, scol, nullptr, nullptr,
      x1, nullptr, se1, nullptr, ea4, w1f2, w2f2, c2b1, c2b2, se2, nullptr);
  node_sum_kernel<0><<<NN / 4, 256, 0, stream>>>(se2, start, x2);

  edge_conv_kernel<3><<<GRID_EC, 256, 0, stream>>>(srow, scol, nullptr, nullptr,
      x2, x1, se2, se1, nullptr, w1f3, w2f3, c3b1, c3b2, se3, nullptr);
  node_sum_kernel<0><<<NN / 4, 256, 0, stream>>>(se3, start, x3);

  edge_conv_kernel<4><<<GRID_EC, 256, 0, stream>>>(srow, scol, perm, nullptr,
      x3, x2, se3, se2, nullptr, w1f4, w2f4, c4b1, c4b2, se1, out_e);
  node_sum_kernel<1><<<NN / 4, 256, 0, stream>>>(se1, start, x4);

  head_kernel<<<NN / 4, 256, 0, stream>>>(x4, mW1, mb1, mW2, mb2, out_x);
}

// Round 2
// 1262.070 us; speedup vs baseline: 1.0825x; 1.0825x over previous
//
#include <hip/hip_runtime.h>
#include <cstdint>
#include <cstddef>

// MPNN: 4 edge-conv layers + head MLP.  N=50000, E=800000, F=64.
// Round 5: recover from round-4 regression (launch_bounds(256,4) -> VGPR 64 ->
// scratch spills; global B-frags for ks>=8 -> L2-evicted -> +400MB HBM).
//  - ALL ksteps staged in LDS again (conv3/4: 48KB w1s + 5KB hbuf = 54272 B,
//    exactly 3 blocks/CU; conv2: 33KB -> 4 blocks/CU).
//  - hbuf stays [4][16][40] (round-4 two-pass transpose, the good part).
//  - __launch_bounds__(256,3): VGPR cap ~170, natural demand ~128 -> no spill,
//    conv1/2 can still reach 4 blocks/CU via actual usage.
//  - grid stride uses gridDim.x; conv1/2 launched 1024 blocks, conv3/4 768.

#define NN 50000
#define NE 800000

typedef _Float16 f16;
typedef _Float16 f16x8 __attribute__((ext_vector_type(8)));
typedef _Float16 f16x4 __attribute__((ext_vector_type(4)));
typedef float    f32x4 __attribute__((ext_vector_type(4)));

// ---------------------------------------------------------------- sort build
__global__ void count_kernel(const int* __restrict__ eidx, int* __restrict__ cnt) {
  int i = blockIdx.x * 256 + threadIdx.x;
  if (i < NE) atomicAdd(&cnt[eidx[i]], 1);
}

__global__ void scan_a(const int* __restrict__ cnt, int* __restrict__ bsum) {
  __shared__ int sh[256];
  int i = blockIdx.x * 256 + threadIdx.x;
  sh[threadIdx.x] = (i < NN) ? cnt[i] : 0;
  __syncthreads();
  for (int off = 128; off > 0; off >>= 1) {
    if (threadIdx.x < off) sh[threadIdx.x] += sh[threadIdx.x + off];
    __syncthreads();
  }
  if (threadIdx.x == 0) bsum[blockIdx.x] = sh[0];
}

__global__ void scan_b(const int* __restrict__ bsum, int* __restrict__ boff, int nb) {
  __shared__ int sh[256];
  int t = threadIdx.x;
  int v = (t < nb) ? bsum[t] : 0;
  sh[t] = v; __syncthreads();
  for (int off = 1; off < 256; off <<= 1) {
    int x = (t >= off) ? sh[t - off] : 0;
    __syncthreads();
    sh[t] += x;
    __syncthreads();
  }
  if (t < nb) boff[t] = sh[t] - v;   // exclusive
}

__global__ void scan_c(const int* __restrict__ cnt, const int* __restrict__ boff,
                       int* __restrict__ start, int* __restrict__ cursor) {
  __shared__ int sh[256];
  int t = threadIdx.x;
  int i = blockIdx.x * 256 + t;
  int v = (i < NN) ? cnt[i] : 0;
  sh[t] = v; __syncthreads();
  for (int off = 1; off < 256; off <<= 1) {
    int x = (t >= off) ? sh[t - off] : 0;
    __syncthreads();
    sh[t] += x;
    __syncthreads();
  }
  if (i < NN) {
    int ex = boff[blockIdx.x] + sh[t] - v;
    start[i] = ex; cursor[i] = ex;
  }
  if (i == 0) start[NN] = NE;
}

__global__ void scatter_kernel(const int* __restrict__ eidx, const float* __restrict__ ea,
                               int* __restrict__ cursor,
                               int* __restrict__ srow, int* __restrict__ scol,
                               int* __restrict__ perm, f16* __restrict__ ea4) {
  int e = blockIdx.x * 256 + threadIdx.x;
  if (e >= NE) return;
  int r = eidx[e];
  int j = atomicAdd(&cursor[r], 1);
  srow[j] = r;
  scol[j] = eidx[NE + e];
  perm[j] = e;
  f16x4 v;
  v[0] = (f16)ea[3 * (size_t)e];
  v[1] = (f16)ea[3 * (size_t)e + 1];
  v[2] = (f16)ea[3 * (size_t)e + 2];
  v[3] = (f16)0.0f;
  *(f16x4*)&ea4[4 * (size_t)j] = v;
}

// ---------------------------------------------------------------- weight prep
// frag slot (ks,t,lane): dst[slot*8+j] = W[(ks*32+(lane>>4)*8+j)*64 + (t*16+(lane&15))]
__global__ void prep_kernel(const float* __restrict__ W1, int kreal1, int ksteps1,
                            const float* __restrict__ W2,
                            f16* __restrict__ w1f, f16* __restrict__ w2f) {
  int u = blockIdx.x * 256 + threadIdx.x;
  int total1 = ksteps1 * 256;
  const float* W; f16* dst; int kreal, slot;
  if (u < total1)            { W = W1; dst = w1f; kreal = kreal1; slot = u; }
  else if (u < total1 + 512) { W = W2; dst = w2f; kreal = 64;     slot = u - total1; }
  else return;
  int l = slot & 63, t = (slot >> 6) & 3, ks = slot >> 8;
  int n  = t * 16 + (l & 15);
  int kb = ks * 32 + ((l >> 4) * 8);
  f16x8 v;
#pragma unroll
  for (int j = 0; j < 8; ++j) {
    int k = kb + j;
    v[j] = (f16)((k < kreal) ? W[k * 64 + n] : 0.0f);
  }
  *(f16x8*)&dst[slot * 8] = v;
}

// ---------------------------------------------------------------- node segment sum
// one wave per node: sum raw f16 edge rows over [start[v], start[v+1]) -> relu(mean)
template<int F32OUT>
__global__ void node_sum_kernel(const f16* __restrict__ eout, const int* __restrict__ start,
                                void* __restrict__ xout) {
  int v = blockIdx.x * 4 + (threadIdx.x >> 6);
  int lane = threadIdx.x & 63;
  int g = lane >> 4, c4 = (lane & 15) * 4;
  int s0 = start[v], s1 = start[v + 1];
  f32x4 acc = (f32x4){0.f, 0.f, 0.f, 0.f};
  for (int i = s0 + g; i < s1; i += 4) {
    f16x4 h = *(const f16x4*)&eout[(size_t)i * 64 + c4];
#pragma unroll
    for (int q = 0; q < 4; ++q) acc[q] += (float)h[q];
  }
#pragma unroll
  for (int q = 0; q < 4; ++q) {
    acc[q] += __shfl_xor(acc[q], 16, 64);
    acc[q] += __shfl_xor(acc[q], 32, 64);
  }
  int cv = s1 - s0;
  float inv = 1.0f / (float)(cv > 0 ? cv : 1);
  if (g == 0) {
    if (F32OUT) {
      f32x4 o;
#pragma unroll
      for (int q = 0; q < 4; ++q) o[q] = fmaxf(acc[q] * inv, 0.0f);
      *(f32x4*)&((float*)xout)[(size_t)v * 64 + c4] = o;
    } else {
      f16x4 o;
#pragma unroll
      for (int q = 0; q < 4; ++q) o[q] = (f16)fmaxf(acc[q] * inv, 0.0f);
      *(f16x4*)&((f16*)xout)[(size_t)v * 64 + c4] = o;
    }
  }
}

// ---------------------------------------------------------------- edge conv
// Processes edges in SORTED order j. Writes eout[j] = RAW f16 edge output
// (relu applied by consumers). CONV==4 additionally scatters relu fp32 to
// out_e[perm[j]].
template<int CONV>
__global__ __launch_bounds__(256, 3) void edge_conv_kernel(
    const int* __restrict__ srow, const int* __restrict__ scol,
    const int* __restrict__ perm,
    const float* __restrict__ na,
    const f16* __restrict__ xA, const f16* __restrict__ xB,
    const f16* __restrict__ eA, const f16* __restrict__ eB,
    const f16* __restrict__ ea4,
    const f16* __restrict__ w1f, const f16* __restrict__ w2f,
    const float* __restrict__ b1, const float* __restrict__ b2,
    f16* __restrict__ eout, float* __restrict__ out_e)
{
  constexpr int KSTEPS = (CONV == 1) ? 1 : (CONV == 2 ? 7 : 12);

  __shared__ f16 w1s[KSTEPS * 2048];                  // all B-frags, 4KB per ks
  __shared__ __align__(16) f16 hbuf[4][16][40];       // per-wave 32-col xpose buf

  const int tid  = threadIdx.x;
  const int lane = tid & 63;
  const int wv   = tid >> 6;
  const int quad = lane >> 4;
  const int l15  = lane & 15;

  for (int u = tid; u < KSTEPS * 256; u += 256)
    *(f16x8*)&w1s[u * 8] = *(const f16x8*)&w1f[u * 8];

  float bb1[4], bb2[4];
#pragma unroll
  for (int t = 0; t < 4; ++t) { bb1[t] = b1[t * 16 + l15]; bb2[t] = b2[t * 16 + l15]; }

  f16x8 w2r[2][4];
#pragma unroll
  for (int kk = 0; kk < 2; ++kk)
#pragma unroll
    for (int t = 0; t < 4; ++t)
      w2r[kk][t] = *(const f16x8*)&w2f[((kk * 4 + t) * 64 + lane) * 8];

  __syncthreads();   // w1s visible; no further barriers

  constexpr int NTILE = NE / 32;          // wave-tiles of 32 edges
  const int gw = blockIdx.x * 4 + wv;
  const int stride = gridDim.x * 4;

  for (int jt = gw; jt < NTILE; jt += stride) {
    const int jb = jt * 32;
    const int j0 = jb + l15, j1 = j0 + 16;

    f32x4 acc[2][4];
#pragma unroll
    for (int s = 0; s < 2; ++s)
#pragma unroll
      for (int t = 0; t < 4; ++t) acc[s][t] = (f32x4){0.f, 0.f, 0.f, 0.f};

    if constexpr (CONV == 1) {
      const int r0 = srow[j0], r1 = srow[j1];
      const int c0 = scol[j0], c1 = scol[j1];
      f16x8 a0, a1;
#pragma unroll
      for (int j = 0; j < 8; ++j) { a0[j] = (f16)0.0f; a1[j] = (f16)0.0f; }
      f16x4 q0 = *(const f16x4*)&ea4[4 * (size_t)j0];
      f16x4 q1 = *(const f16x4*)&ea4[4 * (size_t)j1];
      if (quad == 0) {
        a0[0] = (f16)na[r0*3];  a0[1] = (f16)na[r0*3+1];  a0[2] = (f16)na[r0*3+2];
        a0[3] = (f16)na[c0*3];  a0[4] = (f16)na[c0*3+1];  a0[5] = (f16)na[c0*3+2];
        a0[6] = q0[0];          a0[7] = q0[1];
        a1[0] = (f16)na[r1*3];  a1[1] = (f16)na[r1*3+1];  a1[2] = (f16)na[r1*3+2];
        a1[3] = (f16)na[c1*3];  a1[4] = (f16)na[c1*3+1];  a1[5] = (f16)na[c1*3+2];
        a1[6] = q1[0];          a1[7] = q1[1];
      } else if (quad == 1) {
        a0[0] = q0[2];
        a1[0] = q1[2];
      }
#pragma unroll
      for (int t = 0; t < 4; ++t) {
        f16x8 b = *(const f16x8*)&w1s[(t * 64 + lane) * 8];
        acc[0][t] = __builtin_amdgcn_mfma_f32_16x16x32_f16(a0, b, acc[0][t], 0, 0, 0);
        acc[1][t] = __builtin_amdgcn_mfma_f32_16x16x32_f16(a1, b, acc[1][t], 0, 0, 0);
      }
    } else {
      constexpr int NREG = (CONV == 2) ? 3 : 6;
      constexpr int ERCH = (CONV == 2) ? 2 : 4;   // chunks >= ERCH are e-prev (relu)
      const int r0 = srow[j0], r1 = srow[j1];
      const int c0 = scol[j0], c1 = scol[j1];
      const f16* p0[NREG]; const f16* p1[NREG];
      if constexpr (CONV == 2) {
        p0[0] = xA + (size_t)r0 * 64;  p1[0] = xA + (size_t)r1 * 64;
        p0[1] = xA + (size_t)c0 * 64;  p1[1] = xA + (size_t)c1 * 64;
        p0[2] = eA + (size_t)j0 * 64;  p1[2] = eA + (size_t)j1 * 64;
      } else {
        p0[0] = xA + (size_t)r0 * 64;  p1[0] = xA + (size_t)r1 * 64;
        p0[1] = xB + (size_t)r0 * 64;  p1[1] = xB + (size_t)r1 * 64;
        p0[2] = xA + (size_t)c0 * 64;  p1[2] = xA + (size_t)c1 * 64;
        p0[3] = xB + (size_t)c0 * 64;  p1[3] = xB + (size_t)c1 * 64;
        p0[4] = eA + (size_t)j0 * 64;  p1[4] = eA + (size_t)j1 * 64;
        p0[5] = eB + (size_t)j0 * 64;  p1[5] = eB + (size_t)j1 * 64;
      }
#pragma unroll
      for (int ks = 0; ks < NREG * 2; ++ks) {
        const int c = ks >> 1, kk = ks & 1;
        f16x8 a0 = *(const f16x8*)(p0[c] + kk * 32 + quad * 8);
        f16x8 a1 = *(const f16x8*)(p1[c] + kk * 32 + quad * 8);
        if (c >= ERCH) {            // e-prev stored raw -> relu on load
#pragma unroll
          for (int j = 0; j < 8; ++j) {
            a0[j] = (a0[j] > (f16)0.0f) ? a0[j] : (f16)0.0f;
            a1[j] = (a1[j] > (f16)0.0f) ? a1[j] : (f16)0.0f;
          }
        }
#pragma unroll
        for (int t = 0; t < 4; ++t) {
          f16x8 b = *(const f16x8*)&w1s[((ks * 4 + t) * 64 + lane) * 8];
          acc[0][t] = __builtin_amdgcn_mfma_f32_16x16x32_f16(a0, b, acc[0][t], 0, 0, 0);
          acc[1][t] = __builtin_amdgcn_mfma_f32_16x16x32_f16(a1, b, acc[1][t], 0, 0, 0);
        }
      }
      if constexpr (CONV == 2) {    // tail ks 6: ea at cols 192..194
        f16x8 a0, a1;
#pragma unroll
        for (int j = 0; j < 8; ++j) { a0[j] = (f16)0.0f; a1[j] = (f16)0.0f; }
        f16x4 q0 = *(const f16x4*)&ea4[4 * (size_t)j0];
        f16x4 q1 = *(const f16x4*)&ea4[4 * (size_t)j1];
        if (quad == 0) {
          a0[0] = q0[0]; a0[1] = q0[1]; a0[2] = q0[2];
          a1[0] = q1[0]; a1[1] = q1[1]; a1[2] = q1[2];
        }
#pragma unroll
        for (int t = 0; t < 4; ++t) {
          f16x8 b = *(const f16x8*)&w1s[((6 * 4 + t) * 64 + lane) * 8];
          acc[0][t] = __builtin_amdgcn_mfma_f32_16x16x32_f16(a0, b, acc[0][t], 0, 0, 0);
          acc[1][t] = __builtin_amdgcn_mfma_f32_16x16x32_f16(a1, b, acc[1][t], 0, 0, 0);
        }
      }
    }

    // ---- per sub-tile: GEMM2 + stores (wave-private hbuf, in-order DS).
    // hbuf holds 32 cols at a time: two {write half, read A-frag} passes.
#pragma unroll
    for (int s = 0; s < 2; ++s) {
      f32x4 a2[4];
#pragma unroll
      for (int t = 0; t < 4; ++t) a2[t] = (f32x4){0.f, 0.f, 0.f, 0.f};
#pragma unroll
      for (int kk = 0; kk < 2; ++kk) {
#pragma unroll
        for (int th = 0; th < 2; ++th) {
          const int t = kk * 2 + th;
#pragma unroll
          for (int r = 0; r < 4; ++r)
            hbuf[wv][quad * 4 + r][th * 16 + l15] = (f16)fmaxf(acc[s][t][r] + bb1[t], 0.0f);
        }
        f16x8 ah = *(const f16x8*)&hbuf[wv][l15][quad * 8];
#pragma unroll
        for (int t = 0; t < 4; ++t)
          a2[t] = __builtin_amdgcn_mfma_f32_16x16x32_f16(ah, w2r[kk][t], a2[t], 0, 0, 0);
      }

      // raw edge-out f16: two 32-col transpose passes -> coalesced row stores
      const int j = jb + s * 16 + l15;
      f16x8 oh[2];
#pragma unroll
      for (int h = 0; h < 2; ++h) {
#pragma unroll
        for (int th = 0; th < 2; ++th) {
          const int t = h * 2 + th;
#pragma unroll
          for (int r = 0; r < 4; ++r)
            hbuf[wv][quad * 4 + r][th * 16 + l15] = (f16)(a2[t][r] + bb2[t]);
        }
        oh[h] = *(const f16x8*)&hbuf[wv][l15][quad * 8];
      }
      *(f16x8*)&eout[(size_t)j * 64 + quad * 8] = oh[0];
      *(f16x8*)&eout[(size_t)j * 64 + 32 + quad * 8] = oh[1];

      if constexpr (CONV == 4) {
        // full-precision relu output, scattered to original edge order
#pragma unroll
        for (int r = 0; r < 4; ++r) {
          const int p = perm[jb + s * 16 + quad * 4 + r];
#pragma unroll
          for (int t = 0; t < 4; ++t)
            out_e[(size_t)p * 64 + t * 16 + l15] = fmaxf(a2[t][r] + bb2[t], 0.0f);
        }
      }
    }
  }
}

// ---------------------------------------------------------------- head MLP
__global__ void head_kernel(const float* __restrict__ x4,
                            const float* __restrict__ W1, const float* __restrict__ b1,
                            const float* __restrict__ W2, const float* __restrict__ b2,
                            float* __restrict__ out) {
  __shared__ float xs[4][64];
  __shared__ float hs[4][64];
  int tid = threadIdx.x;
  int i = tid >> 6, f = tid & 63;
  int nb = blockIdx.x * 4;
  xs[i][f] = x4[(size_t)(nb + i) * 64 + f];
  __syncthreads();
  float h = b1[f];
#pragma unroll
  for (int k = 0; k < 64; ++k) h += xs[i][k] * W1[k * 64 + f];
  hs[i][f] = fmaxf(h, 0.0f);
  __syncthreads();
  if (tid < 12) {
    int ii = tid / 3, j = tid % 3;
    float o = b2[j];
#pragma unroll
    for (int k = 0; k < 64; ++k) o += hs[ii][k] * W2[k * 3 + j];
    out[(size_t)(nb + ii) * 3 + j] = o;
  }
}

// ---------------------------------------------------------------- launch
extern "C" void kernel_launch(void* const* d_in, const int* in_sizes, int n_in,
                              void* d_out, int out_size, void* d_ws, size_t ws_size,
                              hipStream_t stream) {
  const float* na   = (const float*)d_in[0];
  const float* ea   = (const float*)d_in[1];
  const int*   eidx = (const int*)d_in[2];
  const float* c1W1 = (const float*)d_in[3];
  const float* c1b1 = (const float*)d_in[4];
  const float* c1W2 = (const float*)d_in[5];
  const float* c1b2 = (const float*)d_in[6];
  const float* c2W1 = (const float*)d_in[7];
  const float* c2b1 = (const float*)d_in[8];
  const float* c2W2 = (const float*)d_in[9];
  const float* c2b2 = (const float*)d_in[10];
  const float* c3W1 = (const float*)d_in[11];
  const float* c3b1 = (const float*)d_in[12];
  const float* c3W2 = (const float*)d_in[13];
  const float* c3b2 = (const float*)d_in[14];
  const float* c4W1 = (const float*)d_in[15];
  const float* c4b1 = (const float*)d_in[16];
  const float* c4W2 = (const float*)d_in[17];
  const float* c4b2 = (const float*)d_in[18];
  const float* mW1  = (const float*)d_in[19];
  const float* mb1  = (const float*)d_in[20];
  const float* mW2  = (const float*)d_in[21];
  const float* mb2  = (const float*)d_in[22];

  char* ws = (char*)d_ws;
  size_t off = 0;
  auto alloc = [&](size_t b) -> void* {
    void* p = ws + off;
    off += (b + 255) & ~(size_t)255;
    return p;
  };
  int*   cnt    = (int*)alloc((size_t)NN * 4);
  int*   bsum   = (int*)alloc(256 * 4);
  int*   boff   = (int*)alloc(256 * 4);
  int*   start  = (int*)alloc((size_t)(NN + 1) * 4);
  int*   cursor = (int*)alloc((size_t)NN * 4);
  int*   srow   = (int*)alloc((size_t)NE * 4);
  int*   scol   = (int*)alloc((size_t)NE * 4);
  int*   perm   = (int*)alloc((size_t)NE * 4);
  f16*   ea4    = (f16*)alloc((size_t)NE * 4 * 2);
  f16*   x1     = (f16*)alloc((size_t)NN * 64 * 2);
  f16*   x2     = (f16*)alloc((size_t)NN * 64 * 2);
  f16*   x3     = (f16*)alloc((size_t)NN * 64 * 2);
  float* x4     = (float*)alloc((size_t)NN * 64 * 4);
  f16*   se1    = (f16*)alloc((size_t)NE * 64 * 2);   // also reused as e4 raw
  f16*   se2    = (f16*)alloc((size_t)NE * 64 * 2);
  f16*   se3    = (f16*)alloc((size_t)NE * 64 * 2);
  f16*   w1f1 = (f16*)alloc((size_t) 1 * 2048 * 2);
  f16*   w1f2 = (f16*)alloc((size_t) 7 * 2048 * 2);
  f16*   w1f3 = (f16*)alloc((size_t)12 * 2048 * 2);
  f16*   w1f4 = (f16*)alloc((size_t)12 * 2048 * 2);
  f16*   w2f1 = (f16*)alloc((size_t)4096 * 2);
  f16*   w2f2 = (f16*)alloc((size_t)4096 * 2);
  f16*   w2f3 = (f16*)alloc((size_t)4096 * 2);
  f16*   w2f4 = (f16*)alloc((size_t)4096 * 2);

  float* out_x = (float*)d_out;
  float* out_e = out_x + (size_t)NN * 3;

  constexpr int NBS = (NN + 255) / 256;   // 196
  constexpr int GRID_C12 = 1024;          // 4 blocks/CU potential (LDS 33KB)
  constexpr int GRID_C34 = 768;           // 3 blocks/CU (LDS 54272 B)

  hipMemsetAsync(cnt, 0, (size_t)NN * 4, stream);
  count_kernel<<<NE / 256, 256, 0, stream>>>(eidx, cnt);
  scan_a<<<NBS, 256, 0, stream>>>(cnt, bsum);
  scan_b<<<1, 256, 0, stream>>>(bsum, boff, NBS);
  scan_c<<<NBS, 256, 0, stream>>>(cnt, boff, start, cursor);
  scatter_kernel<<<NE / 256, 256, 0, stream>>>(eidx, ea, cursor, srow, scol, perm, ea4);

  prep_kernel<<< 3, 256, 0, stream>>>(c1W1,   9,  1, c1W2, w1f1, w2f1);
  prep_kernel<<< 9, 256, 0, stream>>>(c2W1, 195,  7, c2W2, w1f2, w2f2);
  prep_kernel<<<14, 256, 0, stream>>>(c3W1, 384, 12, c3W2, w1f3, w2f3);
  prep_kernel<<<14, 256, 0, stream>>>(c4W1, 384, 12, c4W2, w1f4, w2f4);

  edge_conv_kernel<1><<<GRID_C12, 256, 0, stream>>>(srow, scol, nullptr, na,
      nullptr, nullptr, nullptr, nullptr, ea4, w1f1, w2f1, c1b1, c1b2, se1, nullptr);
  node_sum_kernel<0><<<NN / 4, 256, 0, stream>>>(se1, start, x1);

  edge_conv_kernel<2><<<GRID_C12, 256, 0, stream>>>(srow, scol, nullptr, nullptr,
      x1, nullptr, se1, nullptr, ea4, w1f2, w2f2, c2b1, c2b2, se2, nullptr);
  node_sum_kernel<0><<<NN / 4, 256, 0, stream>>>(se2, start, x2);

  edge_conv_kernel<3><<<GRID_C34, 256, 0, stream>>>(srow, scol, nullptr, nullptr,
      x2, x1, se2, se1, nullptr, w1f3, w2f3, c3b1, c3b2, se3, nullptr);
  node_sum_kernel<0><<<NN / 4, 256, 0, stream>>>(se3, start, x3);

  edge_conv_kernel<4><<<GRID_C34, 256, 0, stream>>>(srow, scol, perm, nullptr,
      x3, x2, se3, se2, nullptr, w1f4, w2f4, c4b1, c4b2, se1, out_e);
  node_sum_kernel<1><<<NN / 4, 256, 0, stream>>>(se1, start, x4);

  head_kernel<<<NN / 4, 256, 0, stream>>>(x4, mW1, mb1, mW2, mb2, out_x);
}

// Round 3
// 1124.763 us; speedup vs baseline: 1.2147x; 1.1221x over previous
//
#include <hip/hip_runtime.h>
#include <cstdint>
#include <cstddef>

// MPNN: 4 edge-conv layers + head MLP.  N=50000, E=800000, F=64.
// Round 6: latency attack. Rounds 4/5 proved minwaves>2 makes the allocator
// spill (VGPR 64/84, +270..500MB HBM). Revert to launch_bounds(256,2),
// GRID 512 (exactly 2 resident blocks/CU), and hide the per-tile serial chain
// (idx load -> x-gather -> MFMA) with an explicit software pipeline:
//  - indices prefetched 2 tiles ahead
//  - x-row fragments (random gathers) prefetched 1 tile ahead (64 VGPRs)
//  - e-prev streaming loads issued at top of iteration
//  - w2 fragments moved VGPR->LDS (8KB) to fund prefetch registers

#define NN 50000
#define NE 800000

typedef _Float16 f16;
typedef _Float16 f16x8 __attribute__((ext_vector_type(8)));
typedef _Float16 f16x4 __attribute__((ext_vector_type(4)));
typedef float    f32x4 __attribute__((ext_vector_type(4)));

// ---------------------------------------------------------------- sort build
__global__ void count_kernel(const int* __restrict__ eidx, int* __restrict__ cnt) {
  int i = blockIdx.x * 256 + threadIdx.x;
  if (i < NE) atomicAdd(&cnt[eidx[i]], 1);
}

__global__ void scan_a(const int* __restrict__ cnt, int* __restrict__ bsum) {
  __shared__ int sh[256];
  int i = blockIdx.x * 256 + threadIdx.x;
  sh[threadIdx.x] = (i < NN) ? cnt[i] : 0;
  __syncthreads();
  for (int off = 128; off > 0; off >>= 1) {
    if (threadIdx.x < off) sh[threadIdx.x] += sh[threadIdx.x + off];
    __syncthreads();
  }
  if (threadIdx.x == 0) bsum[blockIdx.x] = sh[0];
}

__global__ void scan_b(const int* __restrict__ bsum, int* __restrict__ boff, int nb) {
  __shared__ int sh[256];
  int t = threadIdx.x;
  int v = (t < nb) ? bsum[t] : 0;
  sh[t] = v; __syncthreads();
  for (int off = 1; off < 256; off <<= 1) {
    int x = (t >= off) ? sh[t - off] : 0;
    __syncthreads();
    sh[t] += x;
    __syncthreads();
  }
  if (t < nb) boff[t] = sh[t] - v;   // exclusive
}

__global__ void scan_c(const int* __restrict__ cnt, const int* __restrict__ boff,
                       int* __restrict__ start, int* __restrict__ cursor) {
  __shared__ int sh[256];
  int t = threadIdx.x;
  int i = blockIdx.x * 256 + t;
  int v = (i < NN) ? cnt[i] : 0;
  sh[t] = v; __syncthreads();
  for (int off = 1; off < 256; off <<= 1) {
    int x = (t >= off) ? sh[t - off] : 0;
    __syncthreads();
    sh[t] += x;
    __syncthreads();
  }
  if (i < NN) {
    int ex = boff[blockIdx.x] + sh[t] - v;
    start[i] = ex; cursor[i] = ex;
  }
  if (i == 0) start[NN] = NE;
}

__global__ void scatter_kernel(const int* __restrict__ eidx, const float* __restrict__ ea,
                               int* __restrict__ cursor,
                               int* __restrict__ srow, int* __restrict__ scol,
                               int* __restrict__ perm, f16* __restrict__ ea4) {
  int e = blockIdx.x * 256 + threadIdx.x;
  if (e >= NE) return;
  int r = eidx[e];
  int j = atomicAdd(&cursor[r], 1);
  srow[j] = r;
  scol[j] = eidx[NE + e];
  perm[j] = e;
  f16x4 v;
  v[0] = (f16)ea[3 * (size_t)e];
  v[1] = (f16)ea[3 * (size_t)e + 1];
  v[2] = (f16)ea[3 * (size_t)e + 2];
  v[3] = (f16)0.0f;
  *(f16x4*)&ea4[4 * (size_t)j] = v;
}

// ---------------------------------------------------------------- weight prep
// frag slot (ks,t,lane): dst[slot*8+j] = W[(ks*32+(lane>>4)*8+j)*64 + (t*16+(lane&15))]
__global__ void prep_kernel(const float* __restrict__ W1, int kreal1, int ksteps1,
                            const float* __restrict__ W2,
                            f16* __restrict__ w1f, f16* __restrict__ w2f) {
  int u = blockIdx.x * 256 + threadIdx.x;
  int total1 = ksteps1 * 256;
  const float* W; f16* dst; int kreal, slot;
  if (u < total1)            { W = W1; dst = w1f; kreal = kreal1; slot = u; }
  else if (u < total1 + 512) { W = W2; dst = w2f; kreal = 64;     slot = u - total1; }
  else return;
  int l = slot & 63, t = (slot >> 6) & 3, ks = slot >> 8;
  int n  = t * 16 + (l & 15);
  int kb = ks * 32 + ((l >> 4) * 8);
  f16x8 v;
#pragma unroll
  for (int j = 0; j < 8; ++j) {
    int k = kb + j;
    v[j] = (f16)((k < kreal) ? W[k * 64 + n] : 0.0f);
  }
  *(f16x8*)&dst[slot * 8] = v;
}

// ---------------------------------------------------------------- node segment sum
// one wave per node: sum raw f16 edge rows over [start[v], start[v+1]) -> relu(mean)
template<int F32OUT>
__global__ void node_sum_kernel(const f16* __restrict__ eout, const int* __restrict__ start,
                                void* __restrict__ xout) {
  int v = blockIdx.x * 4 + (threadIdx.x >> 6);
  int lane = threadIdx.x & 63;
  int g = lane >> 4, c4 = (lane & 15) * 4;
  int s0 = start[v], s1 = start[v + 1];
  f32x4 acc = (f32x4){0.f, 0.f, 0.f, 0.f};
  for (int i = s0 + g; i < s1; i += 4) {
    f16x4 h = *(const f16x4*)&eout[(size_t)i * 64 + c4];
#pragma unroll
    for (int q = 0; q < 4; ++q) acc[q] += (float)h[q];
  }
#pragma unroll
  for (int q = 0; q < 4; ++q) {
    acc[q] += __shfl_xor(acc[q], 16, 64);
    acc[q] += __shfl_xor(acc[q], 32, 64);
  }
  int cv = s1 - s0;
  float inv = 1.0f / (float)(cv > 0 ? cv : 1);
  if (g == 0) {
    if (F32OUT) {
      f32x4 o;
#pragma unroll
      for (int q = 0; q < 4; ++q) o[q] = fmaxf(acc[q] * inv, 0.0f);
      *(f32x4*)&((float*)xout)[(size_t)v * 64 + c4] = o;
    } else {
      f16x4 o;
#pragma unroll
      for (int q = 0; q < 4; ++q) o[q] = (f16)fmaxf(acc[q] * inv, 0.0f);
      *(f16x4*)&((f16*)xout)[(size_t)v * 64 + c4] = o;
    }
  }
}

// ---------------------------------------------------------------- edge conv
// Processes edges in SORTED order j. Writes eout[j] = RAW f16 edge output
// (relu applied by consumers). CONV==4 additionally scatters relu fp32 to
// out_e[perm[j]].
template<int CONV>
__global__ __launch_bounds__(256, 2) void edge_conv_kernel(
    const int* __restrict__ srow, const int* __restrict__ scol,
    const int* __restrict__ perm,
    const float* __restrict__ na,
    const f16* __restrict__ xA, const f16* __restrict__ xB,
    const f16* __restrict__ eA, const f16* __restrict__ eB,
    const f16* __restrict__ ea4,
    const f16* __restrict__ w1f, const f16* __restrict__ w2f,
    const float* __restrict__ b1, const float* __restrict__ b2,
    f16* __restrict__ eout, float* __restrict__ out_e)
{
  constexpr int KSTEPS = (CONV == 1) ? 1 : (CONV == 2 ? 7 : 12);

  __shared__ f16 w1s[KSTEPS * 2048];                  // GEMM1 B-frags (4KB/ks)
  __shared__ f16 w2s[4096];                           // GEMM2 B-frags (8KB)
  __shared__ __align__(16) f16 hbuf[4][16][40];       // per-wave 32-col xpose buf

  const int tid  = threadIdx.x;
  const int lane = tid & 63;
  const int wv   = tid >> 6;
  const int quad = lane >> 4;
  const int l15  = lane & 15;

  for (int u = tid; u < KSTEPS * 256; u += 256)
    *(f16x8*)&w1s[u * 8] = *(const f16x8*)&w1f[u * 8];
  for (int u = tid; u < 512; u += 256)
    *(f16x8*)&w2s[u * 8] = *(const f16x8*)&w2f[u * 8];

  float bb1[4], bb2[4];
#pragma unroll
  for (int t = 0; t < 4; ++t) { bb1[t] = b1[t * 16 + l15]; bb2[t] = b2[t * 16 + l15]; }

  __syncthreads();   // w1s/w2s visible; no further barriers

  constexpr int NTILE = NE / 32;          // wave-tiles of 32 edges
  const int gw = blockIdx.x * 4 + wv;
  const int stride = gridDim.x * 4;

  // ---- shared epilogue: hidden=relu(acc+b1) -> GEMM2 -> raw f16 row stores
  auto epilogue = [&](f32x4 (&acc)[2][4], int jb) {
#pragma unroll
    for (int s = 0; s < 2; ++s) {
      f32x4 a2[4];
#pragma unroll
      for (int t = 0; t < 4; ++t) a2[t] = (f32x4){0.f, 0.f, 0.f, 0.f};
#pragma unroll
      for (int kk = 0; kk < 2; ++kk) {
#pragma unroll
        for (int th = 0; th < 2; ++th) {
          const int t = kk * 2 + th;
#pragma unroll
          for (int r = 0; r < 4; ++r)
            hbuf[wv][quad * 4 + r][th * 16 + l15] = (f16)fmaxf(acc[s][t][r] + bb1[t], 0.0f);
        }
        f16x8 ah = *(const f16x8*)&hbuf[wv][l15][quad * 8];
#pragma unroll
        for (int t = 0; t < 4; ++t) {
          f16x8 wb = *(const f16x8*)&w2s[((kk * 4 + t) * 64 + lane) * 8];
          a2[t] = __builtin_amdgcn_mfma_f32_16x16x32_f16(ah, wb, a2[t], 0, 0, 0);
        }
      }

      const int j = jb + s * 16 + l15;
      f16x8 oh[2];
#pragma unroll
      for (int h = 0; h < 2; ++h) {
#pragma unroll
        for (int th = 0; th < 2; ++th) {
          const int t = h * 2 + th;
#pragma unroll
          for (int r = 0; r < 4; ++r)
            hbuf[wv][quad * 4 + r][th * 16 + l15] = (f16)(a2[t][r] + bb2[t]);
        }
        oh[h] = *(const f16x8*)&hbuf[wv][l15][quad * 8];
      }
      *(f16x8*)&eout[(size_t)j * 64 + quad * 8] = oh[0];
      *(f16x8*)&eout[(size_t)j * 64 + 32 + quad * 8] = oh[1];

      if constexpr (CONV == 4) {
#pragma unroll
        for (int r = 0; r < 4; ++r) {
          const int p = perm[jb + s * 16 + quad * 4 + r];
#pragma unroll
          for (int t = 0; t < 4; ++t)
            out_e[(size_t)p * 64 + t * 16 + l15] = fmaxf(a2[t][r] + bb2[t], 0.0f);
        }
      }
    }
  };

  if constexpr (CONV == 1) {
    for (int jt = gw; jt < NTILE; jt += stride) {
      const int jb = jt * 32;
      const int j0 = jb + l15, j1 = j0 + 16;
      const int r0 = srow[j0], r1 = srow[j1];
      const int c0 = scol[j0], c1 = scol[j1];
      f16x8 a0, a1;
#pragma unroll
      for (int j = 0; j < 8; ++j) { a0[j] = (f16)0.0f; a1[j] = (f16)0.0f; }
      f16x4 q0 = *(const f16x4*)&ea4[4 * (size_t)j0];
      f16x4 q1 = *(const f16x4*)&ea4[4 * (size_t)j1];
      if (quad == 0) {
        a0[0] = (f16)na[r0*3];  a0[1] = (f16)na[r0*3+1];  a0[2] = (f16)na[r0*3+2];
        a0[3] = (f16)na[c0*3];  a0[4] = (f16)na[c0*3+1];  a0[5] = (f16)na[c0*3+2];
        a0[6] = q0[0];          a0[7] = q0[1];
        a1[0] = (f16)na[r1*3];  a1[1] = (f16)na[r1*3+1];  a1[2] = (f16)na[r1*3+2];
        a1[3] = (f16)na[c1*3];  a1[4] = (f16)na[c1*3+1];  a1[5] = (f16)na[c1*3+2];
        a1[6] = q1[0];          a1[7] = q1[1];
      } else if (quad == 1) {
        a0[0] = q0[2];
        a1[0] = q1[2];
      }
      f32x4 acc[2][4];
#pragma unroll
      for (int s = 0; s < 2; ++s)
#pragma unroll
        for (int t = 0; t < 4; ++t) acc[s][t] = (f32x4){0.f, 0.f, 0.f, 0.f};
#pragma unroll
      for (int t = 0; t < 4; ++t) {
        f16x8 b = *(const f16x8*)&w1s[(t * 64 + lane) * 8];
        acc[0][t] = __builtin_amdgcn_mfma_f32_16x16x32_f16(a0, b, acc[0][t], 0, 0, 0);
        acc[1][t] = __builtin_amdgcn_mfma_f32_16x16x32_f16(a1, b, acc[1][t], 0, 0, 0);
      }
      epilogue(acc, jb);
    }
  } else {
    // -------- software-pipelined path (CONV 2/3/4) --------
    constexpr int NXC = (CONV == 2) ? 2 : 4;   // x-gather chunks (prefetched)
    constexpr int NEC = (CONV == 2) ? 1 : 2;   // e-prev chunks (streamed)

    f16x8 xc[NXC * 4], xn[NXC * 4];            // [c][kk][subtile] flattened

    auto issue_x = [&](f16x8 (&dst)[NXC * 4], int r0, int c0, int r1, int c1) {
      const f16* q0[NXC]; const f16* q1[NXC];
      if constexpr (CONV == 2) {
        q0[0] = xA + (size_t)r0 * 64;  q1[0] = xA + (size_t)r1 * 64;
        q0[1] = xA + (size_t)c0 * 64;  q1[1] = xA + (size_t)c1 * 64;
      } else {
        q0[0] = xA + (size_t)r0 * 64;  q1[0] = xA + (size_t)r1 * 64;
        q0[1] = xB + (size_t)r0 * 64;  q1[1] = xB + (size_t)r1 * 64;
        q0[2] = xA + (size_t)c0 * 64;  q1[2] = xA + (size_t)c1 * 64;
        q0[3] = xB + (size_t)c0 * 64;  q1[3] = xB + (size_t)c1 * 64;
      }
#pragma unroll
      for (int c = 0; c < NXC; ++c)
#pragma unroll
        for (int kk = 0; kk < 2; ++kk) {
          dst[(c * 2 + kk) * 2 + 0] = *(const f16x8*)(q0[c] + kk * 32 + quad * 8);
          dst[(c * 2 + kk) * 2 + 1] = *(const f16x8*)(q1[c] + kk * 32 + quad * 8);
        }
    };

    int jt = gw;
    if (jt < NTILE) {
      {  // prologue: current tile's x-frags + next tile's indices
        const int jb = jt * 32;
        const int r0 = srow[jb + l15], r1 = srow[jb + 16 + l15];
        const int c0 = scol[jb + l15], c1 = scol[jb + 16 + l15];
        issue_x(xc, r0, c0, r1, c1);
      }
      int nr0 = 0, nr1 = 0, nc0 = 0, nc1 = 0;
      {
        const int jn = jt + stride;
        if (jn < NTILE) {
          const int njb = jn * 32;
          nr0 = srow[njb + l15];  nr1 = srow[njb + 16 + l15];
          nc0 = scol[njb + l15];  nc1 = scol[njb + 16 + l15];
        }
      }

      for (; jt < NTILE; jt += stride) {
        const int jb = jt * 32;
        const size_t j0 = (size_t)(jb + l15), j1 = j0 + 16;
        const int jn = jt + stride;
        const bool hasnext = jn < NTILE;

        // 1) current-tile e-prev streaming loads (needed after NXC*2 ksteps)
        f16x8 e0[NEC * 2], e1[NEC * 2];
#pragma unroll
        for (int ec = 0; ec < NEC; ++ec) {
          const f16* ep = (ec == 0) ? eA : eB;
#pragma unroll
          for (int kk = 0; kk < 2; ++kk) {
            e0[ec * 2 + kk] = *(const f16x8*)(ep + j0 * 64 + kk * 32 + quad * 8);
            e1[ec * 2 + kk] = *(const f16x8*)(ep + j1 * 64 + kk * 32 + quad * 8);
          }
        }
        // conv2 tail (edge_attr cols 192..194)
        f16x4 t0, t1;
        if constexpr (CONV == 2) {
          t0 = *(const f16x4*)&ea4[4 * j0];
          t1 = *(const f16x4*)&ea4[4 * j1];
        }

        // 2) next-tile x gathers (consumed next iteration)
        if (hasnext) issue_x(xn, nr0, nc0, nr1, nc1);

        // 3) indices two tiles ahead
        int mr0 = 0, mr1 = 0, mc0 = 0, mc1 = 0;
        const int jm = jn + stride;
        if (jm < NTILE) {
          const int mjb = jm * 32;
          mr0 = srow[mjb + l15];  mr1 = srow[mjb + 16 + l15];
          mc0 = scol[mjb + l15];  mc1 = scol[mjb + 16 + l15];
        }

        f32x4 acc[2][4];
#pragma unroll
        for (int s = 0; s < 2; ++s)
#pragma unroll
          for (int t = 0; t < 4; ++t) acc[s][t] = (f32x4){0.f, 0.f, 0.f, 0.f};

        // 4) GEMM1: x chunks from prefetched regs (ready)
#pragma unroll
        for (int ks = 0; ks < NXC * 2; ++ks) {
#pragma unroll
          for (int t = 0; t < 4; ++t) {
            f16x8 b = *(const f16x8*)&w1s[((ks * 4 + t) * 64 + lane) * 8];
            acc[0][t] = __builtin_amdgcn_mfma_f32_16x16x32_f16(xc[ks * 2 + 0], b, acc[0][t], 0, 0, 0);
            acc[1][t] = __builtin_amdgcn_mfma_f32_16x16x32_f16(xc[ks * 2 + 1], b, acc[1][t], 0, 0, 0);
          }
        }

        // 5) GEMM1: e-prev chunks (relu on load; loads had ks0..NXC*2-1 to land)
#pragma unroll
        for (int ec = 0; ec < NEC; ++ec)
#pragma unroll
          for (int kk = 0; kk < 2; ++kk) {
            const int u = ec * 2 + kk;
            f16x8 a0 = e0[u], a1 = e1[u];
#pragma unroll
            for (int j = 0; j < 8; ++j) {
              a0[j] = (a0[j] > (f16)0.0f) ? a0[j] : (f16)0.0f;
              a1[j] = (a1[j] > (f16)0.0f) ? a1[j] : (f16)0.0f;
            }
            const int ks = NXC * 2 + u;
#pragma unroll
            for (int t = 0; t < 4; ++t) {
              f16x8 b = *(const f16x8*)&w1s[((ks * 4 + t) * 64 + lane) * 8];
              acc[0][t] = __builtin_amdgcn_mfma_f32_16x16x32_f16(a0, b, acc[0][t], 0, 0, 0);
              acc[1][t] = __builtin_amdgcn_mfma_f32_16x16x32_f16(a1, b, acc[1][t], 0, 0, 0);
            }
          }

        if constexpr (CONV == 2) {   // tail ks 6: ea at cols 192..194
          f16x8 a0, a1;
#pragma unroll
          for (int j = 0; j < 8; ++j) { a0[j] = (f16)0.0f; a1[j] = (f16)0.0f; }
          if (quad == 0) {
            a0[0] = t0[0]; a0[1] = t0[1]; a0[2] = t0[2];
            a1[0] = t1[0]; a1[1] = t1[1]; a1[2] = t1[2];
          }
#pragma unroll
          for (int t = 0; t < 4; ++t) {
            f16x8 b = *(const f16x8*)&w1s[((6 * 4 + t) * 64 + lane) * 8];
            acc[0][t] = __builtin_amdgcn_mfma_f32_16x16x32_f16(a0, b, acc[0][t], 0, 0, 0);
            acc[1][t] = __builtin_amdgcn_mfma_f32_16x16x32_f16(a1, b, acc[1][t], 0, 0, 0);
          }
        }

        // 6) GEMM2 + stores
        epilogue(acc, jb);

        // 7) rotate pipeline state (xn landed during 4-6)
        if (hasnext) {
#pragma unroll
          for (int u = 0; u < NXC * 4; ++u) xc[u] = xn[u];
          nr0 = mr0; nr1 = mr1; nc0 = mc0; nc1 = mc1;
        }
      }
    }
  }
}

// ---------------------------------------------------------------- head MLP
__global__ void head_kernel(const float* __restrict__ x4,
                            const float* __restrict__ W1, const float* __restrict__ b1,
                            const float* __restrict__ W2, const float* __restrict__ b2,
                            float* __restrict__ out) {
  __shared__ float xs[4][64];
  __shared__ float hs[4][64];
  int tid = threadIdx.x;
  int i = tid >> 6, f = tid & 63;
  int nb = blockIdx.x * 4;
  xs[i][f] = x4[(size_t)(nb + i) * 64 + f];
  __syncthreads();
  float h = b1[f];
#pragma unroll
  for (int k = 0; k < 64; ++k) h += xs[i][k] * W1[k * 64 + f];
  hs[i][f] = fmaxf(h, 0.0f);
  __syncthreads();
  if (tid < 12) {
    int ii = tid / 3, j = tid % 3;
    float o = b2[j];
#pragma unroll
    for (int k = 0; k < 64; ++k) o += hs[ii][k] * W2[k * 3 + j];
    out[(size_t)(nb + ii) * 3 + j] = o;
  }
}

// ---------------------------------------------------------------- launch
extern "C" void kernel_launch(void* const* d_in, const int* in_sizes, int n_in,
                              void* d_out, int out_size, void* d_ws, size_t ws_size,
                              hipStream_t stream) {
  const float* na   = (const float*)d_in[0];
  const float* ea   = (const float*)d_in[1];
  const int*   eidx = (const int*)d_in[2];
  const float* c1W1 = (const float*)d_in[3];
  const float* c1b1 = (const float*)d_in[4];
  const float* c1W2 = (const float*)d_in[5];
  const float* c1b2 = (const float*)d_in[6];
  const float* c2W1 = (const float*)d_in[7];
  const float* c2b1 = (const float*)d_in[8];
  const float* c2W2 = (const float*)d_in[9];
  const float* c2b2 = (const float*)d_in[10];
  const float* c3W1 = (const float*)d_in[11];
  const float* c3b1 = (const float*)d_in[12];
  const float* c3W2 = (const float*)d_in[13];
  const float* c3b2 = (const float*)d_in[14];
  const float* c4W1 = (const float*)d_in[15];
  const float* c4b1 = (const float*)d_in[16];
  const float* c4W2 = (const float*)d_in[17];
  const float* c4b2 = (const float*)d_in[18];
  const float* mW1  = (const float*)d_in[19];
  const float* mb1  = (const float*)d_in[20];
  const float* mW2  = (const float*)d_in[21];
  const float* mb2  = (const float*)d_in[22];

  char* ws = (char*)d_ws;
  size_t off = 0;
  auto alloc = [&](size_t b) -> void* {
    void* p = ws + off;
    off += (b + 255) & ~(size_t)255;
    return p;
  };
  int*   cnt    = (int*)alloc((size_t)NN * 4);
  int*   bsum   = (int*)alloc(256 * 4);
  int*   boff   = (int*)alloc(256 * 4);
  int*   start  = (int*)alloc((size_t)(NN + 1) * 4);
  int*   cursor = (int*)alloc((size_t)NN * 4);
  int*   srow   = (int*)alloc((size_t)NE * 4);
  int*   scol   = (int*)alloc((size_t)NE * 4);
  int*   perm   = (int*)alloc((size_t)NE * 4);
  f16*   ea4    = (f16*)alloc((size_t)NE * 4 * 2);
  f16*   x1     = (f16*)alloc((size_t)NN * 64 * 2);
  f16*   x2     = (f16*)alloc((size_t)NN * 64 * 2);
  f16*   x3     = (f16*)alloc((size_t)NN * 64 * 2);
  float* x4     = (float*)alloc((size_t)NN * 64 * 4);
  f16*   se1    = (f16*)alloc((size_t)NE * 64 * 2);   // also reused as e4 raw
  f16*   se2    = (f16*)alloc((size_t)NE * 64 * 2);
  f16*   se3    = (f16*)alloc((size_t)NE * 64 * 2);
  f16*   w1f1 = (f16*)alloc((size_t) 1 * 2048 * 2);
  f16*   w1f2 = (f16*)alloc((size_t) 7 * 2048 * 2);
  f16*   w1f3 = (f16*)alloc((size_t)12 * 2048 * 2);
  f16*   w1f4 = (f16*)alloc((size_t)12 * 2048 * 2);
  f16*   w2f1 = (f16*)alloc((size_t)4096 * 2);
  f16*   w2f2 = (f16*)alloc((size_t)4096 * 2);
  f16*   w2f3 = (f16*)alloc((size_t)4096 * 2);
  f16*   w2f4 = (f16*)alloc((size_t)4096 * 2);

  float* out_x = (float*)d_out;
  float* out_e = out_x + (size_t)NN * 3;

  constexpr int NBS = (NN + 255) / 256;   // 196
  constexpr int GRID_C1  = 1024;
  constexpr int GRID_C   = 512;           // 2 resident blocks/CU, no tail

  hipMemsetAsync(cnt, 0, (size_t)NN * 4, stream);
  count_kernel<<<NE / 256, 256, 0, stream>>>(eidx, cnt);
  scan_a<<<NBS, 256, 0, stream>>>(cnt, bsum);
  scan_b<<<1, 256, 0, stream>>>(bsum, boff, NBS);
  scan_c<<<NBS, 256, 0, stream>>>(cnt, boff, start, cursor);
  scatter_kernel<<<NE / 256, 256, 0, stream>>>(eidx, ea, cursor, srow, scol, perm, ea4);

  prep_kernel<<< 3, 256, 0, stream>>>(c1W1,   9,  1, c1W2, w1f1, w2f1);
  prep_kernel<<< 9, 256, 0, stream>>>(c2W1, 195,  7, c2W2, w1f2, w2f2);
  prep_kernel<<<14, 256, 0, stream>>>(c3W1, 384, 12, c3W2, w1f3, w2f3);
  prep_kernel<<<14, 256, 0, stream>>>(c4W1, 384, 12, c4W2, w1f4, w2f4);

  edge_conv_kernel<1><<<GRID_C1, 256, 0, stream>>>(srow, scol, nullptr, na,
      nullptr, nullptr, nullptr, nullptr, ea4, w1f1, w2f1, c1b1, c1b2, se1, nullptr);
  node_sum_kernel<0><<<NN / 4, 256, 0, stream>>>(se1, start, x1);

  edge_conv_kernel<2><<<GRID_C, 256, 0, stream>>>(srow, scol, nullptr, nullptr,
      x1, nullptr, se1, nullptr, ea4, w1f2, w2f2, c2b1, c2b2, se2, nullptr);
  node_sum_kernel<0><<<NN / 4, 256, 0, stream>>>(se2, start, x2);

  edge_conv_kernel<3><<<GRID_C, 256, 0, stream>>>(srow, scol, nullptr, nullptr,
      x2, x1, se2, se1, nullptr, w1f3, w2f3, c3b1, c3b2, se3, nullptr);
  node_sum_kernel<0><<<NN / 4, 256, 0, stream>>>(se3, start, x3);

  edge_conv_kernel<4><<<GRID_C, 256, 0, stream>>>(srow, scol, perm, nullptr,
      x3, x2, se3, se2, nullptr, w1f4, w2f4, c4b1, c4b2, se1, out_e);
  node_sum_kernel<1><<<NN / 4, 256, 0, stream>>>(se1, start, x4);

  head_kernel<<<NN / 4, 256, 0, stream>>>(x4, mW1, mb1, mW2, mb2, out_x);
}

// Round 4
// 1094.954 us; speedup vs baseline: 1.2477x; 1.0272x over previous
//
#include <hip/hip_runtime.h>
#include <cstdint>
#include <cstddef>

// MPNN: 4 edge-conv layers + head MLP.  N=50000, E=800000, F=64.
// Round 7: compose ONLY verified pieces. Round-3 body (launch_bounds(256,2),
// VGPR 128, no spills) + round-5 LDS layout (48KB w1s + 5KB hbuf = 54272 B ->
// 3 blocks/CU for conv3/4; conv2 33.8KB -> 4 blocks/CU) + a 4-VGPR next-tile
// index prefetch (the only survivor of round-6's pipeline: cheap, no arrays).
// Rounds 4/5/6 all regressed via allocator spills (VGPR 64/84/128+scratch);
// this round adds zero register-pressure risk beyond +4 VGPRs.

#define NN 50000
#define NE 800000

typedef _Float16 f16;
typedef _Float16 f16x8 __attribute__((ext_vector_type(8)));
typedef _Float16 f16x4 __attribute__((ext_vector_type(4)));
typedef float    f32x4 __attribute__((ext_vector_type(4)));

// ---------------------------------------------------------------- sort build
__global__ void count_kernel(const int* __restrict__ eidx, int* __restrict__ cnt) {
  int i = blockIdx.x * 256 + threadIdx.x;
  if (i < NE) atomicAdd(&cnt[eidx[i]], 1);
}

__global__ void scan_a(const int* __restrict__ cnt, int* __restrict__ bsum) {
  __shared__ int sh[256];
  int i = blockIdx.x * 256 + threadIdx.x;
  sh[threadIdx.x] = (i < NN) ? cnt[i] : 0;
  __syncthreads();
  for (int off = 128; off > 0; off >>= 1) {
    if (threadIdx.x < off) sh[threadIdx.x] += sh[threadIdx.x + off];
    __syncthreads();
  }
  if (threadIdx.x == 0) bsum[blockIdx.x] = sh[0];
}

__global__ void scan_b(const int* __restrict__ bsum, int* __restrict__ boff, int nb) {
  __shared__ int sh[256];
  int t = threadIdx.x;
  int v = (t < nb) ? bsum[t] : 0;
  sh[t] = v; __syncthreads();
  for (int off = 1; off < 256; off <<= 1) {
    int x = (t >= off) ? sh[t - off] : 0;
    __syncthreads();
    sh[t] += x;
    __syncthreads();
  }
  if (t < nb) boff[t] = sh[t] - v;   // exclusive
}

__global__ void scan_c(const int* __restrict__ cnt, const int* __restrict__ boff,
                       int* __restrict__ start, int* __restrict__ cursor) {
  __shared__ int sh[256];
  int t = threadIdx.x;
  int i = blockIdx.x * 256 + t;
  int v = (i < NN) ? cnt[i] : 0;
  sh[t] = v; __syncthreads();
  for (int off = 1; off < 256; off <<= 1) {
    int x = (t >= off) ? sh[t - off] : 0;
    __syncthreads();
    sh[t] += x;
    __syncthreads();
  }
  if (i < NN) {
    int ex = boff[blockIdx.x] + sh[t] - v;
    start[i] = ex; cursor[i] = ex;
  }
  if (i == 0) start[NN] = NE;
}

__global__ void scatter_kernel(const int* __restrict__ eidx, const float* __restrict__ ea,
                               int* __restrict__ cursor,
                               int* __restrict__ srow, int* __restrict__ scol,
                               int* __restrict__ perm, f16* __restrict__ ea4) {
  int e = blockIdx.x * 256 + threadIdx.x;
  if (e >= NE) return;
  int r = eidx[e];
  int j = atomicAdd(&cursor[r], 1);
  srow[j] = r;
  scol[j] = eidx[NE + e];
  perm[j] = e;
  f16x4 v;
  v[0] = (f16)ea[3 * (size_t)e];
  v[1] = (f16)ea[3 * (size_t)e + 1];
  v[2] = (f16)ea[3 * (size_t)e + 2];
  v[3] = (f16)0.0f;
  *(f16x4*)&ea4[4 * (size_t)j] = v;
}

// ---------------------------------------------------------------- weight prep
// frag slot (ks,t,lane): dst[slot*8+j] = W[(ks*32+(lane>>4)*8+j)*64 + (t*16+(lane&15))]
__global__ void prep_kernel(const float* __restrict__ W1, int kreal1, int ksteps1,
                            const float* __restrict__ W2,
                            f16* __restrict__ w1f, f16* __restrict__ w2f) {
  int u = blockIdx.x * 256 + threadIdx.x;
  int total1 = ksteps1 * 256;
  const float* W; f16* dst; int kreal, slot;
  if (u < total1)            { W = W1; dst = w1f; kreal = kreal1; slot = u; }
  else if (u < total1 + 512) { W = W2; dst = w2f; kreal = 64;     slot = u - total1; }
  else return;
  int l = slot & 63, t = (slot >> 6) & 3, ks = slot >> 8;
  int n  = t * 16 + (l & 15);
  int kb = ks * 32 + ((l >> 4) * 8);
  f16x8 v;
#pragma unroll
  for (int j = 0; j < 8; ++j) {
    int k = kb + j;
    v[j] = (f16)((k < kreal) ? W[k * 64 + n] : 0.0f);
  }
  *(f16x8*)&dst[slot * 8] = v;
}

// ---------------------------------------------------------------- node segment sum
// one wave per node: sum raw f16 edge rows over [start[v], start[v+1]) -> relu(mean)
template<int F32OUT>
__global__ void node_sum_kernel(const f16* __restrict__ eout, const int* __restrict__ start,
                                void* __restrict__ xout) {
  int v = blockIdx.x * 4 + (threadIdx.x >> 6);
  int lane = threadIdx.x & 63;
  int g = lane >> 4, c4 = (lane & 15) * 4;
  int s0 = start[v], s1 = start[v + 1];
  f32x4 acc = (f32x4){0.f, 0.f, 0.f, 0.f};
  for (int i = s0 + g; i < s1; i += 4) {
    f16x4 h = *(const f16x4*)&eout[(size_t)i * 64 + c4];
#pragma unroll
    for (int q = 0; q < 4; ++q) acc[q] += (float)h[q];
  }
#pragma unroll
  for (int q = 0; q < 4; ++q) {
    acc[q] += __shfl_xor(acc[q], 16, 64);
    acc[q] += __shfl_xor(acc[q], 32, 64);
  }
  int cv = s1 - s0;
  float inv = 1.0f / (float)(cv > 0 ? cv : 1);
  if (g == 0) {
    if (F32OUT) {
      f32x4 o;
#pragma unroll
      for (int q = 0; q < 4; ++q) o[q] = fmaxf(acc[q] * inv, 0.0f);
      *(f32x4*)&((float*)xout)[(size_t)v * 64 + c4] = o;
    } else {
      f16x4 o;
#pragma unroll
      for (int q = 0; q < 4; ++q) o[q] = (f16)fmaxf(acc[q] * inv, 0.0f);
      *(f16x4*)&((f16*)xout)[(size_t)v * 64 + c4] = o;
    }
  }
}

// ---------------------------------------------------------------- edge conv
// Processes edges in SORTED order j. Writes eout[j] = RAW f16 edge output
// (relu applied by consumers). CONV==4 additionally scatters relu fp32 to
// out_e[perm[j]].
template<int CONV>
__global__ __launch_bounds__(256, 2) void edge_conv_kernel(
    const int* __restrict__ srow, const int* __restrict__ scol,
    const int* __restrict__ perm,
    const float* __restrict__ na,
    const f16* __restrict__ xA, const f16* __restrict__ xB,
    const f16* __restrict__ eA, const f16* __restrict__ eB,
    const f16* __restrict__ ea4,
    const f16* __restrict__ w1f, const f16* __restrict__ w2f,
    const float* __restrict__ b1, const float* __restrict__ b2,
    f16* __restrict__ eout, float* __restrict__ out_e)
{
  constexpr int KSTEPS = (CONV == 1) ? 1 : (CONV == 2 ? 7 : 12);

  __shared__ f16 w1s[KSTEPS * 2048];                  // all B-frags, 4KB per ks
  __shared__ __align__(16) f16 hbuf[4][16][40];       // per-wave 32-col xpose buf

  const int tid  = threadIdx.x;
  const int lane = tid & 63;
  const int wv   = tid >> 6;
  const int quad = lane >> 4;
  const int l15  = lane & 15;

  for (int u = tid; u < KSTEPS * 256; u += 256)
    *(f16x8*)&w1s[u * 8] = *(const f16x8*)&w1f[u * 8];

  float bb1[4], bb2[4];
#pragma unroll
  for (int t = 0; t < 4; ++t) { bb1[t] = b1[t * 16 + l15]; bb2[t] = b2[t * 16 + l15]; }

  f16x8 w2r[2][4];
#pragma unroll
  for (int kk = 0; kk < 2; ++kk)
#pragma unroll
    for (int t = 0; t < 4; ++t)
      w2r[kk][t] = *(const f16x8*)&w2f[((kk * 4 + t) * 64 + lane) * 8];

  __syncthreads();   // w1s visible; no further barriers

  constexpr int NTILE = NE / 32;          // wave-tiles of 32 edges
  const int gw = blockIdx.x * 4 + wv;
  const int stride = gridDim.x * 4;

  // ---- shared epilogue: hidden=relu(acc+b1) -> GEMM2 -> raw f16 row stores
  auto epilogue = [&](f32x4 (&acc)[2][4], int jb) {
#pragma unroll
    for (int s = 0; s < 2; ++s) {
      f32x4 a2[4];
#pragma unroll
      for (int t = 0; t < 4; ++t) a2[t] = (f32x4){0.f, 0.f, 0.f, 0.f};
#pragma unroll
      for (int kk = 0; kk < 2; ++kk) {
#pragma unroll
        for (int th = 0; th < 2; ++th) {
          const int t = kk * 2 + th;
#pragma unroll
          for (int r = 0; r < 4; ++r)
            hbuf[wv][quad * 4 + r][th * 16 + l15] = (f16)fmaxf(acc[s][t][r] + bb1[t], 0.0f);
        }
        f16x8 ah = *(const f16x8*)&hbuf[wv][l15][quad * 8];
#pragma unroll
        for (int t = 0; t < 4; ++t)
          a2[t] = __builtin_amdgcn_mfma_f32_16x16x32_f16(ah, w2r[kk][t], a2[t], 0, 0, 0);
      }

      const int j = jb + s * 16 + l15;
      f16x8 oh[2];
#pragma unroll
      for (int h = 0; h < 2; ++h) {
#pragma unroll
        for (int th = 0; th < 2; ++th) {
          const int t = h * 2 + th;
#pragma unroll
          for (int r = 0; r < 4; ++r)
            hbuf[wv][quad * 4 + r][th * 16 + l15] = (f16)(a2[t][r] + bb2[t]);
        }
        oh[h] = *(const f16x8*)&hbuf[wv][l15][quad * 8];
      }
      *(f16x8*)&eout[(size_t)j * 64 + quad * 8] = oh[0];
      *(f16x8*)&eout[(size_t)j * 64 + 32 + quad * 8] = oh[1];

      if constexpr (CONV == 4) {
#pragma unroll
        for (int r = 0; r < 4; ++r) {
          const int p = perm[jb + s * 16 + quad * 4 + r];
#pragma unroll
          for (int t = 0; t < 4; ++t)
            out_e[(size_t)p * 64 + t * 16 + l15] = fmaxf(a2[t][r] + bb2[t], 0.0f);
        }
      }
    }
  };

  if constexpr (CONV == 1) {
    for (int jt = gw; jt < NTILE; jt += stride) {
      const int jb = jt * 32;
      const int j0 = jb + l15, j1 = j0 + 16;
      const int r0 = srow[j0], r1 = srow[j1];
      const int c0 = scol[j0], c1 = scol[j1];
      f16x8 a0, a1;
#pragma unroll
      for (int j = 0; j < 8; ++j) { a0[j] = (f16)0.0f; a1[j] = (f16)0.0f; }
      f16x4 q0 = *(const f16x4*)&ea4[4 * (size_t)j0];
      f16x4 q1 = *(const f16x4*)&ea4[4 * (size_t)j1];
      if (quad == 0) {
        a0[0] = (f16)na[r0*3];  a0[1] = (f16)na[r0*3+1];  a0[2] = (f16)na[r0*3+2];
        a0[3] = (f16)na[c0*3];  a0[4] = (f16)na[c0*3+1];  a0[5] = (f16)na[c0*3+2];
        a0[6] = q0[0];          a0[7] = q0[1];
        a1[0] = (f16)na[r1*3];  a1[1] = (f16)na[r1*3+1];  a1[2] = (f16)na[r1*3+2];
        a1[3] = (f16)na[c1*3];  a1[4] = (f16)na[c1*3+1];  a1[5] = (f16)na[c1*3+2];
        a1[6] = q1[0];          a1[7] = q1[1];
      } else if (quad == 1) {
        a0[0] = q0[2];
        a1[0] = q1[2];
      }
      f32x4 acc[2][4];
#pragma unroll
      for (int s = 0; s < 2; ++s)
#pragma unroll
        for (int t = 0; t < 4; ++t) acc[s][t] = (f32x4){0.f, 0.f, 0.f, 0.f};
#pragma unroll
      for (int t = 0; t < 4; ++t) {
        f16x8 b = *(const f16x8*)&w1s[(t * 64 + lane) * 8];
        acc[0][t] = __builtin_amdgcn_mfma_f32_16x16x32_f16(a0, b, acc[0][t], 0, 0, 0);
        acc[1][t] = __builtin_amdgcn_mfma_f32_16x16x32_f16(a1, b, acc[1][t], 0, 0, 0);
      }
      epilogue(acc, jb);
    }
  } else {
    constexpr int NREG = (CONV == 2) ? 3 : 6;
    constexpr int ERCH = (CONV == 2) ? 2 : 4;   // chunks >= ERCH are e-prev (relu)

    int jt = gw;
    int pr0 = 0, pr1 = 0, pc0 = 0, pc1 = 0;     // current tile's indices
    if (jt < NTILE) {
      const int jb = jt * 32;
      pr0 = srow[jb + l15];  pr1 = srow[jb + 16 + l15];
      pc0 = scol[jb + l15];  pc1 = scol[jb + 16 + l15];
    }

    for (; jt < NTILE; jt += stride) {
      const int jb = jt * 32;
      const int j0 = jb + l15, j1 = j0 + 16;

      // prefetch NEXT tile's indices (4 VGPRs; hides idx->gather serial link)
      const int jn = jt + stride;
      int nr0 = 0, nr1 = 0, nc0 = 0, nc1 = 0;
      if (jn < NTILE) {
        const int njb = jn * 32;
        nr0 = srow[njb + l15];  nr1 = srow[njb + 16 + l15];
        nc0 = scol[njb + l15];  nc1 = scol[njb + 16 + l15];
      }

      const int r0 = pr0, r1 = pr1, c0 = pc0, c1 = pc1;
      const f16* p0[NREG]; const f16* p1[NREG];
      if constexpr (CONV == 2) {
        p0[0] = xA + (size_t)r0 * 64;  p1[0] = xA + (size_t)r1 * 64;
        p0[1] = xA + (size_t)c0 * 64;  p1[1] = xA + (size_t)c1 * 64;
        p0[2] = eA + (size_t)j0 * 64;  p1[2] = eA + (size_t)j1 * 64;
      } else {
        p0[0] = xA + (size_t)r0 * 64;  p1[0] = xA + (size_t)r1 * 64;
        p0[1] = xB + (size_t)r0 * 64;  p1[1] = xB + (size_t)r1 * 64;
        p0[2] = xA + (size_t)c0 * 64;  p1[2] = xA + (size_t)c1 * 64;
        p0[3] = xB + (size_t)c0 * 64;  p1[3] = xB + (size_t)c1 * 64;
        p0[4] = eA + (size_t)j0 * 64;  p1[4] = eA + (size_t)j1 * 64;
        p0[5] = eB + (size_t)j0 * 64;  p1[5] = eB + (size_t)j1 * 64;
      }

      f32x4 acc[2][4];
#pragma unroll
      for (int s = 0; s < 2; ++s)
#pragma unroll
        for (int t = 0; t < 4; ++t) acc[s][t] = (f32x4){0.f, 0.f, 0.f, 0.f};

#pragma unroll
      for (int ks = 0; ks < NREG * 2; ++ks) {
        const int c = ks >> 1, kk = ks & 1;
        f16x8 a0 = *(const f16x8*)(p0[c] + kk * 32 + quad * 8);
        f16x8 a1 = *(const f16x8*)(p1[c] + kk * 32 + quad * 8);
        if (c >= ERCH) {            // e-prev stored raw -> relu on load
#pragma unroll
          for (int j = 0; j < 8; ++j) {
            a0[j] = (a0[j] > (f16)0.0f) ? a0[j] : (f16)0.0f;
            a1[j] = (a1[j] > (f16)0.0f) ? a1[j] : (f16)0.0f;
          }
        }
#pragma unroll
        for (int t = 0; t < 4; ++t) {
          f16x8 b = *(const f16x8*)&w1s[((ks * 4 + t) * 64 + lane) * 8];
          acc[0][t] = __builtin_amdgcn_mfma_f32_16x16x32_f16(a0, b, acc[0][t], 0, 0, 0);
          acc[1][t] = __builtin_amdgcn_mfma_f32_16x16x32_f16(a1, b, acc[1][t], 0, 0, 0);
        }
      }
      if constexpr (CONV == 2) {    // tail ks 6: ea at cols 192..194
        f16x8 a0, a1;
#pragma unroll
        for (int j = 0; j < 8; ++j) { a0[j] = (f16)0.0f; a1[j] = (f16)0.0f; }
        f16x4 q0 = *(const f16x4*)&ea4[4 * (size_t)j0];
        f16x4 q1 = *(const f16x4*)&ea4[4 * (size_t)j1];
        if (quad == 0) {
          a0[0] = q0[0]; a0[1] = q0[1]; a0[2] = q0[2];
          a1[0] = q1[0]; a1[1] = q1[1]; a1[2] = q1[2];
        }
#pragma unroll
        for (int t = 0; t < 4; ++t) {
          f16x8 b = *(const f16x8*)&w1s[((6 * 4 + t) * 64 + lane) * 8];
          acc[0][t] = __builtin_amdgcn_mfma_f32_16x16x32_f16(a0, b, acc[0][t], 0, 0, 0);
          acc[1][t] = __builtin_amdgcn_mfma_f32_16x16x32_f16(a1, b, acc[1][t], 0, 0, 0);
        }
      }

      epilogue(acc, jb);

      pr0 = nr0; pr1 = nr1; pc0 = nc0; pc1 = nc1;
    }
  }
}

// ---------------------------------------------------------------- head MLP
__global__ void head_kernel(const float* __restrict__ x4,
                            const float* __restrict__ W1, const float* __restrict__ b1,
                            const float* __restrict__ W2, const float* __restrict__ b2,
                            float* __restrict__ out) {
  __shared__ float xs[4][64];
  __shared__ float hs[4][64];
  int tid = threadIdx.x;
  int i = tid >> 6, f = tid & 63;
  int nb = blockIdx.x * 4;
  xs[i][f] = x4[(size_t)(nb + i) * 64 + f];
  __syncthreads();
  float h = b1[f];
#pragma unroll
  for (int k = 0; k < 64; ++k) h += xs[i][k] * W1[k * 64 + f];
  hs[i][f] = fmaxf(h, 0.0f);
  __syncthreads();
  if (tid < 12) {
    int ii = tid / 3, j = tid % 3;
    float o = b2[j];
#pragma unroll
    for (int k = 0; k < 64; ++k) o += hs[ii][k] * W2[k * 3 + j];
    out[(size_t)(nb + ii) * 3 + j] = o;
  }
}

// ---------------------------------------------------------------- launch
extern "C" void kernel_launch(void* const* d_in, const int* in_sizes, int n_in,
                              void* d_out, int out_size, void* d_ws, size_t ws_size,
                              hipStream_t stream) {
  const float* na   = (const float*)d_in[0];
  const float* ea   = (const float*)d_in[1];
  const int*   eidx = (const int*)d_in[2];
  const float* c1W1 = (const float*)d_in[3];
  const float* c1b1 = (const float*)d_in[4];
  const float* c1W2 = (const float*)d_in[5];
  const float* c1b2 = (const float*)d_in[6];
  const float* c2W1 = (const float*)d_in[7];
  const float* c2b1 = (const float*)d_in[8];
  const float* c2W2 = (const float*)d_in[9];
  const float* c2b2 = (const float*)d_in[10];
  const float* c3W1 = (const float*)d_in[11];
  const float* c3b1 = (const float*)d_in[12];
  const float* c3W2 = (const float*)d_in[13];
  const float* c3b2 = (const float*)d_in[14];
  const float* c4W1 = (const float*)d_in[15];
  const float* c4b1 = (const float*)d_in[16];
  const float* c4W2 = (const float*)d_in[17];
  const float* c4b2 = (const float*)d_in[18];
  const float* mW1  = (const float*)d_in[19];
  const float* mb1  = (const float*)d_in[20];
  const float* mW2  = (const float*)d_in[21];
  const float* mb2  = (const float*)d_in[22];

  char* ws = (char*)d_ws;
  size_t off = 0;
  auto alloc = [&](size_t b) -> void* {
    void* p = ws + off;
    off += (b + 255) & ~(size_t)255;
    return p;
  };
  int*   cnt    = (int*)alloc((size_t)NN * 4);
  int*   bsum   = (int*)alloc(256 * 4);
  int*   boff   = (int*)alloc(256 * 4);
  int*   start  = (int*)alloc((size_t)(NN + 1) * 4);
  int*   cursor = (int*)alloc((size_t)NN * 4);
  int*   srow   = (int*)alloc((size_t)NE * 4);
  int*   scol   = (int*)alloc((size_t)NE * 4);
  int*   perm   = (int*)alloc((size_t)NE * 4);
  f16*   ea4    = (f16*)alloc((size_t)NE * 4 * 2);
  f16*   x1     = (f16*)alloc((size_t)NN * 64 * 2);
  f16*   x2     = (f16*)alloc((size_t)NN * 64 * 2);
  f16*   x3     = (f16*)alloc((size_t)NN * 64 * 2);
  float* x4     = (float*)alloc((size_t)NN * 64 * 4);
  f16*   se1    = (f16*)alloc((size_t)NE * 64 * 2);   // also reused as e4 raw
  f16*   se2    = (f16*)alloc((size_t)NE * 64 * 2);
  f16*   se3    = (f16*)alloc((size_t)NE * 64 * 2);
  f16*   w1f1 = (f16*)alloc((size_t) 1 * 2048 * 2);
  f16*   w1f2 = (f16*)alloc((size_t) 7 * 2048 * 2);
  f16*   w1f3 = (f16*)alloc((size_t)12 * 2048 * 2);
  f16*   w1f4 = (f16*)alloc((size_t)12 * 2048 * 2);
  f16*   w2f1 = (f16*)alloc((size_t)4096 * 2);
  f16*   w2f2 = (f16*)alloc((size_t)4096 * 2);
  f16*   w2f3 = (f16*)alloc((size_t)4096 * 2);
  f16*   w2f4 = (f16*)alloc((size_t)4096 * 2);

  float* out_x = (float*)d_out;
  float* out_e = out_x + (size_t)NN * 3;

  constexpr int NBS = (NN + 255) / 256;   // 196
  constexpr int GRID_C12 = 1024;          // conv1/2: 4 blocks/CU (LDS 33.8KB)
  constexpr int GRID_C34 = 768;           // conv3/4: 3 blocks/CU (LDS 54272 B)

  hipMemsetAsync(cnt, 0, (size_t)NN * 4, stream);
  count_kernel<<<NE / 256, 256, 0, stream>>>(eidx, cnt);
  scan_a<<<NBS, 256, 0, stream>>>(cnt, bsum);
  scan_b<<<1, 256, 0, stream>>>(bsum, boff, NBS);
  scan_c<<<NBS, 256, 0, stream>>>(cnt, boff, start, cursor);
  scatter_kernel<<<NE / 256, 256, 0, stream>>>(eidx, ea, cursor, srow, scol, perm, ea4);

  prep_kernel<<< 3, 256, 0, stream>>>(c1W1,   9,  1, c1W2, w1f1, w2f1);
  prep_kernel<<< 9, 256, 0, stream>>>(c2W1, 195,  7, c2W2, w1f2, w2f2);
  prep_kernel<<<14, 256, 0, stream>>>(c3W1, 384, 12, c3W2, w1f3, w2f3);
  prep_kernel<<<14, 256, 0, stream>>>(c4W1, 384, 12, c4W2, w1f4, w2f4);

  edge_conv_kernel<1><<<GRID_C12, 256, 0, stream>>>(srow, scol, nullptr, na,
      nullptr, nullptr, nullptr, nullptr, ea4, w1f1, w2f1, c1b1, c1b2, se1, nullptr);
  node_sum_kernel<0><<<NN / 4, 256, 0, stream>>>(se1, start, x1);

  edge_conv_kernel<2><<<GRID_C12, 256, 0, stream>>>(srow, scol, nullptr, nullptr,
      x1, nullptr, se1, nullptr, ea4, w1f2, w2f2, c2b1, c2b2, se2, nullptr);
  node_sum_kernel<0><<<NN / 4, 256, 0, stream>>>(se2, start, x2);

  edge_conv_kernel<3><<<GRID_C34, 256, 0, stream>>>(srow, scol, nullptr, nullptr,
      x2, x1, se2, se1, nullptr, w1f3, w2f3, c3b1, c3b2, se3, nullptr);
  node_sum_kernel<0><<<NN / 4, 256, 0, stream>>>(se3, start, x3);

  edge_conv_kernel<4><<<GRID_C34, 256, 0, stream>>>(srow, scol, perm, nullptr,
      x3, x2, se3, se2, nullptr, w1f4, w2f4, c4b1, c4b2, se1, out_e);
  node_sum_kernel<1><<<NN / 4, 256, 0, stream>>>(se1, start, x4);

  head_kernel<<<NN / 4, 256, 0, stream>>>(x4, mW1, mb1, mW2, mb2, out_x);
}

// Round 5
// 1000.377 us; speedup vs baseline: 1.3657x; 1.0945x over previous
//
#include <hip/hip_runtime.h>
#include <cstdint>
#include <cstddef>

// MPNN: 4 edge-conv layers + head MLP.  N=50000, E=800000, F=64.
// Round 8: TLP via block shape. Rounds 5/7 proved LDS 54272 -> only 2 blocks/CU
// (granularity cliff just above 160K/3). Instead of shaving LDS: 512-thread
// blocks (8 waves) with the SAME per-wave body. LDS/block = 48KB w1s +
// hbuf[8] 10KB = 59392 -> 2 blocks/CU = 16 waves/CU (vs 8), 118KB/160KB used,
// no granule risk. VGPR 128 x 16 waves = 2048 = exactly the CU pool (m69 tier).
// Grid 512: exactly 2 resident/CU, one pass, no tail. Memory patterns,
// register pressure, per-wave code: identical to the verified round-3 body.

#define NN 50000
#define NE 800000

typedef _Float16 f16;
typedef _Float16 f16x8 __attribute__((ext_vector_type(8)));
typedef _Float16 f16x4 __attribute__((ext_vector_type(4)));
typedef float    f32x4 __attribute__((ext_vector_type(4)));

// ---------------------------------------------------------------- sort build
__global__ void count_kernel(const int* __restrict__ eidx, int* __restrict__ cnt) {
  int i = blockIdx.x * 256 + threadIdx.x;
  if (i < NE) atomicAdd(&cnt[eidx[i]], 1);
}

__global__ void scan_a(const int* __restrict__ cnt, int* __restrict__ bsum) {
  __shared__ int sh[256];
  int i = blockIdx.x * 256 + threadIdx.x;
  sh[threadIdx.x] = (i < NN) ? cnt[i] : 0;
  __syncthreads();
  for (int off = 128; off > 0; off >>= 1) {
    if (threadIdx.x < off) sh[threadIdx.x] += sh[threadIdx.x + off];
    __syncthreads();
  }
  if (threadIdx.x == 0) bsum[blockIdx.x] = sh[0];
}

__global__ void scan_b(const int* __restrict__ bsum, int* __restrict__ boff, int nb) {
  __shared__ int sh[256];
  int t = threadIdx.x;
  int v = (t < nb) ? bsum[t] : 0;
  sh[t] = v; __syncthreads();
  for (int off = 1; off < 256; off <<= 1) {
    int x = (t >= off) ? sh[t - off] : 0;
    __syncthreads();
    sh[t] += x;
    __syncthreads();
  }
  if (t < nb) boff[t] = sh[t] - v;   // exclusive
}

__global__ void scan_c(const int* __restrict__ cnt, const int* __restrict__ boff,
                       int* __restrict__ start, int* __restrict__ cursor) {
  __shared__ int sh[256];
  int t = threadIdx.x;
  int i = blockIdx.x * 256 + t;
  int v = (i < NN) ? cnt[i] : 0;
  sh[t] = v; __syncthreads();
  for (int off = 1; off < 256; off <<= 1) {
    int x = (t >= off) ? sh[t - off] : 0;
    __syncthreads();
    sh[t] += x;
    __syncthreads();
  }
  if (i < NN) {
    int ex = boff[blockIdx.x] + sh[t] - v;
    start[i] = ex; cursor[i] = ex;
  }
  if (i == 0) start[NN] = NE;
}

__global__ void scatter_kernel(const int* __restrict__ eidx, const float* __restrict__ ea,
                               int* __restrict__ cursor,
                               int* __restrict__ srow, int* __restrict__ scol,
                               int* __restrict__ perm, f16* __restrict__ ea4) {
  int e = blockIdx.x * 256 + threadIdx.x;
  if (e >= NE) return;
  int r = eidx[e];
  int j = atomicAdd(&cursor[r], 1);
  srow[j] = r;
  scol[j] = eidx[NE + e];
  perm[j] = e;
  f16x4 v;
  v[0] = (f16)ea[3 * (size_t)e];
  v[1] = (f16)ea[3 * (size_t)e + 1];
  v[2] = (f16)ea[3 * (size_t)e + 2];
  v[3] = (f16)0.0f;
  *(f16x4*)&ea4[4 * (size_t)j] = v;
}

// ---------------------------------------------------------------- weight prep
// frag slot (ks,t,lane): dst[slot*8+j] = W[(ks*32+(lane>>4)*8+j)*64 + (t*16+(lane&15))]
__global__ void prep_kernel(const float* __restrict__ W1, int kreal1, int ksteps1,
                            const float* __restrict__ W2,
                            f16* __restrict__ w1f, f16* __restrict__ w2f) {
  int u = blockIdx.x * 256 + threadIdx.x;
  int total1 = ksteps1 * 256;
  const float* W; f16* dst; int kreal, slot;
  if (u < total1)            { W = W1; dst = w1f; kreal = kreal1; slot = u; }
  else if (u < total1 + 512) { W = W2; dst = w2f; kreal = 64;     slot = u - total1; }
  else return;
  int l = slot & 63, t = (slot >> 6) & 3, ks = slot >> 8;
  int n  = t * 16 + (l & 15);
  int kb = ks * 32 + ((l >> 4) * 8);
  f16x8 v;
#pragma unroll
  for (int j = 0; j < 8; ++j) {
    int k = kb + j;
    v[j] = (f16)((k < kreal) ? W[k * 64 + n] : 0.0f);
  }
  *(f16x8*)&dst[slot * 8] = v;
}

// ---------------------------------------------------------------- node segment sum
// one wave per node: sum raw f16 edge rows over [start[v], start[v+1]) -> relu(mean)
template<int F32OUT>
__global__ void node_sum_kernel(const f16* __restrict__ eout, const int* __restrict__ start,
                                void* __restrict__ xout) {
  int v = blockIdx.x * 4 + (threadIdx.x >> 6);
  int lane = threadIdx.x & 63;
  int g = lane >> 4, c4 = (lane & 15) * 4;
  int s0 = start[v], s1 = start[v + 1];
  f32x4 acc = (f32x4){0.f, 0.f, 0.f, 0.f};
  for (int i = s0 + g; i < s1; i += 4) {
    f16x4 h = *(const f16x4*)&eout[(size_t)i * 64 + c4];
#pragma unroll
    for (int q = 0; q < 4; ++q) acc[q] += (float)h[q];
  }
#pragma unroll
  for (int q = 0; q < 4; ++q) {
    acc[q] += __shfl_xor(acc[q], 16, 64);
    acc[q] += __shfl_xor(acc[q], 32, 64);
  }
  int cv = s1 - s0;
  float inv = 1.0f / (float)(cv > 0 ? cv : 1);
  if (g == 0) {
    if (F32OUT) {
      f32x4 o;
#pragma unroll
      for (int q = 0; q < 4; ++q) o[q] = fmaxf(acc[q] * inv, 0.0f);
      *(f32x4*)&((float*)xout)[(size_t)v * 64 + c4] = o;
    } else {
      f16x4 o;
#pragma unroll
      for (int q = 0; q < 4; ++q) o[q] = (f16)fmaxf(acc[q] * inv, 0.0f);
      *(f16x4*)&((f16*)xout)[(size_t)v * 64 + c4] = o;
    }
  }
}

// ---------------------------------------------------------------- edge conv
// 512 threads = 8 waves per block; each wave processes tiles of 32 edges in
// SORTED order j. Writes eout[j] = RAW f16 edge output (relu applied by
// consumers). CONV==4 additionally scatters relu fp32 to out_e[perm[j]].
template<int CONV>
__global__ __launch_bounds__(512, 2) void edge_conv_kernel(
    const int* __restrict__ srow, const int* __restrict__ scol,
    const int* __restrict__ perm,
    const float* __restrict__ na,
    const f16* __restrict__ xA, const f16* __restrict__ xB,
    const f16* __restrict__ eA, const f16* __restrict__ eB,
    const f16* __restrict__ ea4,
    const f16* __restrict__ w1f, const f16* __restrict__ w2f,
    const float* __restrict__ b1, const float* __restrict__ b2,
    f16* __restrict__ eout, float* __restrict__ out_e)
{
  constexpr int KSTEPS = (CONV == 1) ? 1 : (CONV == 2 ? 7 : 12);

  __shared__ f16 w1s[KSTEPS * 2048];                  // all B-frags, 4KB per ks
  __shared__ __align__(16) f16 hbuf[8][16][40];       // per-wave 32-col xpose buf

  const int tid  = threadIdx.x;
  const int lane = tid & 63;
  const int wv   = tid >> 6;                          // 0..7
  const int quad = lane >> 4;
  const int l15  = lane & 15;

  for (int u = tid; u < KSTEPS * 256; u += 512)
    *(f16x8*)&w1s[u * 8] = *(const f16x8*)&w1f[u * 8];

  float bb1[4], bb2[4];
#pragma unroll
  for (int t = 0; t < 4; ++t) { bb1[t] = b1[t * 16 + l15]; bb2[t] = b2[t * 16 + l15]; }

  f16x8 w2r[2][4];
#pragma unroll
  for (int kk = 0; kk < 2; ++kk)
#pragma unroll
    for (int t = 0; t < 4; ++t)
      w2r[kk][t] = *(const f16x8*)&w2f[((kk * 4 + t) * 64 + lane) * 8];

  __syncthreads();   // w1s visible; no further barriers

  constexpr int NTILE = NE / 32;          // wave-tiles of 32 edges
  const int gw = blockIdx.x * 8 + wv;
  const int stride = gridDim.x * 8;

  // ---- shared epilogue: hidden=relu(acc+b1) -> GEMM2 -> raw f16 row stores
  auto epilogue = [&](f32x4 (&acc)[2][4], int jb) {
#pragma unroll
    for (int s = 0; s < 2; ++s) {
      f32x4 a2[4];
#pragma unroll
      for (int t = 0; t < 4; ++t) a2[t] = (f32x4){0.f, 0.f, 0.f, 0.f};
#pragma unroll
      for (int kk = 0; kk < 2; ++kk) {
#pragma unroll
        for (int th = 0; th < 2; ++th) {
          const int t = kk * 2 + th;
#pragma unroll
          for (int r = 0; r < 4; ++r)
            hbuf[wv][quad * 4 + r][th * 16 + l15] = (f16)fmaxf(acc[s][t][r] + bb1[t], 0.0f);
        }
        f16x8 ah = *(const f16x8*)&hbuf[wv][l15][quad * 8];
#pragma unroll
        for (int t = 0; t < 4; ++t)
          a2[t] = __builtin_amdgcn_mfma_f32_16x16x32_f16(ah, w2r[kk][t], a2[t], 0, 0, 0);
      }

      const int j = jb + s * 16 + l15;
      f16x8 oh[2];
#pragma unroll
      for (int h = 0; h < 2; ++h) {
#pragma unroll
        for (int th = 0; th < 2; ++th) {
          const int t = h * 2 + th;
#pragma unroll
          for (int r = 0; r < 4; ++r)
            hbuf[wv][quad * 4 + r][th * 16 + l15] = (f16)(a2[t][r] + bb2[t]);
        }
        oh[h] = *(const f16x8*)&hbuf[wv][l15][quad * 8];
      }
      *(f16x8*)&eout[(size_t)j * 64 + quad * 8] = oh[0];
      *(f16x8*)&eout[(size_t)j * 64 + 32 + quad * 8] = oh[1];

      if constexpr (CONV == 4) {
#pragma unroll
        for (int r = 0; r < 4; ++r) {
          const int p = perm[jb + s * 16 + quad * 4 + r];
#pragma unroll
          for (int t = 0; t < 4; ++t)
            out_e[(size_t)p * 64 + t * 16 + l15] = fmaxf(a2[t][r] + bb2[t], 0.0f);
        }
      }
    }
  };

  if constexpr (CONV == 1) {
    for (int jt = gw; jt < NTILE; jt += stride) {
      const int jb = jt * 32;
      const int j0 = jb + l15, j1 = j0 + 16;
      const int r0 = srow[j0], r1 = srow[j1];
      const int c0 = scol[j0], c1 = scol[j1];
      f16x8 a0, a1;
#pragma unroll
      for (int j = 0; j < 8; ++j) { a0[j] = (f16)0.0f; a1[j] = (f16)0.0f; }
      f16x4 q0 = *(const f16x4*)&ea4[4 * (size_t)j0];
      f16x4 q1 = *(const f16x4*)&ea4[4 * (size_t)j1];
      if (quad == 0) {
        a0[0] = (f16)na[r0*3];  a0[1] = (f16)na[r0*3+1];  a0[2] = (f16)na[r0*3+2];
        a0[3] = (f16)na[c0*3];  a0[4] = (f16)na[c0*3+1];  a0[5] = (f16)na[c0*3+2];
        a0[6] = q0[0];          a0[7] = q0[1];
        a1[0] = (f16)na[r1*3];  a1[1] = (f16)na[r1*3+1];  a1[2] = (f16)na[r1*3+2];
        a1[3] = (f16)na[c1*3];  a1[4] = (f16)na[c1*3+1];  a1[5] = (f16)na[c1*3+2];
        a1[6] = q1[0];          a1[7] = q1[1];
      } else if (quad == 1) {
        a0[0] = q0[2];
        a1[0] = q1[2];
      }
      f32x4 acc[2][4];
#pragma unroll
      for (int s = 0; s < 2; ++s)
#pragma unroll
        for (int t = 0; t < 4; ++t) acc[s][t] = (f32x4){0.f, 0.f, 0.f, 0.f};
#pragma unroll
      for (int t = 0; t < 4; ++t) {
        f16x8 b = *(const f16x8*)&w1s[(t * 64 + lane) * 8];
        acc[0][t] = __builtin_amdgcn_mfma_f32_16x16x32_f16(a0, b, acc[0][t], 0, 0, 0);
        acc[1][t] = __builtin_amdgcn_mfma_f32_16x16x32_f16(a1, b, acc[1][t], 0, 0, 0);
      }
      epilogue(acc, jb);
    }
  } else {
    constexpr int NREG = (CONV == 2) ? 3 : 6;
    constexpr int ERCH = (CONV == 2) ? 2 : 4;   // chunks >= ERCH are e-prev (relu)

    int jt = gw;
    int pr0 = 0, pr1 = 0, pc0 = 0, pc1 = 0;     // current tile's indices
    if (jt < NTILE) {
      const int jb = jt * 32;
      pr0 = srow[jb + l15];  pr1 = srow[jb + 16 + l15];
      pc0 = scol[jb + l15];  pc1 = scol[jb + 16 + l15];
    }

    for (; jt < NTILE; jt += stride) {
      const int jb = jt * 32;
      const int j0 = jb + l15, j1 = j0 + 16;

      // prefetch NEXT tile's indices (4 VGPRs; hides idx->gather serial link)
      const int jn = jt + stride;
      int nr0 = 0, nr1 = 0, nc0 = 0, nc1 = 0;
      if (jn < NTILE) {
        const int njb = jn * 32;
        nr0 = srow[njb + l15];  nr1 = srow[njb + 16 + l15];
        nc0 = scol[njb + l15];  nc1 = scol[njb + 16 + l15];
      }

      const int r0 = pr0, r1 = pr1, c0 = pc0, c1 = pc1;
      const f16* p0[NREG]; const f16* p1[NREG];
      if constexpr (CONV == 2) {
        p0[0] = xA + (size_t)r0 * 64;  p1[0] = xA + (size_t)r1 * 64;
        p0[1] = xA + (size_t)c0 * 64;  p1[1] = xA + (size_t)c1 * 64;
        p0[2] = eA + (size_t)j0 * 64;  p1[2] = eA + (size_t)j1 * 64;
      } else {
        p0[0] = xA + (size_t)r0 * 64;  p1[0] = xA + (size_t)r1 * 64;
        p0[1] = xB + (size_t)r0 * 64;  p1[1] = xB + (size_t)r1 * 64;
        p0[2] = xA + (size_t)c0 * 64;  p1[2] = xA + (size_t)c1 * 64;
        p0[3] = xB + (size_t)c0 * 64;  p1[3] = xB + (size_t)c1 * 64;
        p0[4] = eA + (size_t)j0 * 64;  p1[4] = eA + (size_t)j1 * 64;
        p0[5] = eB + (size_t)j0 * 64;  p1[5] = eB + (size_t)j1 * 64;
      }

      f32x4 acc[2][4];
#pragma unroll
      for (int s = 0; s < 2; ++s)
#pragma unroll
        for (int t = 0; t < 4; ++t) acc[s][t] = (f32x4){0.f, 0.f, 0.f, 0.f};

#pragma unroll
      for (int ks = 0; ks < NREG * 2; ++ks) {
        const int c = ks >> 1, kk = ks & 1;
        f16x8 a0 = *(const f16x8*)(p0[c] + kk * 32 + quad * 8);
        f16x8 a1 = *(const f16x8*)(p1[c] + kk * 32 + quad * 8);
        if (c >= ERCH) {            // e-prev stored raw -> relu on load
#pragma unroll
          for (int j = 0; j < 8; ++j) {
            a0[j] = (a0[j] > (f16)0.0f) ? a0[j] : (f16)0.0f;
            a1[j] = (a1[j] > (f16)0.0f) ? a1[j] : (f16)0.0f;
          }
        }
#pragma unroll
        for (int t = 0; t < 4; ++t) {
          f16x8 b = *(const f16x8*)&w1s[((ks * 4 + t) * 64 + lane) * 8];
          acc[0][t] = __builtin_amdgcn_mfma_f32_16x16x32_f16(a0, b, acc[0][t], 0, 0, 0);
          acc[1][t] = __builtin_amdgcn_mfma_f32_16x16x32_f16(a1, b, acc[1][t], 0, 0, 0);
        }
      }
      if constexpr (CONV == 2) {    // tail ks 6: ea at cols 192..194
        f16x8 a0, a1;
#pragma unroll
        for (int j = 0; j < 8; ++j) { a0[j] = (f16)0.0f; a1[j] = (f16)0.0f; }
        f16x4 q0 = *(const f16x4*)&ea4[4 * (size_t)j0];
        f16x4 q1 = *(const f16x4*)&ea4[4 * (size_t)j1];
        if (quad == 0) {
          a0[0] = q0[0]; a0[1] = q0[1]; a0[2] = q0[2];
          a1[0] = q1[0]; a1[1] = q1[1]; a1[2] = q1[2];
        }
#pragma unroll
        for (int t = 0; t < 4; ++t) {
          f16x8 b = *(const f16x8*)&w1s[((6 * 4 + t) * 64 + lane) * 8];
          acc[0][t] = __builtin_amdgcn_mfma_f32_16x16x32_f16(a0, b, acc[0][t], 0, 0, 0);
          acc[1][t] = __builtin_amdgcn_mfma_f32_16x16x32_f16(a1, b, acc[1][t], 0, 0, 0);
        }
      }

      epilogue(acc, jb);

      pr0 = nr0; pr1 = nr1; pc0 = nc0; pc1 = nc1;
    }
  }
}

// ---------------------------------------------------------------- head MLP
__global__ void head_kernel(const float* __restrict__ x4,
                            const float* __restrict__ W1, const float* __restrict__ b1,
                            const float* __restrict__ W2, const float* __restrict__ b2,
                            float* __restrict__ out) {
  __shared__ float xs[4][64];
  __shared__ float hs[4][64];
  int tid = threadIdx.x;
  int i = tid >> 6, f = tid & 63;
  int nb = blockIdx.x * 4;
  xs[i][f] = x4[(size_t)(nb + i) * 64 + f];
  __syncthreads();
  float h = b1[f];
#pragma unroll
  for (int k = 0; k < 64; ++k) h += xs[i][k] * W1[k * 64 + f];
  hs[i][f] = fmaxf(h, 0.0f);
  __syncthreads();
  if (tid < 12) {
    int ii = tid / 3, j = tid % 3;
    float o = b2[j];
#pragma unroll
    for (int k = 0; k < 64; ++k) o += hs[ii][k] * W2[k * 3 + j];
    out[(size_t)(nb + ii) * 3 + j] = o;
  }
}

// ---------------------------------------------------------------- launch
extern "C" void kernel_launch(void* const* d_in, const int* in_sizes, int n_in,
                              void* d_out, int out_size, void* d_ws, size_t ws_size,
                              hipStream_t stream) {
  const float* na   = (const float*)d_in[0];
  const float* ea   = (const float*)d_in[1];
  const int*   eidx = (const int*)d_in[2];
  const float* c1W1 = (const float*)d_in[3];
  const float* c1b1 = (const float*)d_in[4];
  const float* c1W2 = (const float*)d_in[5];
  const float* c1b2 = (const float*)d_in[6];
  const float* c2W1 = (const float*)d_in[7];
  const float* c2b1 = (const float*)d_in[8];
  const float* c2W2 = (const float*)d_in[9];
  const float* c2b2 = (const float*)d_in[10];
  const float* c3W1 = (const float*)d_in[11];
  const float* c3b1 = (const float*)d_in[12];
  const float* c3W2 = (const float*)d_in[13];
  const float* c3b2 = (const float*)d_in[14];
  const float* c4W1 = (const float*)d_in[15];
  const float* c4b1 = (const float*)d_in[16];
  const float* c4W2 = (const float*)d_in[17];
  const float* c4b2 = (const float*)d_in[18];
  const float* mW1  = (const float*)d_in[19];
  const float* mb1  = (const float*)d_in[20];
  const float* mW2  = (const float*)d_in[21];
  const float* mb2  = (const float*)d_in[22];

  char* ws = (char*)d_ws;
  size_t off = 0;
  auto alloc = [&](size_t b) -> void* {
    void* p = ws + off;
    off += (b + 255) & ~(size_t)255;
    return p;
  };
  int*   cnt    = (int*)alloc((size_t)NN * 4);
  int*   bsum   = (int*)alloc(256 * 4);
  int*   boff   = (int*)alloc(256 * 4);
  int*   start  = (int*)alloc((size_t)(NN + 1) * 4);
  int*   cursor = (int*)alloc((size_t)NN * 4);
  int*   srow   = (int*)alloc((size_t)NE * 4);
  int*   scol   = (int*)alloc((size_t)NE * 4);
  int*   perm   = (int*)alloc((size_t)NE * 4);
  f16*   ea4    = (f16*)alloc((size_t)NE * 4 * 2);
  f16*   x1     = (f16*)alloc((size_t)NN * 64 * 2);
  f16*   x2     = (f16*)alloc((size_t)NN * 64 * 2);
  f16*   x3     = (f16*)alloc((size_t)NN * 64 * 2);
  float* x4     = (float*)alloc((size_t)NN * 64 * 4);
  f16*   se1    = (f16*)alloc((size_t)NE * 64 * 2);   // also reused as e4 raw
  f16*   se2    = (f16*)alloc((size_t)NE * 64 * 2);
  f16*   se3    = (f16*)alloc((size_t)NE * 64 * 2);
  f16*   w1f1 = (f16*)alloc((size_t) 1 * 2048 * 2);
  f16*   w1f2 = (f16*)alloc((size_t) 7 * 2048 * 2);
  f16*   w1f3 = (f16*)alloc((size_t)12 * 2048 * 2);
  f16*   w1f4 = (f16*)alloc((size_t)12 * 2048 * 2);
  f16*   w2f1 = (f16*)alloc((size_t)4096 * 2);
  f16*   w2f2 = (f16*)alloc((size_t)4096 * 2);
  f16*   w2f3 = (f16*)alloc((size_t)4096 * 2);
  f16*   w2f4 = (f16*)alloc((size_t)4096 * 2);

  float* out_x = (float*)d_out;
  float* out_e = out_x + (size_t)NN * 3;

  constexpr int NBS = (NN + 255) / 256;   // 196
  constexpr int GRID_EC = 512;            // 512-thread blocks, 2 resident/CU

  hipMemsetAsync(cnt, 0, (size_t)NN * 4, stream);
  count_kernel<<<NE / 256, 256, 0, stream>>>(eidx, cnt);
  scan_a<<<NBS, 256, 0, stream>>>(cnt, bsum);
  scan_b<<<1, 256, 0, stream>>>(bsum, boff, NBS);
  scan_c<<<NBS, 256, 0, stream>>>(cnt, boff, start, cursor);
  scatter_kernel<<<NE / 256, 256, 0, stream>>>(eidx, ea, cursor, srow, scol, perm, ea4);

  prep_kernel<<< 3, 256, 0, stream>>>(c1W1,   9,  1, c1W2, w1f1, w2f1);
  prep_kernel<<< 9, 256, 0, stream>>>(c2W1, 195,  7, c2W2, w1f2, w2f2);
  prep_kernel<<<14, 256, 0, stream>>>(c3W1, 384, 12, c3W2, w1f3, w2f3);
  prep_kernel<<<14, 256, 0, stream>>>(c4W1, 384, 12, c4W2, w1f4, w2f4);

  edge_conv_kernel<1><<<GRID_EC, 512, 0, stream>>>(srow, scol, nullptr, na,
      nullptr, nullptr, nullptr, nullptr, ea4, w1f1, w2f1, c1b1, c1b2, se1, nullptr);
  node_sum_kernel<0><<<NN / 4, 256, 0, stream>>>(se1, start, x1);

  edge_conv_kernel<2><<<GRID_EC, 512, 0, stream>>>(srow, scol, nullptr, nullptr,
      x1, nullptr, se1, nullptr, ea4, w1f2, w2f2, c2b1, c2b2, se2, nullptr);
  node_sum_kernel<0><<<NN / 4, 256, 0, stream>>>(se2, start, x2);

  edge_conv_kernel<3><<<GRID_EC, 512, 0, stream>>>(srow, scol, nullptr, nullptr,
      x2, x1, se2, se1, nullptr, w1f3, w2f3, c3b1, c3b2, se3, nullptr);
  node_sum_kernel<0><<<NN / 4, 256, 0, stream>>>(se3, start, x3);

  edge_conv_kernel<4><<<GRID_EC, 512, 0, stream>>>(srow, scol, perm, nullptr,
      x3, x2, se3, se2, nullptr, w1f4, w2f4, c4b1, c4b2, se1, out_e);
  node_sum_kernel<1><<<NN / 4, 256, 0, stream>>>(se1, start, x4);

  head_kernel<<<NN / 4, 256, 0, stream>>>(x4, mW1, mb1, mW2, mb2, out_x);
}

// Round 6
// 876.948 us; speedup vs baseline: 1.5579x; 1.1407x over previous
//
#include <hip/hip_runtime.h>
#include <cstdint>
#include <cstddef>

// MPNN: 4 edge-conv layers + head MLP.  N=50000, E=800000, F=64.
// Round 9: algebraic gather reduction. Rounds 3/8 proved throughput is
// independent of wave count (8 vs 16 waves/CU: 222 vs 240us) -> random-gather
// service rate is the wall, not latency hiding. Fix: precompute per-node
// projections f[n]=x@W1[0:128], g[n]=x@W1[128:256] (node_proj kernel, dense,
// trivial); edge conv3/4 then needs ONE random row g[c] per edge instead of
// two (xA[c],xB[c]), plus f[r] (L2-local). f/g enter the accumulator via
// identity-weight K-chunks (prep writes I-blocks into the frag buffer).
// KSTEPS 12->8, w1s 48KB->32KB -> LDS 37888 -> 4 blocks/CU possible.

#define NN 50000
#define NE 800000

typedef _Float16 f16;
typedef _Float16 f16x8 __attribute__((ext_vector_type(8)));
typedef _Float16 f16x4 __attribute__((ext_vector_type(4)));
typedef float    f32x4 __attribute__((ext_vector_type(4)));

// ---------------------------------------------------------------- sort build
__global__ void count_kernel(const int* __restrict__ eidx, int* __restrict__ cnt) {
  int i = blockIdx.x * 256 + threadIdx.x;
  if (i < NE) atomicAdd(&cnt[eidx[i]], 1);
}

__global__ void scan_a(const int* __restrict__ cnt, int* __restrict__ bsum) {
  __shared__ int sh[256];
  int i = blockIdx.x * 256 + threadIdx.x;
  sh[threadIdx.x] = (i < NN) ? cnt[i] : 0;
  __syncthreads();
  for (int off = 128; off > 0; off >>= 1) {
    if (threadIdx.x < off) sh[threadIdx.x] += sh[threadIdx.x + off];
    __syncthreads();
  }
  if (threadIdx.x == 0) bsum[blockIdx.x] = sh[0];
}

__global__ void scan_b(const int* __restrict__ bsum, int* __restrict__ boff, int nb) {
  __shared__ int sh[256];
  int t = threadIdx.x;
  int v = (t < nb) ? bsum[t] : 0;
  sh[t] = v; __syncthreads();
  for (int off = 1; off < 256; off <<= 1) {
    int x = (t >= off) ? sh[t - off] : 0;
    __syncthreads();
    sh[t] += x;
    __syncthreads();
  }
  if (t < nb) boff[t] = sh[t] - v;   // exclusive
}

__global__ void scan_c(const int* __restrict__ cnt, const int* __restrict__ boff,
                       int* __restrict__ start, int* __restrict__ cursor) {
  __shared__ int sh[256];
  int t = threadIdx.x;
  int i = blockIdx.x * 256 + t;
  int v = (i < NN) ? cnt[i] : 0;
  sh[t] = v; __syncthreads();
  for (int off = 1; off < 256; off <<= 1) {
    int x = (t >= off) ? sh[t - off] : 0;
    __syncthreads();
    sh[t] += x;
    __syncthreads();
  }
  if (i < NN) {
    int ex = boff[blockIdx.x] + sh[t] - v;
    start[i] = ex; cursor[i] = ex;
  }
  if (i == 0) start[NN] = NE;
}

__global__ void scatter_kernel(const int* __restrict__ eidx, const float* __restrict__ ea,
                               int* __restrict__ cursor,
                               int* __restrict__ srow, int* __restrict__ scol,
                               int* __restrict__ perm, f16* __restrict__ ea4) {
  int e = blockIdx.x * 256 + threadIdx.x;
  if (e >= NE) return;
  int r = eidx[e];
  int j = atomicAdd(&cursor[r], 1);
  srow[j] = r;
  scol[j] = eidx[NE + e];
  perm[j] = e;
  f16x4 v;
  v[0] = (f16)ea[3 * (size_t)e];
  v[1] = (f16)ea[3 * (size_t)e + 1];
  v[2] = (f16)ea[3 * (size_t)e + 2];
  v[3] = (f16)0.0f;
  *(f16x4*)&ea4[4 * (size_t)j] = v;
}

// ---------------------------------------------------------------- weight prep
// frag slot (ks,t,lane): for ks >= ident_ks:
//   dst[slot*8+j] = W1[(koff+(ks-ident_ks)*32+(lane>>4)*8+j)*64 + (t*16+(lane&15))]
// for ks < ident_ks: identity block pattern (64x64 I split in 2 ksteps/chunk):
//   v = ((ks&1)*32+(lane>>4)*8+j == t*16+(lane&15)) ? 1 : 0
__global__ void prep_kernel(const float* __restrict__ W1, int kreal1, int ksteps1,
                            int ident_ks, int koff,
                            const float* __restrict__ W2,
                            f16* __restrict__ w1f, f16* __restrict__ w2f) {
  int u = blockIdx.x * 256 + threadIdx.x;
  int total1 = ksteps1 * 256;
  if (u < total1) {
    int slot = u;
    int l = slot & 63, t = (slot >> 6) & 3, ks = slot >> 8;
    int n = t * 16 + (l & 15);
    f16x8 v;
    if (ks < ident_ks) {
#pragma unroll
      for (int j = 0; j < 8; ++j) {
        int lk = (ks & 1) * 32 + ((l >> 4) * 8) + j;
        v[j] = (lk == n) ? (f16)1.0f : (f16)0.0f;
      }
    } else {
      int kb = koff + (ks - ident_ks) * 32 + ((l >> 4) * 8);
#pragma unroll
      for (int j = 0; j < 8; ++j) {
        int k = kb + j;
        v[j] = (f16)((k < kreal1) ? W1[k * 64 + n] : 0.0f);
      }
    }
    *(f16x8*)&w1f[slot * 8] = v;
  } else if (u < total1 + 512) {
    int slot = u - total1;
    int l = slot & 63, t = (slot >> 6) & 3, ks = slot >> 8;
    int n = t * 16 + (l & 15);
    int kb = ks * 32 + ((l >> 4) * 8);
    f16x8 v;
#pragma unroll
    for (int j = 0; j < 8; ++j)
      v[j] = (f16)W2[(kb + j) * 64 + n];
    *(f16x8*)&w2f[slot * 8] = v;
  }
}

// ---------------------------------------------------------------- node proj
// f[n] = [xA[n],xB[n]] @ W1[0:128]; g[n] = same @ W1[128:256]  (raw f16 out)
// w1p holds 8 frag-ksteps: ks0-3 = W1 rows 0-127, ks4-7 = rows 128-255.
__global__ __launch_bounds__(256, 2) void node_proj_kernel(
    const f16* __restrict__ xA, const f16* __restrict__ xB,
    const f16* __restrict__ w1p,
    f16* __restrict__ fN, f16* __restrict__ gN)
{
  __shared__ f16 wps[8 * 2048];
  __shared__ __align__(16) f16 hbuf[4][16][40];
  const int tid  = threadIdx.x;
  const int lane = tid & 63;
  const int wv   = tid >> 6;
  const int quad = lane >> 4;
  const int l15  = lane & 15;

  for (int u = tid; u < 8 * 256; u += 256)
    *(f16x8*)&wps[u * 8] = *(const f16x8*)&w1p[u * 8];
  __syncthreads();

  constexpr int NT = (NN + 31) / 32;   // 1563
  const int stride = gridDim.x * 4;
  for (int tI = blockIdx.x * 4 + wv; tI < NT; tI += stride) {
    const int nb = tI * 32;
    const int m0 = nb + l15, m1 = nb + 16 + l15;
    const size_t n0 = (size_t)(m0 < NN ? m0 : NN - 1);
    const size_t n1 = (size_t)(m1 < NN ? m1 : NN - 1);
    f16x8 a0[4], a1[4];
#pragma unroll
    for (int ks = 0; ks < 4; ++ks) {
      const f16* src = (ks < 2) ? xA : xB;
      const int kk = ks & 1;
      a0[ks] = *(const f16x8*)(src + n0 * 64 + kk * 32 + quad * 8);
      a1[ks] = *(const f16x8*)(src + n1 * 64 + kk * 32 + quad * 8);
    }
    f32x4 af[2][4], ag[2][4];
#pragma unroll
    for (int s = 0; s < 2; ++s)
#pragma unroll
      for (int t = 0; t < 4; ++t) {
        af[s][t] = (f32x4){0.f, 0.f, 0.f, 0.f};
        ag[s][t] = (f32x4){0.f, 0.f, 0.f, 0.f};
      }
#pragma unroll
    for (int ks = 0; ks < 4; ++ks) {
#pragma unroll
      for (int t = 0; t < 4; ++t) {
        f16x8 bf = *(const f16x8*)&wps[((ks * 4 + t) * 64 + lane) * 8];
        f16x8 bg = *(const f16x8*)&wps[(((4 + ks) * 4 + t) * 64 + lane) * 8];
        af[0][t] = __builtin_amdgcn_mfma_f32_16x16x32_f16(a0[ks], bf, af[0][t], 0, 0, 0);
        af[1][t] = __builtin_amdgcn_mfma_f32_16x16x32_f16(a1[ks], bf, af[1][t], 0, 0, 0);
        ag[0][t] = __builtin_amdgcn_mfma_f32_16x16x32_f16(a0[ks], bg, ag[0][t], 0, 0, 0);
        ag[1][t] = __builtin_amdgcn_mfma_f32_16x16x32_f16(a1[ks], bg, ag[1][t], 0, 0, 0);
      }
    }
#pragma unroll
    for (int s = 0; s < 2; ++s) {
      const int row = nb + s * 16 + l15;
      // f: two 32-col transpose passes -> raw f16 row store
      f16x8 oh[2];
#pragma unroll
      for (int h = 0; h < 2; ++h) {
#pragma unroll
        for (int th = 0; th < 2; ++th) {
          const int t = h * 2 + th;
#pragma unroll
          for (int r = 0; r < 4; ++r)
            hbuf[wv][quad * 4 + r][th * 16 + l15] = (f16)af[s][t][r];
        }
        oh[h] = *(const f16x8*)&hbuf[wv][l15][quad * 8];
      }
      if (row < NN) {
        *(f16x8*)&fN[(size_t)row * 64 + quad * 8] = oh[0];
        *(f16x8*)&fN[(size_t)row * 64 + 32 + quad * 8] = oh[1];
      }
      // g
#pragma unroll
      for (int h = 0; h < 2; ++h) {
#pragma unroll
        for (int th = 0; th < 2; ++th) {
          const int t = h * 2 + th;
#pragma unroll
          for (int r = 0; r < 4; ++r)
            hbuf[wv][quad * 4 + r][th * 16 + l15] = (f16)ag[s][t][r];
        }
        oh[h] = *(const f16x8*)&hbuf[wv][l15][quad * 8];
      }
      if (row < NN) {
        *(f16x8*)&gN[(size_t)row * 64 + quad * 8] = oh[0];
        *(f16x8*)&gN[(size_t)row * 64 + 32 + quad * 8] = oh[1];
      }
    }
  }
}

// ---------------------------------------------------------------- node segment sum
// one wave per node: sum raw f16 edge rows over [start[v], start[v+1]) -> relu(mean)
template<int F32OUT>
__global__ void node_sum_kernel(const f16* __restrict__ eout, const int* __restrict__ start,
                                void* __restrict__ xout) {
  int v = blockIdx.x * 4 + (threadIdx.x >> 6);
  int lane = threadIdx.x & 63;
  int g = lane >> 4, c4 = (lane & 15) * 4;
  int s0 = start[v], s1 = start[v + 1];
  f32x4 acc = (f32x4){0.f, 0.f, 0.f, 0.f};
  for (int i = s0 + g; i < s1; i += 4) {
    f16x4 h = *(const f16x4*)&eout[(size_t)i * 64 + c4];
#pragma unroll
    for (int q = 0; q < 4; ++q) acc[q] += (float)h[q];
  }
#pragma unroll
  for (int q = 0; q < 4; ++q) {
    acc[q] += __shfl_xor(acc[q], 16, 64);
    acc[q] += __shfl_xor(acc[q], 32, 64);
  }
  int cv = s1 - s0;
  float inv = 1.0f / (float)(cv > 0 ? cv : 1);
  if (g == 0) {
    if (F32OUT) {
      f32x4 o;
#pragma unroll
      for (int q = 0; q < 4; ++q) o[q] = fmaxf(acc[q] * inv, 0.0f);
      *(f32x4*)&((float*)xout)[(size_t)v * 64 + c4] = o;
    } else {
      f16x4 o;
#pragma unroll
      for (int q = 0; q < 4; ++q) o[q] = (f16)fmaxf(acc[q] * inv, 0.0f);
      *(f16x4*)&((f16*)xout)[(size_t)v * 64 + c4] = o;
    }
  }
}

// ---------------------------------------------------------------- edge conv
// Sorted order j. eout[j] = RAW f16 edge output. CONV==4 scatters relu fp32
// to out_e[perm[j]]. CONV 3/4 chunks: f[r] (ident), g[c] (ident), eA, eB.
template<int CONV>
__global__ __launch_bounds__(256, 2) void edge_conv_kernel(
    const int* __restrict__ srow, const int* __restrict__ scol,
    const int* __restrict__ perm,
    const float* __restrict__ na,
    const f16* __restrict__ xA, const f16* __restrict__ xB,
    const f16* __restrict__ eA, const f16* __restrict__ eB,
    const f16* __restrict__ ea4,
    const f16* __restrict__ w1f, const f16* __restrict__ w2f,
    const float* __restrict__ b1, const float* __restrict__ b2,
    f16* __restrict__ eout, float* __restrict__ out_e)
{
  constexpr int KSTEPS = (CONV == 1) ? 1 : (CONV == 2 ? 7 : 8);

  __shared__ f16 w1s[KSTEPS * 2048];                  // all B-frags, 4KB per ks
  __shared__ __align__(16) f16 hbuf[4][16][40];       // per-wave 32-col xpose buf

  const int tid  = threadIdx.x;
  const int lane = tid & 63;
  const int wv   = tid >> 6;
  const int quad = lane >> 4;
  const int l15  = lane & 15;

  for (int u = tid; u < KSTEPS * 256; u += 256)
    *(f16x8*)&w1s[u * 8] = *(const f16x8*)&w1f[u * 8];

  float bb1[4], bb2[4];
#pragma unroll
  for (int t = 0; t < 4; ++t) { bb1[t] = b1[t * 16 + l15]; bb2[t] = b2[t * 16 + l15]; }

  f16x8 w2r[2][4];
#pragma unroll
  for (int kk = 0; kk < 2; ++kk)
#pragma unroll
    for (int t = 0; t < 4; ++t)
      w2r[kk][t] = *(const f16x8*)&w2f[((kk * 4 + t) * 64 + lane) * 8];

  __syncthreads();   // w1s visible; no further barriers

  constexpr int NTILE = NE / 32;          // wave-tiles of 32 edges
  const int gw = blockIdx.x * 4 + wv;
  const int stride = gridDim.x * 4;

  // ---- shared epilogue: hidden=relu(acc+b1) -> GEMM2 -> raw f16 row stores
  auto epilogue = [&](f32x4 (&acc)[2][4], int jb) {
#pragma unroll
    for (int s = 0; s < 2; ++s) {
      f32x4 a2[4];
#pragma unroll
      for (int t = 0; t < 4; ++t) a2[t] = (f32x4){0.f, 0.f, 0.f, 0.f};
#pragma unroll
      for (int kk = 0; kk < 2; ++kk) {
#pragma unroll
        for (int th = 0; th < 2; ++th) {
          const int t = kk * 2 + th;
#pragma unroll
          for (int r = 0; r < 4; ++r)
            hbuf[wv][quad * 4 + r][th * 16 + l15] = (f16)fmaxf(acc[s][t][r] + bb1[t], 0.0f);
        }
        f16x8 ah = *(const f16x8*)&hbuf[wv][l15][quad * 8];
#pragma unroll
        for (int t = 0; t < 4; ++t)
          a2[t] = __builtin_amdgcn_mfma_f32_16x16x32_f16(ah, w2r[kk][t], a2[t], 0, 0, 0);
      }

      const int j = jb + s * 16 + l15;
      f16x8 oh[2];
#pragma unroll
      for (int h = 0; h < 2; ++h) {
#pragma unroll
        for (int th = 0; th < 2; ++th) {
          const int t = h * 2 + th;
#pragma unroll
          for (int r = 0; r < 4; ++r)
            hbuf[wv][quad * 4 + r][th * 16 + l15] = (f16)(a2[t][r] + bb2[t]);
        }
        oh[h] = *(const f16x8*)&hbuf[wv][l15][quad * 8];
      }
      *(f16x8*)&eout[(size_t)j * 64 + quad * 8] = oh[0];
      *(f16x8*)&eout[(size_t)j * 64 + 32 + quad * 8] = oh[1];

      if constexpr (CONV == 4) {
#pragma unroll
        for (int r = 0; r < 4; ++r) {
          const int p = perm[jb + s * 16 + quad * 4 + r];
#pragma unroll
          for (int t = 0; t < 4; ++t)
            out_e[(size_t)p * 64 + t * 16 + l15] = fmaxf(a2[t][r] + bb2[t], 0.0f);
        }
      }
    }
  };

  if constexpr (CONV == 1) {
    for (int jt = gw; jt < NTILE; jt += stride) {
      const int jb = jt * 32;
      const int j0 = jb + l15, j1 = j0 + 16;
      const int r0 = srow[j0], r1 = srow[j1];
      const int c0 = scol[j0], c1 = scol[j1];
      f16x8 a0, a1;
#pragma unroll
      for (int j = 0; j < 8; ++j) { a0[j] = (f16)0.0f; a1[j] = (f16)0.0f; }
      f16x4 q0 = *(const f16x4*)&ea4[4 * (size_t)j0];
      f16x4 q1 = *(const f16x4*)&ea4[4 * (size_t)j1];
      if (quad == 0) {
        a0[0] = (f16)na[r0*3];  a0[1] = (f16)na[r0*3+1];  a0[2] = (f16)na[r0*3+2];
        a0[3] = (f16)na[c0*3];  a0[4] = (f16)na[c0*3+1];  a0[5] = (f16)na[c0*3+2];
        a0[6] = q0[0];          a0[7] = q0[1];
        a1[0] = (f16)na[r1*3];  a1[1] = (f16)na[r1*3+1];  a1[2] = (f16)na[r1*3+2];
        a1[3] = (f16)na[c1*3];  a1[4] = (f16)na[c1*3+1];  a1[5] = (f16)na[c1*3+2];
        a1[6] = q1[0];          a1[7] = q1[1];
      } else if (quad == 1) {
        a0[0] = q0[2];
        a1[0] = q1[2];
      }
      f32x4 acc[2][4];
#pragma unroll
      for (int s = 0; s < 2; ++s)
#pragma unroll
        for (int t = 0; t < 4; ++t) acc[s][t] = (f32x4){0.f, 0.f, 0.f, 0.f};
#pragma unroll
      for (int t = 0; t < 4; ++t) {
        f16x8 b = *(const f16x8*)&w1s[(t * 64 + lane) * 8];
        acc[0][t] = __builtin_amdgcn_mfma_f32_16x16x32_f16(a0, b, acc[0][t], 0, 0, 0);
        acc[1][t] = __builtin_amdgcn_mfma_f32_16x16x32_f16(a1, b, acc[1][t], 0, 0, 0);
      }
      epilogue(acc, jb);
    }
  } else {
    constexpr int NREG = (CONV == 2) ? 3 : 4;
    constexpr int ERCH = 2;   // chunks >= ERCH are e-prev (relu on load)

    int jt = gw;
    int pr0 = 0, pr1 = 0, pc0 = 0, pc1 = 0;     // current tile's indices
    if (jt < NTILE) {
      const int jb = jt * 32;
      pr0 = srow[jb + l15];  pr1 = srow[jb + 16 + l15];
      pc0 = scol[jb + l15];  pc1 = scol[jb + 16 + l15];
    }

    for (; jt < NTILE; jt += stride) {
      const int jb = jt * 32;
      const int j0 = jb + l15, j1 = j0 + 16;

      // prefetch NEXT tile's indices (4 VGPRs; hides idx->gather serial link)
      const int jn = jt + stride;
      int nr0 = 0, nr1 = 0, nc0 = 0, nc1 = 0;
      if (jn < NTILE) {
        const int njb = jn * 32;
        nr0 = srow[njb + l15];  nr1 = srow[njb + 16 + l15];
        nc0 = scol[njb + l15];  nc1 = scol[njb + 16 + l15];
      }

      const int r0 = pr0, r1 = pr1, c0 = pc0, c1 = pc1;
      const f16* p0[NREG]; const f16* p1[NREG];
      if constexpr (CONV == 2) {
        p0[0] = xA + (size_t)r0 * 64;  p1[0] = xA + (size_t)r1 * 64;
        p0[1] = xA + (size_t)c0 * 64;  p1[1] = xA + (size_t)c1 * 64;
        p0[2] = eA + (size_t)j0 * 64;  p1[2] = eA + (size_t)j1 * 64;
      } else {
        p0[0] = xA + (size_t)r0 * 64;  p1[0] = xA + (size_t)r1 * 64;   // f[r]
        p0[1] = xB + (size_t)c0 * 64;  p1[1] = xB + (size_t)c1 * 64;   // g[c]
        p0[2] = eA + (size_t)j0 * 64;  p1[2] = eA + (size_t)j1 * 64;
        p0[3] = eB + (size_t)j0 * 64;  p1[3] = eB + (size_t)j1 * 64;
      }

      f32x4 acc[2][4];
#pragma unroll
      for (int s = 0; s < 2; ++s)
#pragma unroll
        for (int t = 0; t < 4; ++t) acc[s][t] = (f32x4){0.f, 0.f, 0.f, 0.f};

#pragma unroll
      for (int ks = 0; ks < NREG * 2; ++ks) {
        const int c = ks >> 1, kk = ks & 1;
        f16x8 a0 = *(const f16x8*)(p0[c] + kk * 32 + quad * 8);
        f16x8 a1 = *(const f16x8*)(p1[c] + kk * 32 + quad * 8);
        if (c >= ERCH) {            // e-prev stored raw -> relu on load
#pragma unroll
          for (int j = 0; j < 8; ++j) {
            a0[j] = (a0[j] > (f16)0.0f) ? a0[j] : (f16)0.0f;
            a1[j] = (a1[j] > (f16)0.0f) ? a1[j] : (f16)0.0f;
          }
        }
#pragma unroll
        for (int t = 0; t < 4; ++t) {
          f16x8 b = *(const f16x8*)&w1s[((ks * 4 + t) * 64 + lane) * 8];
          acc[0][t] = __builtin_amdgcn_mfma_f32_16x16x32_f16(a0, b, acc[0][t], 0, 0, 0);
          acc[1][t] = __builtin_amdgcn_mfma_f32_16x16x32_f16(a1, b, acc[1][t], 0, 0, 0);
        }
      }
      if constexpr (CONV == 2) {    // tail ks 6: ea at cols 192..194
        f16x8 a0, a1;
#pragma unroll
        for (int j = 0; j < 8; ++j) { a0[j] = (f16)0.0f; a1[j] = (f16)0.0f; }
        f16x4 q0 = *(const f16x4*)&ea4[4 * (size_t)j0];
        f16x4 q1 = *(const f16x4*)&ea4[4 * (size_t)j1];
        if (quad == 0) {
          a0[0] = q0[0]; a0[1] = q0[1]; a0[2] = q0[2];
          a1[0] = q1[0]; a1[1] = q1[1]; a1[2] = q1[2];
        }
#pragma unroll
        for (int t = 0; t < 4; ++t) {
          f16x8 b = *(const f16x8*)&w1s[((6 * 4 + t) * 64 + lane) * 8];
          acc[0][t] = __builtin_amdgcn_mfma_f32_16x16x32_f16(a0, b, acc[0][t], 0, 0, 0);
          acc[1][t] = __builtin_amdgcn_mfma_f32_16x16x32_f16(a1, b, acc[1][t], 0, 0, 0);
        }
      }

      epilogue(acc, jb);

      pr0 = nr0; pr1 = nr1; pc0 = nc0; pc1 = nc1;
    }
  }
}

// ---------------------------------------------------------------- head MLP
__global__ void head_kernel(const float* __restrict__ x4,
                            const float* __restrict__ W1, const float* __restrict__ b1,
                            const float* __restrict__ W2, const float* __restrict__ b2,
                            float* __restrict__ out) {
  __shared__ float xs[4][64];
  __shared__ float hs[4][64];
  int tid = threadIdx.x;
  int i = tid >> 6, f = tid & 63;
  int nb = blockIdx.x * 4;
  xs[i][f] = x4[(size_t)(nb + i) * 64 + f];
  __syncthreads();
  float h = b1[f];
#pragma unroll
  for (int k = 0; k < 64; ++k) h += xs[i][k] * W1[k * 64 + f];
  hs[i][f] = fmaxf(h, 0.0f);
  __syncthreads();
  if (tid < 12) {
    int ii = tid / 3, j = tid % 3;
    float o = b2[j];
#pragma unroll
    for (int k = 0; k < 64; ++k) o += hs[ii][k] * W2[k * 3 + j];
    out[(size_t)(nb + ii) * 3 + j] = o;
  }
}

// ---------------------------------------------------------------- launch
extern "C" void kernel_launch(void* const* d_in, const int* in_sizes, int n_in,
                              void* d_out, int out_size, void* d_ws, size_t ws_size,
                              hipStream_t stream) {
  const float* na   = (const float*)d_in[0];
  const float* ea   = (const float*)d_in[1];
  const int*   eidx = (const int*)d_in[2];
  const float* c1W1 = (const float*)d_in[3];
  const float* c1b1 = (const float*)d_in[4];
  const float* c1W2 = (const float*)d_in[5];
  const float* c1b2 = (const float*)d_in[6];
  const float* c2W1 = (const float*)d_in[7];
  const float* c2b1 = (const float*)d_in[8];
  const float* c2W2 = (const float*)d_in[9];
  const float* c2b2 = (const float*)d_in[10];
  const float* c3W1 = (const float*)d_in[11];
  const float* c3b1 = (const float*)d_in[12];
  const float* c3W2 = (const float*)d_in[13];
  const float* c3b2 = (const float*)d_in[14];
  const float* c4W1 = (const float*)d_in[15];
  const float* c4b1 = (const float*)d_in[16];
  const float* c4W2 = (const float*)d_in[17];
  const float* c4b2 = (const float*)d_in[18];
  const float* mW1  = (const float*)d_in[19];
  const float* mb1  = (const float*)d_in[20];
  const float* mW2  = (const float*)d_in[21];
  const float* mb2  = (const float*)d_in[22];

  char* ws = (char*)d_ws;
  size_t off = 0;
  auto alloc = [&](size_t b) -> void* {
    void* p = ws + off;
    off += (b + 255) & ~(size_t)255;
    return p;
  };
  int*   cnt    = (int*)alloc((size_t)NN * 4);
  int*   bsum   = (int*)alloc(256 * 4);
  int*   boff   = (int*)alloc(256 * 4);
  int*   start  = (int*)alloc((size_t)(NN + 1) * 4);
  int*   cursor = (int*)alloc((size_t)NN * 4);
  int*   srow   = (int*)alloc((size_t)NE * 4);
  int*   scol   = (int*)alloc((size_t)NE * 4);
  int*   perm   = (int*)alloc((size_t)NE * 4);
  f16*   ea4    = (f16*)alloc((size_t)NE * 4 * 2);
  f16*   x1     = (f16*)alloc((size_t)NN * 64 * 2);
  f16*   x2     = (f16*)alloc((size_t)NN * 64 * 2);
  f16*   x3     = (f16*)alloc((size_t)NN * 64 * 2);
  float* x4     = (float*)alloc((size_t)NN * 64 * 4);
  f16*   fN3    = (f16*)alloc((size_t)NN * 64 * 2);
  f16*   gN3    = (f16*)alloc((size_t)NN * 64 * 2);
  f16*   fN4    = (f16*)alloc((size_t)NN * 64 * 2);
  f16*   gN4    = (f16*)alloc((size_t)NN * 64 * 2);
  f16*   se1    = (f16*)alloc((size_t)NE * 64 * 2);   // also reused as e4 raw
  f16*   se2    = (f16*)alloc((size_t)NE * 64 * 2);
  f16*   se3    = (f16*)alloc((size_t)NE * 64 * 2);
  f16*   w1f1 = (f16*)alloc((size_t) 1 * 2048 * 2);
  f16*   w1f2 = (f16*)alloc((size_t) 7 * 2048 * 2);
  f16*   w1f3 = (f16*)alloc((size_t) 8 * 2048 * 2);
  f16*   w1f4 = (f16*)alloc((size_t) 8 * 2048 * 2);
  f16*   w1p3 = (f16*)alloc((size_t) 8 * 2048 * 2);
  f16*   w1p4 = (f16*)alloc((size_t) 8 * 2048 * 2);
  f16*   w2f1 = (f16*)alloc((size_t)4096 * 2);
  f16*   w2f2 = (f16*)alloc((size_t)4096 * 2);
  f16*   w2f3 = (f16*)alloc((size_t)4096 * 2);
  f16*   w2f4 = (f16*)alloc((size_t)4096 * 2);

  float* out_x = (float*)d_out;
  float* out_e = out_x + (size_t)NN * 3;

  constexpr int NBS = (NN + 255) / 256;   // 196
  constexpr int GRID_EC = 1024;           // 256-thr blocks; LDS allows 4/CU
  constexpr int GRID_NP = 391;            // node_proj: ceil(1563/4)

  hipMemsetAsync(cnt, 0, (size_t)NN * 4, stream);
  count_kernel<<<NE / 256, 256, 0, stream>>>(eidx, cnt);
  scan_a<<<NBS, 256, 0, stream>>>(cnt, bsum);
  scan_b<<<1, 256, 0, stream>>>(bsum, boff, NBS);
  scan_c<<<NBS, 256, 0, stream>>>(cnt, boff, start, cursor);
  scatter_kernel<<<NE / 256, 256, 0, stream>>>(eidx, ea, cursor, srow, scol, perm, ea4);

  prep_kernel<<< 3, 256, 0, stream>>>(c1W1,   9, 1, 0,   0, c1W2, w1f1, w2f1);
  prep_kernel<<< 9, 256, 0, stream>>>(c2W1, 195, 7, 0,   0, c2W2, w1f2, w2f2);
  prep_kernel<<<10, 256, 0, stream>>>(c3W1, 384, 8, 4, 256, c3W2, w1f3, w2f3);
  prep_kernel<<<10, 256, 0, stream>>>(c4W1, 384, 8, 4, 256, c4W2, w1f4, w2f4);
  prep_kernel<<<10, 256, 0, stream>>>(c3W1, 384, 8, 0,   0, c3W2, w1p3, w2f3);
  prep_kernel<<<10, 256, 0, stream>>>(c4W1, 384, 8, 0,   0, c4W2, w1p4, w2f4);

  edge_conv_kernel<1><<<GRID_EC, 256, 0, stream>>>(srow, scol, nullptr, na,
      nullptr, nullptr, nullptr, nullptr, ea4, w1f1, w2f1, c1b1, c1b2, se1, nullptr);
  node_sum_kernel<0><<<NN / 4, 256, 0, stream>>>(se1, start, x1);

  edge_conv_kernel<2><<<GRID_EC, 256, 0, stream>>>(srow, scol, nullptr, nullptr,
      x1, nullptr, se1, nullptr, ea4, w1f2, w2f2, c2b1, c2b2, se2, nullptr);
  node_sum_kernel<0><<<NN / 4, 256, 0, stream>>>(se2, start, x2);

  node_proj_kernel<<<GRID_NP, 256, 0, stream>>>(x2, x1, w1p3, fN3, gN3);
  edge_conv_kernel<3><<<GRID_EC, 256, 0, stream>>>(srow, scol, nullptr, nullptr,
      fN3, gN3, se2, se1, nullptr, w1f3, w2f3, c3b1, c3b2, se3, nullptr);
  node_sum_kernel<0><<<NN / 4, 256, 0, stream>>>(se3, start, x3);

  node_proj_kernel<<<GRID_NP, 256, 0, stream>>>(x3, x2, w1p4, fN4, gN4);
  edge_conv_kernel<4><<<GRID_EC, 256, 0, stream>>>(srow, scol, perm, nullptr,
      fN4, gN4, se3, se2, nullptr, w1f4, w2f4, c4b1, c4b2, se1, out_e);
  node_sum_kernel<1><<<NN / 4, 256, 0, stream>>>(se1, start, x4);

  head_kernel<<<NN / 4, 256, 0, stream>>>(x4, mW1, mb1, mW2, mb2, out_x);
}

// Round 9
// 864.689 us; speedup vs baseline: 1.5800x; 1.0142x over previous
//
#include <hip/hip_runtime.h>
#include <cstdint>
#include <cstddef>

// MPNN: 4 edge-conv layers + head MLP.  N=50000, E=800000, F=64.
// Round 12: BISECTION. The round-10/11 kernel (dynamic atomic tile grab +
// identity-MFMA skip) failed 4 container attempts across 2 rounds right after
// round 9 passed. Treating the failure as kernel-correlated: this round is
// round 9's VERIFIED kernel (static stride, no atomics, no wctr) plus ONLY
// the compile-time identity-kstep MFMA skip (16 of 64 GEMM1 MFMAs provably
// multiply all-zero B-blocks: ks even -> t{2,3} zero, ks odd -> t{0,1} zero).
// If this passes, the atomic grab is the poison; if it fails, it's infra.

#define NN 50000
#define NE 800000

typedef _Float16 f16;
typedef _Float16 f16x8 __attribute__((ext_vector_type(8)));
typedef _Float16 f16x4 __attribute__((ext_vector_type(4)));
typedef float    f32x4 __attribute__((ext_vector_type(4)));

// ---------------------------------------------------------------- sort build
__global__ void count_kernel(const int* __restrict__ eidx, int* __restrict__ cnt) {
  int i = blockIdx.x * 256 + threadIdx.x;
  if (i < NE) atomicAdd(&cnt[eidx[i]], 1);
}

__global__ void scan_a(const int* __restrict__ cnt, int* __restrict__ bsum) {
  __shared__ int sh[256];
  int i = blockIdx.x * 256 + threadIdx.x;
  sh[threadIdx.x] = (i < NN) ? cnt[i] : 0;
  __syncthreads();
  for (int off = 128; off > 0; off >>= 1) {
    if (threadIdx.x < off) sh[threadIdx.x] += sh[threadIdx.x + off];
    __syncthreads();
  }
  if (threadIdx.x == 0) bsum[blockIdx.x] = sh[0];
}

__global__ void scan_b(const int* __restrict__ bsum, int* __restrict__ boff, int nb) {
  __shared__ int sh[256];
  int t = threadIdx.x;
  int v = (t < nb) ? bsum[t] : 0;
  sh[t] = v; __syncthreads();
  for (int off = 1; off < 256; off <<= 1) {
    int x = (t >= off) ? sh[t - off] : 0;
    __syncthreads();
    sh[t] += x;
    __syncthreads();
  }
  if (t < nb) boff[t] = sh[t] - v;   // exclusive
}

__global__ void scan_c(const int* __restrict__ cnt, const int* __restrict__ boff,
                       int* __restrict__ start, int* __restrict__ cursor) {
  __shared__ int sh[256];
  int t = threadIdx.x;
  int i = blockIdx.x * 256 + t;
  int v = (i < NN) ? cnt[i] : 0;
  sh[t] = v; __syncthreads();
  for (int off = 1; off < 256; off <<= 1) {
    int x = (t >= off) ? sh[t - off] : 0;
    __syncthreads();
    sh[t] += x;
    __syncthreads();
  }
  if (i < NN) {
    int ex = boff[blockIdx.x] + sh[t] - v;
    start[i] = ex; cursor[i] = ex;
  }
  if (i == 0) start[NN] = NE;
}

__global__ void scatter_kernel(const int* __restrict__ eidx, const float* __restrict__ ea,
                               int* __restrict__ cursor,
                               int* __restrict__ srow, int* __restrict__ scol,
                               int* __restrict__ perm, f16* __restrict__ ea4) {
  int e = blockIdx.x * 256 + threadIdx.x;
  if (e >= NE) return;
  int r = eidx[e];
  int j = atomicAdd(&cursor[r], 1);
  srow[j] = r;
  scol[j] = eidx[NE + e];
  perm[j] = e;
  f16x4 v;
  v[0] = (f16)ea[3 * (size_t)e];
  v[1] = (f16)ea[3 * (size_t)e + 1];
  v[2] = (f16)ea[3 * (size_t)e + 2];
  v[3] = (f16)0.0f;
  *(f16x4*)&ea4[4 * (size_t)j] = v;
}

// ---------------------------------------------------------------- weight prep
// frag slot (ks,t,lane): for ks >= ident_ks:
//   dst[slot*8+j] = W1[(koff+(ks-ident_ks)*32+(lane>>4)*8+j)*64 + (t*16+(lane&15))]
// for ks < ident_ks: identity block pattern (64x64 I split in 2 ksteps/chunk):
//   v = ((ks&1)*32+(lane>>4)*8+j == t*16+(lane&15)) ? 1 : 0
__global__ void prep_kernel(const float* __restrict__ W1, int kreal1, int ksteps1,
                            int ident_ks, int koff,
                            const float* __restrict__ W2,
                            f16* __restrict__ w1f, f16* __restrict__ w2f) {
  int u = blockIdx.x * 256 + threadIdx.x;
  int total1 = ksteps1 * 256;
  if (u < total1) {
    int slot = u;
    int l = slot & 63, t = (slot >> 6) & 3, ks = slot >> 8;
    int n = t * 16 + (l & 15);
    f16x8 v;
    if (ks < ident_ks) {
#pragma unroll
      for (int j = 0; j < 8; ++j) {
        int lk = (ks & 1) * 32 + ((l >> 4) * 8) + j;
        v[j] = (lk == n) ? (f16)1.0f : (f16)0.0f;
      }
    } else {
      int kb = koff + (ks - ident_ks) * 32 + ((l >> 4) * 8);
#pragma unroll
      for (int j = 0; j < 8; ++j) {
        int k = kb + j;
        v[j] = (f16)((k < kreal1) ? W1[k * 64 + n] : 0.0f);
      }
    }
    *(f16x8*)&w1f[slot * 8] = v;
  } else if (u < total1 + 512) {
    int slot = u - total1;
    int l = slot & 63, t = (slot >> 6) & 3, ks = slot >> 8;
    int n = t * 16 + (l & 15);
    int kb = ks * 32 + ((l >> 4) * 8);
    f16x8 v;
#pragma unroll
    for (int j = 0; j < 8; ++j)
      v[j] = (f16)W2[(kb + j) * 64 + n];
    *(f16x8*)&w2f[slot * 8] = v;
  }
}

// ---------------------------------------------------------------- node proj
// f[n] = [xA[n],xB[n]] @ W1[0:128]; g[n] = same @ W1[128:256]  (raw f16 out)
// w1p holds 8 frag-ksteps: ks0-3 = W1 rows 0-127, ks4-7 = rows 128-255.
__global__ __launch_bounds__(256, 2) void node_proj_kernel(
    const f16* __restrict__ xA, const f16* __restrict__ xB,
    const f16* __restrict__ w1p,
    f16* __restrict__ fN, f16* __restrict__ gN)
{
  __shared__ f16 wps[8 * 2048];
  __shared__ __align__(16) f16 hbuf[4][16][40];
  const int tid  = threadIdx.x;
  const int lane = tid & 63;
  const int wv   = tid >> 6;
  const int quad = lane >> 4;
  const int l15  = lane & 15;

  for (int u = tid; u < 8 * 256; u += 256)
    *(f16x8*)&wps[u * 8] = *(const f16x8*)&w1p[u * 8];
  __syncthreads();

  constexpr int NT = (NN + 31) / 32;   // 1563
  const int stride = gridDim.x * 4;
  for (int tI = blockIdx.x * 4 + wv; tI < NT; tI += stride) {
    const int nb = tI * 32;
    const int m0 = nb + l15, m1 = nb + 16 + l15;
    const size_t n0 = (size_t)(m0 < NN ? m0 : NN - 1);
    const size_t n1 = (size_t)(m1 < NN ? m1 : NN - 1);
    f16x8 a0[4], a1[4];
#pragma unroll
    for (int ks = 0; ks < 4; ++ks) {
      const f16* src = (ks < 2) ? xA : xB;
      const int kk = ks & 1;
      a0[ks] = *(const f16x8*)(src + n0 * 64 + kk * 32 + quad * 8);
      a1[ks] = *(const f16x8*)(src + n1 * 64 + kk * 32 + quad * 8);
    }
    f32x4 af[2][4], ag[2][4];
#pragma unroll
    for (int s = 0; s < 2; ++s)
#pragma unroll
      for (int t = 0; t < 4; ++t) {
        af[s][t] = (f32x4){0.f, 0.f, 0.f, 0.f};
        ag[s][t] = (f32x4){0.f, 0.f, 0.f, 0.f};
      }
#pragma unroll
    for (int ks = 0; ks < 4; ++ks) {
#pragma unroll
      for (int t = 0; t < 4; ++t) {
        f16x8 bf = *(const f16x8*)&wps[((ks * 4 + t) * 64 + lane) * 8];
        f16x8 bg = *(const f16x8*)&wps[(((4 + ks) * 4 + t) * 64 + lane) * 8];
        af[0][t] = __builtin_amdgcn_mfma_f32_16x16x32_f16(a0[ks], bf, af[0][t], 0, 0, 0);
        af[1][t] = __builtin_amdgcn_mfma_f32_16x16x32_f16(a1[ks], bf, af[1][t], 0, 0, 0);
        ag[0][t] = __builtin_amdgcn_mfma_f32_16x16x32_f16(a0[ks], bg, ag[0][t], 0, 0, 0);
        ag[1][t] = __builtin_amdgcn_mfma_f32_16x16x32_f16(a1[ks], bg, ag[1][t], 0, 0, 0);
      }
    }
#pragma unroll
    for (int s = 0; s < 2; ++s) {
      const int row = nb + s * 16 + l15;
      // f: two 32-col transpose passes -> raw f16 row store
      f16x8 oh[2];
#pragma unroll
      for (int h = 0; h < 2; ++h) {
#pragma unroll
        for (int th = 0; th < 2; ++th) {
          const int t = h * 2 + th;
#pragma unroll
          for (int r = 0; r < 4; ++r)
            hbuf[wv][quad * 4 + r][th * 16 + l15] = (f16)af[s][t][r];
        }
        oh[h] = *(const f16x8*)&hbuf[wv][l15][quad * 8];
      }
      if (row < NN) {
        *(f16x8*)&fN[(size_t)row * 64 + quad * 8] = oh[0];
        *(f16x8*)&fN[(size_t)row * 64 + 32 + quad * 8] = oh[1];
      }
      // g
#pragma unroll
      for (int h = 0; h < 2; ++h) {
#pragma unroll
        for (int th = 0; th < 2; ++th) {
          const int t = h * 2 + th;
#pragma unroll
          for (int r = 0; r < 4; ++r)
            hbuf[wv][quad * 4 + r][th * 16 + l15] = (f16)ag[s][t][r];
        }
        oh[h] = *(const f16x8*)&hbuf[wv][l15][quad * 8];
      }
      if (row < NN) {
        *(f16x8*)&gN[(size_t)row * 64 + quad * 8] = oh[0];
        *(f16x8*)&gN[(size_t)row * 64 + 32 + quad * 8] = oh[1];
      }
    }
  }
}

// ---------------------------------------------------------------- node segment sum
// one wave per node: sum raw f16 edge rows over [start[v], start[v+1]) -> relu(mean)
template<int F32OUT>
__global__ void node_sum_kernel(const f16* __restrict__ eout, const int* __restrict__ start,
                                void* __restrict__ xout) {
  int v = blockIdx.x * 4 + (threadIdx.x >> 6);
  int lane = threadIdx.x & 63;
  int g = lane >> 4, c4 = (lane & 15) * 4;
  int s0 = start[v], s1 = start[v + 1];
  f32x4 acc = (f32x4){0.f, 0.f, 0.f, 0.f};
  for (int i = s0 + g; i < s1; i += 4) {
    f16x4 h = *(const f16x4*)&eout[(size_t)i * 64 + c4];
#pragma unroll
    for (int q = 0; q < 4; ++q) acc[q] += (float)h[q];
  }
#pragma unroll
  for (int q = 0; q < 4; ++q) {
    acc[q] += __shfl_xor(acc[q], 16, 64);
    acc[q] += __shfl_xor(acc[q], 32, 64);
  }
  int cv = s1 - s0;
  float inv = 1.0f / (float)(cv > 0 ? cv : 1);
  if (g == 0) {
    if (F32OUT) {
      f32x4 o;
#pragma unroll
      for (int q = 0; q < 4; ++q) o[q] = fmaxf(acc[q] * inv, 0.0f);
      *(f32x4*)&((float*)xout)[(size_t)v * 64 + c4] = o;
    } else {
      f16x4 o;
#pragma unroll
      for (int q = 0; q < 4; ++q) o[q] = (f16)fmaxf(acc[q] * inv, 0.0f);
      *(f16x4*)&((f16*)xout)[(size_t)v * 64 + c4] = o;
    }
  }
}

// ---------------------------------------------------------------- edge conv
// Sorted order j, static stride schedule (round-9 verified). eout[j] = RAW
// f16 edge output. CONV==4 scatters relu fp32 to out_e[perm[j]].
// CONV 3/4 chunks: f[r] (ident), g[c] (ident), eA, eB; identity ksteps skip
// the two t-tiles whose B-block is all zero (compile-time predicate).
template<int CONV>
__global__ __launch_bounds__(256, 2) void edge_conv_kernel(
    const int* __restrict__ srow, const int* __restrict__ scol,
    const int* __restrict__ perm,
    const float* __restrict__ na,
    const f16* __restrict__ xA, const f16* __restrict__ xB,
    const f16* __restrict__ eA, const f16* __restrict__ eB,
    const f16* __restrict__ ea4,
    const f16* __restrict__ w1f, const f16* __restrict__ w2f,
    const float* __restrict__ b1, const float* __restrict__ b2,
    f16* __restrict__ eout, float* __restrict__ out_e)
{
  constexpr int KSTEPS = (CONV == 1) ? 1 : (CONV == 2 ? 7 : 8);

  __shared__ f16 w1s[KSTEPS * 2048];                  // all B-frags, 4KB per ks
  __shared__ __align__(16) f16 hbuf[4][16][40];       // per-wave 32-col xpose buf

  const int tid  = threadIdx.x;
  const int lane = tid & 63;
  const int wv   = tid >> 6;
  const int quad = lane >> 4;
  const int l15  = lane & 15;

  for (int u = tid; u < KSTEPS * 256; u += 256)
    *(f16x8*)&w1s[u * 8] = *(const f16x8*)&w1f[u * 8];

  float bb1[4], bb2[4];
#pragma unroll
  for (int t = 0; t < 4; ++t) { bb1[t] = b1[t * 16 + l15]; bb2[t] = b2[t * 16 + l15]; }

  f16x8 w2r[2][4];
#pragma unroll
  for (int kk = 0; kk < 2; ++kk)
#pragma unroll
    for (int t = 0; t < 4; ++t)
      w2r[kk][t] = *(const f16x8*)&w2f[((kk * 4 + t) * 64 + lane) * 8];

  __syncthreads();   // w1s visible; no further barriers

  constexpr int NTILE = NE / 32;          // wave-tiles of 32 edges
  const int gw = blockIdx.x * 4 + wv;
  const int stride = gridDim.x * 4;

  // ---- shared epilogue: hidden=relu(acc+b1) -> GEMM2 -> raw f16 row stores
  auto epilogue = [&](f32x4 (&acc)[2][4], int jb) {
#pragma unroll
    for (int s = 0; s < 2; ++s) {
      f32x4 a2[4];
#pragma unroll
      for (int t = 0; t < 4; ++t) a2[t] = (f32x4){0.f, 0.f, 0.f, 0.f};
#pragma unroll
      for (int kk = 0; kk < 2; ++kk) {
#pragma unroll
        for (int th = 0; th < 2; ++th) {
          const int t = kk * 2 + th;
#pragma unroll
          for (int r = 0; r < 4; ++r)
            hbuf[wv][quad * 4 + r][th * 16 + l15] = (f16)fmaxf(acc[s][t][r] + bb1[t], 0.0f);
        }
        f16x8 ah = *(const f16x8*)&hbuf[wv][l15][quad * 8];
#pragma unroll
        for (int t = 0; t < 4; ++t)
          a2[t] = __builtin_amdgcn_mfma_f32_16x16x32_f16(ah, w2r[kk][t], a2[t], 0, 0, 0);
      }

      const int j = jb + s * 16 + l15;
      f16x8 oh[2];
#pragma unroll
      for (int h = 0; h < 2; ++h) {
#pragma unroll
        for (int th = 0; th < 2; ++th) {
          const int t = h * 2 + th;
#pragma unroll
          for (int r = 0; r < 4; ++r)
            hbuf[wv][quad * 4 + r][th * 16 + l15] = (f16)(a2[t][r] + bb2[t]);
        }
        oh[h] = *(const f16x8*)&hbuf[wv][l15][quad * 8];
      }
      *(f16x8*)&eout[(size_t)j * 64 + quad * 8] = oh[0];
      *(f16x8*)&eout[(size_t)j * 64 + 32 + quad * 8] = oh[1];

      if constexpr (CONV == 4) {
#pragma unroll
        for (int r = 0; r < 4; ++r) {
          const int p = perm[jb + s * 16 + quad * 4 + r];
#pragma unroll
          for (int t = 0; t < 4; ++t)
            out_e[(size_t)p * 64 + t * 16 + l15] = fmaxf(a2[t][r] + bb2[t], 0.0f);
        }
      }
    }
  };

  if constexpr (CONV == 1) {
    for (int jt = gw; jt < NTILE; jt += stride) {
      const int jb = jt * 32;
      const int j0 = jb + l15, j1 = j0 + 16;
      const int r0 = srow[j0], r1 = srow[j1];
      const int c0 = scol[j0], c1 = scol[j1];
      f16x8 a0, a1;
#pragma unroll
      for (int j = 0; j < 8; ++j) { a0[j] = (f16)0.0f; a1[j] = (f16)0.0f; }
      f16x4 q0 = *(const f16x4*)&ea4[4 * (size_t)j0];
      f16x4 q1 = *(const f16x4*)&ea4[4 * (size_t)j1];
      if (quad == 0) {
        a0[0] = (f16)na[r0*3];  a0[1] = (f16)na[r0*3+1];  a0[2] = (f16)na[r0*3+2];
        a0[3] = (f16)na[c0*3];  a0[4] = (f16)na[c0*3+1];  a0[5] = (f16)na[c0*3+2];
        a0[6] = q0[0];          a0[7] = q0[1];
        a1[0] = (f16)na[r1*3];  a1[1] = (f16)na[r1*3+1];  a1[2] = (f16)na[r1*3+2];
        a1[3] = (f16)na[c1*3];  a1[4] = (f16)na[c1*3+1];  a1[5] = (f16)na[c1*3+2];
        a1[6] = q1[0];          a1[7] = q1[1];
      } else if (quad == 1) {
        a0[0] = q0[2];
        a1[0] = q1[2];
      }
      f32x4 acc[2][4];
#pragma unroll
      for (int s = 0; s < 2; ++s)
#pragma unroll
        for (int t = 0; t < 4; ++t) acc[s][t] = (f32x4){0.f, 0.f, 0.f, 0.f};
#pragma unroll
      for (int t = 0; t < 4; ++t) {
        f16x8 b = *(const f16x8*)&w1s[(t * 64 + lane) * 8];
        acc[0][t] = __builtin_amdgcn_mfma_f32_16x16x32_f16(a0, b, acc[0][t], 0, 0, 0);
        acc[1][t] = __builtin_amdgcn_mfma_f32_16x16x32_f16(a1, b, acc[1][t], 0, 0, 0);
      }
      epilogue(acc, jb);
    }
  } else {
    constexpr int NREG = (CONV == 2) ? 3 : 4;
    constexpr int ERCH = 2;   // chunks >= ERCH are e-prev (relu on load)

    int jt = gw;
    int pr0 = 0, pr1 = 0, pc0 = 0, pc1 = 0;     // current tile's indices
    if (jt < NTILE) {
      const int jb = jt * 32;
      pr0 = srow[jb + l15];  pr1 = srow[jb + 16 + l15];
      pc0 = scol[jb + l15];  pc1 = scol[jb + 16 + l15];
    }

    for (; jt < NTILE; jt += stride) {
      const int jb = jt * 32;
      const int j0 = jb + l15, j1 = j0 + 16;

      // prefetch NEXT tile's indices (4 VGPRs; hides idx->gather serial link)
      const int jn = jt + stride;
      int nr0 = 0, nr1 = 0, nc0 = 0, nc1 = 0;
      if (jn < NTILE) {
        const int njb = jn * 32;
        nr0 = srow[njb + l15];  nr1 = srow[njb + 16 + l15];
        nc0 = scol[njb + l15];  nc1 = scol[njb + 16 + l15];
      }

      const int r0 = pr0, r1 = pr1, c0 = pc0, c1 = pc1;
      const f16* p0[NREG]; const f16* p1[NREG];
      if constexpr (CONV == 2) {
        p0[0] = xA + (size_t)r0 * 64;  p1[0] = xA + (size_t)r1 * 64;
        p0[1] = xA + (size_t)c0 * 64;  p1[1] = xA + (size_t)c1 * 64;
        p0[2] = eA + (size_t)j0 * 64;  p1[2] = eA + (size_t)j1 * 64;
      } else {
        p0[0] = xA + (size_t)r0 * 64;  p1[0] = xA + (size_t)r1 * 64;   // f[r]
        p0[1] = xB + (size_t)c0 * 64;  p1[1] = xB + (size_t)c1 * 64;   // g[c]
        p0[2] = eA + (size_t)j0 * 64;  p1[2] = eA + (size_t)j1 * 64;
        p0[3] = eB + (size_t)j0 * 64;  p1[3] = eB + (size_t)j1 * 64;
      }

      f32x4 acc[2][4];
#pragma unroll
      for (int s = 0; s < 2; ++s)
#pragma unroll
        for (int t = 0; t < 4; ++t) acc[s][t] = (f32x4){0.f, 0.f, 0.f, 0.f};

#pragma unroll
      for (int ks = 0; ks < NREG * 2; ++ks) {
        const int c = ks >> 1, kk = ks & 1;
        f16x8 a0 = *(const f16x8*)(p0[c] + kk * 32 + quad * 8);
        f16x8 a1 = *(const f16x8*)(p1[c] + kk * 32 + quad * 8);
        if (c >= ERCH) {            // e-prev stored raw -> relu on load
#pragma unroll
          for (int j = 0; j < 8; ++j) {
            a0[j] = (a0[j] > (f16)0.0f) ? a0[j] : (f16)0.0f;
            a1[j] = (a1[j] > (f16)0.0f) ? a1[j] : (f16)0.0f;
          }
        }
#pragma unroll
        for (int t = 0; t < 4; ++t) {
          // identity ksteps (CONV>=3, ks<4): B-block zero for half the t's
          if constexpr (CONV >= 3) {
            if (ks < 4 && ((ks & 1) ? (t < 2) : (t >= 2))) continue;
          }
          f16x8 b = *(const f16x8*)&w1s[((ks * 4 + t) * 64 + lane) * 8];
          acc[0][t] = __builtin_amdgcn_mfma_f32_16x16x32_f16(a0, b, acc[0][t], 0, 0, 0);
          acc[1][t] = __builtin_amdgcn_mfma_f32_16x16x32_f16(a1, b, acc[1][t], 0, 0, 0);
        }
      }
      if constexpr (CONV == 2) {    // tail ks 6: ea at cols 192..194
        f16x8 a0, a1;
#pragma unroll
        for (int j = 0; j < 8; ++j) { a0[j] = (f16)0.0f; a1[j] = (f16)0.0f; }
        f16x4 q0 = *(const f16x4*)&ea4[4 * (size_t)j0];
        f16x4 q1 = *(const f16x4*)&ea4[4 * (size_t)j1];
        if (quad == 0) {
          a0[0] = q0[0]; a0[1] = q0[1]; a0[2] = q0[2];
          a1[0] = q1[0]; a1[1] = q1[1]; a1[2] = q1[2];
        }
#pragma unroll
        for (int t = 0; t < 4; ++t) {
          f16x8 b = *(const f16x8*)&w1s[((6 * 4 + t) * 64 + lane) * 8];
          acc[0][t] = __builtin_amdgcn_mfma_f32_16x16x32_f16(a0, b, acc[0][t], 0, 0, 0);
          acc[1][t] = __builtin_amdgcn_mfma_f32_16x16x32_f16(a1, b, acc[1][t], 0, 0, 0);
        }
      }

      epilogue(acc, jb);

      pr0 = nr0; pr1 = nr1; pc0 = nc0; pc1 = nc1;
    }
  }
}

// ---------------------------------------------------------------- head MLP
__global__ void head_kernel(const float* __restrict__ x4,
                            const float* __restrict__ W1, const float* __restrict__ b1,
                            const float* __restrict__ W2, const float* __restrict__ b2,
                            float* __restrict__ out) {
  __shared__ float xs[4][64];
  __shared__ float hs[4][64];
  int tid = threadIdx.x;
  int i = tid >> 6, f = tid & 63;
  int nb = blockIdx.x * 4;
  xs[i][f] = x4[(size_t)(nb + i) * 64 + f];
  __syncthreads();
  float h = b1[f];
#pragma unroll
  for (int k = 0; k < 64; ++k) h += xs[i][k] * W1[k * 64 + f];
  hs[i][f] = fmaxf(h, 0.0f);
  __syncthreads();
  if (tid < 12) {
    int ii = tid / 3, j = tid % 3;
    float o = b2[j];
#pragma unroll
    for (int k = 0; k < 64; ++k) o += hs[ii][k] * W2[k * 3 + j];
    out[(size_t)(nb + ii) * 3 + j] = o;
  }
}

// ---------------------------------------------------------------- launch
extern "C" void kernel_launch(void* const* d_in, const int* in_sizes, int n_in,
                              void* d_out, int out_size, void* d_ws, size_t ws_size,
                              hipStream_t stream) {
  const float* na   = (const float*)d_in[0];
  const float* ea   = (const float*)d_in[1];
  const int*   eidx = (const int*)d_in[2];
  const float* c1W1 = (const float*)d_in[3];
  const float* c1b1 = (const float*)d_in[4];
  const float* c1W2 = (const float*)d_in[5];
  const float* c1b2 = (const float*)d_in[6];
  const float* c2W1 = (const float*)d_in[7];
  const float* c2b1 = (const float*)d_in[8];
  const float* c2W2 = (const float*)d_in[9];
  const float* c2b2 = (const float*)d_in[10];
  const float* c3W1 = (const float*)d_in[11];
  const float* c3b1 = (const float*)d_in[12];
  const float* c3W2 = (const float*)d_in[13];
  const float* c3b2 = (const float*)d_in[14];
  const float* c4W1 = (const float*)d_in[15];
  const float* c4b1 = (const float*)d_in[16];
  const float* c4W2 = (const float*)d_in[17];
  const float* c4b2 = (const float*)d_in[18];
  const float* mW1  = (const float*)d_in[19];
  const float* mb1  = (const float*)d_in[20];
  const float* mW2  = (const float*)d_in[21];
  const float* mb2  = (const float*)d_in[22];

  char* ws = (char*)d_ws;
  size_t off = 0;
  auto alloc = [&](size_t b) -> void* {
    void* p = ws + off;
    off += (b + 255) & ~(size_t)255;
    return p;
  };
  int*   cnt    = (int*)alloc((size_t)NN * 4);
  int*   bsum   = (int*)alloc(256 * 4);
  int*   boff   = (int*)alloc(256 * 4);
  int*   start  = (int*)alloc((size_t)(NN + 1) * 4);
  int*   cursor = (int*)alloc((size_t)NN * 4);
  int*   srow   = (int*)alloc((size_t)NE * 4);
  int*   scol   = (int*)alloc((size_t)NE * 4);
  int*   perm   = (int*)alloc((size_t)NE * 4);
  f16*   ea4    = (f16*)alloc((size_t)NE * 4 * 2);
  f16*   x1     = (f16*)alloc((size_t)NN * 64 * 2);
  f16*   x2     = (f16*)alloc((size_t)NN * 64 * 2);
  f16*   x3     = (f16*)alloc((size_t)NN * 64 * 2);
  float* x4     = (float*)alloc((size_t)NN * 64 * 4);
  f16*   fN3    = (f16*)alloc((size_t)NN * 64 * 2);
  f16*   gN3    = (f16*)alloc((size_t)NN * 64 * 2);
  f16*   fN4    = (f16*)alloc((size_t)NN * 64 * 2);
  f16*   gN4    = (f16*)alloc((size_t)NN * 64 * 2);
  f16*   se1    = (f16*)alloc((size_t)NE * 64 * 2);   // also reused as e4 raw
  f16*   se2    = (f16*)alloc((size_t)NE * 64 * 2);
  f16*   se3    = (f16*)alloc((size_t)NE * 64 * 2);
  f16*   w1f1 = (f16*)alloc((size_t) 1 * 2048 * 2);
  f16*   w1f2 = (f16*)alloc((size_t) 7 * 2048 * 2);
  f16*   w1f3 = (f16*)alloc((size_t) 8 * 2048 * 2);
  f16*   w1f4 = (f16*)alloc((size_t) 8 * 2048 * 2);
  f16*   w1p3 = (f16*)alloc((size_t) 8 * 2048 * 2);
  f16*   w1p4 = (f16*)alloc((size_t) 8 * 2048 * 2);
  f16*   w2f1 = (f16*)alloc((size_t)4096 * 2);
  f16*   w2f2 = (f16*)alloc((size_t)4096 * 2);
  f16*   w2f3 = (f16*)alloc((size_t)4096 * 2);
  f16*   w2f4 = (f16*)alloc((size_t)4096 * 2);

  float* out_x = (float*)d_out;
  float* out_e = out_x + (size_t)NN * 3;

  constexpr int NBS = (NN + 255) / 256;   // 196
  constexpr int GRID_EC = 1024;           // 256-thr blocks; 4 blocks/CU resident
  constexpr int GRID_NP = 391;            // node_proj: ceil(1563/4)

  hipMemsetAsync(cnt, 0, (size_t)NN * 4, stream);
  count_kernel<<<NE / 256, 256, 0, stream>>>(eidx, cnt);
  scan_a<<<NBS, 256, 0, stream>>>(cnt, bsum);
  scan_b<<<1, 256, 0, stream>>>(bsum, boff, NBS);
  scan_c<<<NBS, 256, 0, stream>>>(cnt, boff, start, cursor);
  scatter_kernel<<<NE / 256, 256, 0, stream>>>(eidx, ea, cursor, srow, scol, perm, ea4);

  prep_kernel<<< 3, 256, 0, stream>>>(c1W1,   9, 1, 0,   0, c1W2, w1f1, w2f1);
  prep_kernel<<< 9, 256, 0, stream>>>(c2W1, 195, 7, 0,   0, c2W2, w1f2, w2f2);
  prep_kernel<<<10, 256, 0, stream>>>(c3W1, 384, 8, 4, 256, c3W2, w1f3, w2f3);
  prep_kernel<<<10, 256, 0, stream>>>(c4W1, 384, 8, 4, 256, c4W2, w1f4, w2f4);
  prep_kernel<<<10, 256, 0, stream>>>(c3W1, 384, 8, 0,   0, c3W2, w1p3, w2f3);
  prep_kernel<<<10, 256, 0, stream>>>(c4W1, 384, 8, 0,   0, c4W2, w1p4, w2f4);

  edge_conv_kernel<1><<<GRID_EC, 256, 0, stream>>>(srow, scol, nullptr, na,
      nullptr, nullptr, nullptr, nullptr, ea4, w1f1, w2f1, c1b1, c1b2, se1, nullptr);
  node_sum_kernel<0><<<NN / 4, 256, 0, stream>>>(se1, start, x1);

  edge_conv_kernel<2><<<GRID_EC, 256, 0, stream>>>(srow, scol, nullptr, nullptr,
      x1, nullptr, se1, nullptr, ea4, w1f2, w2f2, c2b1, c2b2, se2, nullptr);
  node_sum_kernel<0><<<NN / 4, 256, 0, stream>>>(se2, start, x2);

  node_proj_kernel<<<GRID_NP, 256, 0, stream>>>(x2, x1, w1p3, fN3, gN3);
  edge_conv_kernel<3><<<GRID_EC, 256, 0, stream>>>(srow, scol, nullptr, nullptr,
      fN3, gN3, se2, se1, nullptr, w1f3, w2f3, c3b1, c3b2, se3, nullptr);
  node_sum_kernel<0><<<NN / 4, 256, 0, stream>>>(se3, start, x3);

  node_proj_kernel<<<GRID_NP, 256, 0, stream>>>(x3, x2, w1p4, fN4, gN4);
  edge_conv_kernel<4><<<GRID_EC, 256, 0, stream>>>(srow, scol, perm, nullptr,
      fN4, gN4, se3, se2, nullptr, w1f4, w2f4, c4b1, c4b2, se1, out_e);
  node_sum_kernel<1><<<NN / 4, 256, 0, stream>>>(se1, start, x4);

  head_kernel<<<NN / 4, 256, 0, stream>>>(x4, mW1, mb1, mW2, mb2, out_x);
}

// Round 10
// 830.604 us; speedup vs baseline: 1.6449x; 1.0410x over previous
//
#include <hip/hip_runtime.h>
#include <cstdint>
#include <cstddef>

// MPNN: 4 edge-conv layers + head MLP.  N=50000, E=800000, F=64.
// Round 13: fuse conv4's node aggregation. Round 12 verified 865us; conv4
// (155us, top dispatch) wrote se1 (102MB) solely for node_sum<1> to re-read
// (102MB). Edges are sorted by srow, so conv4's epilogue now does a segmented
// reduce over each subtile's contiguous node runs (ballot boundary detect +
// masked lane sums + shfl_xor cross-quad reduce) and atomicAdds fp32 partials
// into a zeroed x4 accumulator; tiny finalize applies relu(acc/cnt).
// Removes 204MB of HBM round-trip + one dispatch. conv1-3 untouched.
// (Round 10/11's atomic tile-grab = branded poison after 4 container fails;
// static stride schedule retained.)

#define NN 50000
#define NE 800000

typedef _Float16 f16;
typedef _Float16 f16x8 __attribute__((ext_vector_type(8)));
typedef _Float16 f16x4 __attribute__((ext_vector_type(4)));
typedef float    f32x4 __attribute__((ext_vector_type(4)));

// ---------------------------------------------------------------- sort build
__global__ void count_kernel(const int* __restrict__ eidx, int* __restrict__ cnt) {
  int i = blockIdx.x * 256 + threadIdx.x;
  if (i < NE) atomicAdd(&cnt[eidx[i]], 1);
}

__global__ void scan_a(const int* __restrict__ cnt, int* __restrict__ bsum) {
  __shared__ int sh[256];
  int i = blockIdx.x * 256 + threadIdx.x;
  sh[threadIdx.x] = (i < NN) ? cnt[i] : 0;
  __syncthreads();
  for (int off = 128; off > 0; off >>= 1) {
    if (threadIdx.x < off) sh[threadIdx.x] += sh[threadIdx.x + off];
    __syncthreads();
  }
  if (threadIdx.x == 0) bsum[blockIdx.x] = sh[0];
}

__global__ void scan_b(const int* __restrict__ bsum, int* __restrict__ boff, int nb) {
  __shared__ int sh[256];
  int t = threadIdx.x;
  int v = (t < nb) ? bsum[t] : 0;
  sh[t] = v; __syncthreads();
  for (int off = 1; off < 256; off <<= 1) {
    int x = (t >= off) ? sh[t - off] : 0;
    __syncthreads();
    sh[t] += x;
    __syncthreads();
  }
  if (t < nb) boff[t] = sh[t] - v;   // exclusive
}

__global__ void scan_c(const int* __restrict__ cnt, const int* __restrict__ boff,
                       int* __restrict__ start, int* __restrict__ cursor) {
  __shared__ int sh[256];
  int t = threadIdx.x;
  int i = blockIdx.x * 256 + t;
  int v = (i < NN) ? cnt[i] : 0;
  sh[t] = v; __syncthreads();
  for (int off = 1; off < 256; off <<= 1) {
    int x = (t >= off) ? sh[t - off] : 0;
    __syncthreads();
    sh[t] += x;
    __syncthreads();
  }
  if (i < NN) {
    int ex = boff[blockIdx.x] + sh[t] - v;
    start[i] = ex; cursor[i] = ex;
  }
  if (i == 0) start[NN] = NE;
}

__global__ void scatter_kernel(const int* __restrict__ eidx, const float* __restrict__ ea,
                               int* __restrict__ cursor,
                               int* __restrict__ srow, int* __restrict__ scol,
                               int* __restrict__ perm, f16* __restrict__ ea4) {
  int e = blockIdx.x * 256 + threadIdx.x;
  if (e >= NE) return;
  int r = eidx[e];
  int j = atomicAdd(&cursor[r], 1);
  srow[j] = r;
  scol[j] = eidx[NE + e];
  perm[j] = e;
  f16x4 v;
  v[0] = (f16)ea[3 * (size_t)e];
  v[1] = (f16)ea[3 * (size_t)e + 1];
  v[2] = (f16)ea[3 * (size_t)e + 2];
  v[3] = (f16)0.0f;
  *(f16x4*)&ea4[4 * (size_t)j] = v;
}

// ---------------------------------------------------------------- weight prep
// frag slot (ks,t,lane): for ks >= ident_ks:
//   dst[slot*8+j] = W1[(koff+(ks-ident_ks)*32+(lane>>4)*8+j)*64 + (t*16+(lane&15))]
// for ks < ident_ks: identity block pattern (64x64 I split in 2 ksteps/chunk):
//   v = ((ks&1)*32+(lane>>4)*8+j == t*16+(lane&15)) ? 1 : 0
__global__ void prep_kernel(const float* __restrict__ W1, int kreal1, int ksteps1,
                            int ident_ks, int koff,
                            const float* __restrict__ W2,
                            f16* __restrict__ w1f, f16* __restrict__ w2f) {
  int u = blockIdx.x * 256 + threadIdx.x;
  int total1 = ksteps1 * 256;
  if (u < total1) {
    int slot = u;
    int l = slot & 63, t = (slot >> 6) & 3, ks = slot >> 8;
    int n = t * 16 + (l & 15);
    f16x8 v;
    if (ks < ident_ks) {
#pragma unroll
      for (int j = 0; j < 8; ++j) {
        int lk = (ks & 1) * 32 + ((l >> 4) * 8) + j;
        v[j] = (lk == n) ? (f16)1.0f : (f16)0.0f;
      }
    } else {
      int kb = koff + (ks - ident_ks) * 32 + ((l >> 4) * 8);
#pragma unroll
      for (int j = 0; j < 8; ++j) {
        int k = kb + j;
        v[j] = (f16)((k < kreal1) ? W1[k * 64 + n] : 0.0f);
      }
    }
    *(f16x8*)&w1f[slot * 8] = v;
  } else if (u < total1 + 512) {
    int slot = u - total1;
    int l = slot & 63, t = (slot >> 6) & 3, ks = slot >> 8;
    int n = t * 16 + (l & 15);
    int kb = ks * 32 + ((l >> 4) * 8);
    f16x8 v;
#pragma unroll
    for (int j = 0; j < 8; ++j)
      v[j] = (f16)W2[(kb + j) * 64 + n];
    *(f16x8*)&w2f[slot * 8] = v;
  }
}

// ---------------------------------------------------------------- node proj
// f[n] = [xA[n],xB[n]] @ W1[0:128]; g[n] = same @ W1[128:256]  (raw f16 out)
// w1p holds 8 frag-ksteps: ks0-3 = W1 rows 0-127, ks4-7 = rows 128-255.
__global__ __launch_bounds__(256, 2) void node_proj_kernel(
    const f16* __restrict__ xA, const f16* __restrict__ xB,
    const f16* __restrict__ w1p,
    f16* __restrict__ fN, f16* __restrict__ gN)
{
  __shared__ f16 wps[8 * 2048];
  __shared__ __align__(16) f16 hbuf[4][16][40];
  const int tid  = threadIdx.x;
  const int lane = tid & 63;
  const int wv   = tid >> 6;
  const int quad = lane >> 4;
  const int l15  = lane & 15;

  for (int u = tid; u < 8 * 256; u += 256)
    *(f16x8*)&wps[u * 8] = *(const f16x8*)&w1p[u * 8];
  __syncthreads();

  constexpr int NT = (NN + 31) / 32;   // 1563
  const int stride = gridDim.x * 4;
  for (int tI = blockIdx.x * 4 + wv; tI < NT; tI += stride) {
    const int nb = tI * 32;
    const int m0 = nb + l15, m1 = nb + 16 + l15;
    const size_t n0 = (size_t)(m0 < NN ? m0 : NN - 1);
    const size_t n1 = (size_t)(m1 < NN ? m1 : NN - 1);
    f16x8 a0[4], a1[4];
#pragma unroll
    for (int ks = 0; ks < 4; ++ks) {
      const f16* src = (ks < 2) ? xA : xB;
      const int kk = ks & 1;
      a0[ks] = *(const f16x8*)(src + n0 * 64 + kk * 32 + quad * 8);
      a1[ks] = *(const f16x8*)(src + n1 * 64 + kk * 32 + quad * 8);
    }
    f32x4 af[2][4], ag[2][4];
#pragma unroll
    for (int s = 0; s < 2; ++s)
#pragma unroll
      for (int t = 0; t < 4; ++t) {
        af[s][t] = (f32x4){0.f, 0.f, 0.f, 0.f};
        ag[s][t] = (f32x4){0.f, 0.f, 0.f, 0.f};
      }
#pragma unroll
    for (int ks = 0; ks < 4; ++ks) {
#pragma unroll
      for (int t = 0; t < 4; ++t) {
        f16x8 bf = *(const f16x8*)&wps[((ks * 4 + t) * 64 + lane) * 8];
        f16x8 bg = *(const f16x8*)&wps[(((4 + ks) * 4 + t) * 64 + lane) * 8];
        af[0][t] = __builtin_amdgcn_mfma_f32_16x16x32_f16(a0[ks], bf, af[0][t], 0, 0, 0);
        af[1][t] = __builtin_amdgcn_mfma_f32_16x16x32_f16(a1[ks], bf, af[1][t], 0, 0, 0);
        ag[0][t] = __builtin_amdgcn_mfma_f32_16x16x32_f16(a0[ks], bg, ag[0][t], 0, 0, 0);
        ag[1][t] = __builtin_amdgcn_mfma_f32_16x16x32_f16(a1[ks], bg, ag[1][t], 0, 0, 0);
      }
    }
#pragma unroll
    for (int s = 0; s < 2; ++s) {
      const int row = nb + s * 16 + l15;
      // f: two 32-col transpose passes -> raw f16 row store
      f16x8 oh[2];
#pragma unroll
      for (int h = 0; h < 2; ++h) {
#pragma unroll
        for (int th = 0; th < 2; ++th) {
          const int t = h * 2 + th;
#pragma unroll
          for (int r = 0; r < 4; ++r)
            hbuf[wv][quad * 4 + r][th * 16 + l15] = (f16)af[s][t][r];
        }
        oh[h] = *(const f16x8*)&hbuf[wv][l15][quad * 8];
      }
      if (row < NN) {
        *(f16x8*)&fN[(size_t)row * 64 + quad * 8] = oh[0];
        *(f16x8*)&fN[(size_t)row * 64 + 32 + quad * 8] = oh[1];
      }
      // g
#pragma unroll
      for (int h = 0; h < 2; ++h) {
#pragma unroll
        for (int th = 0; th < 2; ++th) {
          const int t = h * 2 + th;
#pragma unroll
          for (int r = 0; r < 4; ++r)
            hbuf[wv][quad * 4 + r][th * 16 + l15] = (f16)ag[s][t][r];
        }
        oh[h] = *(const f16x8*)&hbuf[wv][l15][quad * 8];
      }
      if (row < NN) {
        *(f16x8*)&gN[(size_t)row * 64 + quad * 8] = oh[0];
        *(f16x8*)&gN[(size_t)row * 64 + 32 + quad * 8] = oh[1];
      }
    }
  }
}

// ---------------------------------------------------------------- node segment sum
// one wave per node: sum raw f16 edge rows over [start[v], start[v+1]) -> relu(mean)
template<int F32OUT>
__global__ void node_sum_kernel(const f16* __restrict__ eout, const int* __restrict__ start,
                                void* __restrict__ xout) {
  int v = blockIdx.x * 4 + (threadIdx.x >> 6);
  int lane = threadIdx.x & 63;
  int g = lane >> 4, c4 = (lane & 15) * 4;
  int s0 = start[v], s1 = start[v + 1];
  f32x4 acc = (f32x4){0.f, 0.f, 0.f, 0.f};
  for (int i = s0 + g; i < s1; i += 4) {
    f16x4 h = *(const f16x4*)&eout[(size_t)i * 64 + c4];
#pragma unroll
    for (int q = 0; q < 4; ++q) acc[q] += (float)h[q];
  }
#pragma unroll
  for (int q = 0; q < 4; ++q) {
    acc[q] += __shfl_xor(acc[q], 16, 64);
    acc[q] += __shfl_xor(acc[q], 32, 64);
  }
  int cv = s1 - s0;
  float inv = 1.0f / (float)(cv > 0 ? cv : 1);
  if (g == 0) {
    if (F32OUT) {
      f32x4 o;
#pragma unroll
      for (int q = 0; q < 4; ++q) o[q] = fmaxf(acc[q] * inv, 0.0f);
      *(f32x4*)&((float*)xout)[(size_t)v * 64 + c4] = o;
    } else {
      f16x4 o;
#pragma unroll
      for (int q = 0; q < 4; ++q) o[q] = (f16)fmaxf(acc[q] * inv, 0.0f);
      *(f16x4*)&((f16*)xout)[(size_t)v * 64 + c4] = o;
    }
  }
}

// ---------------------------------------------------------------- finalize x4
// x4[v] = relu(acc[v] / max(cnt,1)) in place; 4 nodes per 256-thread block.
__global__ void finalize_x_kernel(float* __restrict__ x4, const int* __restrict__ start) {
  int tid = threadIdx.x;
  int v = blockIdx.x * 4 + (tid >> 6);
  int c = tid & 63;
  int cv = start[v + 1] - start[v];
  float inv = 1.0f / (float)(cv > 0 ? cv : 1);
  float val = x4[(size_t)v * 64 + c];
  x4[(size_t)v * 64 + c] = fmaxf(val * inv, 0.0f);
}

// ---------------------------------------------------------------- edge conv
// Sorted order j, static stride schedule. CONV 1-3: eout[j] = RAW f16 edge
// output (relu applied by consumers). CONV==4: NO eout store; instead
// (a) scatters relu fp32 to out_e[perm[j]] and (b) performs a fused segmented
// node-sum: contiguous srow runs within each 16-edge subtile are reduced
// in-register (masked lane sums + shfl_xor cross-quad) and atomicAdd'ed as
// fp32 partials into xacc (zeroed before launch; finalize applies relu/mean).
// CONV 3/4 chunks: f[r] (ident), g[c] (ident), eA, eB; identity ksteps skip
// the two t-tiles whose B-block is all zero (compile-time predicate).
template<int CONV>
__global__ __launch_bounds__(256, 2) void edge_conv_kernel(
    const int* __restrict__ srow, const int* __restrict__ scol,
    const int* __restrict__ perm,
    const float* __restrict__ na,
    const f16* __restrict__ xA, const f16* __restrict__ xB,
    const f16* __restrict__ eA, const f16* __restrict__ eB,
    const f16* __restrict__ ea4,
    const f16* __restrict__ w1f, const f16* __restrict__ w2f,
    const float* __restrict__ b1, const float* __restrict__ b2,
    f16* __restrict__ eout, float* __restrict__ out_e,
    float* __restrict__ xacc)
{
  constexpr int KSTEPS = (CONV == 1) ? 1 : (CONV == 2 ? 7 : 8);

  __shared__ f16 w1s[KSTEPS * 2048];                  // all B-frags, 4KB per ks
  __shared__ __align__(16) f16 hbuf[4][16][40];       // per-wave 32-col xpose buf

  const int tid  = threadIdx.x;
  const int lane = tid & 63;
  const int wv   = tid >> 6;
  const int quad = lane >> 4;
  const int l15  = lane & 15;

  for (int u = tid; u < KSTEPS * 256; u += 256)
    *(f16x8*)&w1s[u * 8] = *(const f16x8*)&w1f[u * 8];

  float bb1[4], bb2[4];
#pragma unroll
  for (int t = 0; t < 4; ++t) { bb1[t] = b1[t * 16 + l15]; bb2[t] = b2[t * 16 + l15]; }

  f16x8 w2r[2][4];
#pragma unroll
  for (int kk = 0; kk < 2; ++kk)
#pragma unroll
    for (int t = 0; t < 4; ++t)
      w2r[kk][t] = *(const f16x8*)&w2f[((kk * 4 + t) * 64 + lane) * 8];

  __syncthreads();   // w1s visible; no further barriers

  constexpr int NTILE = NE / 32;          // wave-tiles of 32 edges
  const int gw = blockIdx.x * 4 + wv;
  const int stride = gridDim.x * 4;

  // ---- shared epilogue: hidden=relu(acc+b1) -> GEMM2 -> stores/aggregation
  auto epilogue = [&](f32x4 (&acc)[2][4], int jb, int rs0, int rs1) {
#pragma unroll
    for (int s = 0; s < 2; ++s) {
      f32x4 a2[4];
#pragma unroll
      for (int t = 0; t < 4; ++t) a2[t] = (f32x4){0.f, 0.f, 0.f, 0.f};
#pragma unroll
      for (int kk = 0; kk < 2; ++kk) {
#pragma unroll
        for (int th = 0; th < 2; ++th) {
          const int t = kk * 2 + th;
#pragma unroll
          for (int r = 0; r < 4; ++r)
            hbuf[wv][quad * 4 + r][th * 16 + l15] = (f16)fmaxf(acc[s][t][r] + bb1[t], 0.0f);
        }
        f16x8 ah = *(const f16x8*)&hbuf[wv][l15][quad * 8];
#pragma unroll
        for (int t = 0; t < 4; ++t)
          a2[t] = __builtin_amdgcn_mfma_f32_16x16x32_f16(ah, w2r[kk][t], a2[t], 0, 0, 0);
      }

      if constexpr (CONV != 4) {
        // raw edge-out f16: two 32-col transpose passes -> coalesced row stores
        const int j = jb + s * 16 + l15;
        f16x8 oh[2];
#pragma unroll
        for (int h = 0; h < 2; ++h) {
#pragma unroll
          for (int th = 0; th < 2; ++th) {
            const int t = h * 2 + th;
#pragma unroll
            for (int r = 0; r < 4; ++r)
              hbuf[wv][quad * 4 + r][th * 16 + l15] = (f16)(a2[t][r] + bb2[t]);
          }
          oh[h] = *(const f16x8*)&hbuf[wv][l15][quad * 8];
        }
        *(f16x8*)&eout[(size_t)j * 64 + quad * 8] = oh[0];
        *(f16x8*)&eout[(size_t)j * 64 + 32 + quad * 8] = oh[1];
      } else {
        // (a) full-precision relu output, scattered to original edge order
#pragma unroll
        for (int r = 0; r < 4; ++r) {
          const int p = perm[jb + s * 16 + quad * 4 + r];
#pragma unroll
          for (int t = 0; t < 4; ++t)
            out_e[(size_t)p * 64 + t * 16 + l15] = fmaxf(a2[t][r] + bb2[t], 0.0f);
        }
        // (b) fused segmented node-sum of RAW e4 (= a2+bb2) over srow runs.
        // Row l15 of this subtile has node id myv (all quads replicate it).
        const int myv = (s == 0) ? rs0 : rs1;
        const int pv  = __shfl(myv, (l15 > 0) ? (l15 - 1) : 0, 64);
        const bool sf = (l15 == 0) || (myv != pv);
        unsigned long long starts = __ballot(sf) & 0xFFFFull;
        while (starts) {
          const int a = __builtin_ctzll(starts);
          starts &= starts - 1;
          const int b = starts ? __builtin_ctzll(starts) : 16;
          const int va = __shfl(myv, a, 64);
          float sm[4];
#pragma unroll
          for (int t = 0; t < 4; ++t) {
            sm[t] = 0.f;
#pragma unroll
            for (int r = 0; r < 4; ++r) {
              const int w = quad * 4 + r;
              sm[t] += (w >= a && w < b) ? (a2[t][r] + bb2[t]) : 0.0f;
            }
          }
#pragma unroll
          for (int t = 0; t < 4; ++t) {
            sm[t] += __shfl_xor(sm[t], 16, 64);
            sm[t] += __shfl_xor(sm[t], 32, 64);
          }
          if (quad == 0) {
#pragma unroll
            for (int t = 0; t < 4; ++t)
              atomicAdd(&xacc[(size_t)va * 64 + t * 16 + l15], sm[t]);
          }
        }
      }
    }
  };

  if constexpr (CONV == 1) {
    for (int jt = gw; jt < NTILE; jt += stride) {
      const int jb = jt * 32;
      const int j0 = jb + l15, j1 = j0 + 16;
      const int r0 = srow[j0], r1 = srow[j1];
      const int c0 = scol[j0], c1 = scol[j1];
      f16x8 a0, a1;
#pragma unroll
      for (int j = 0; j < 8; ++j) { a0[j] = (f16)0.0f; a1[j] = (f16)0.0f; }
      f16x4 q0 = *(const f16x4*)&ea4[4 * (size_t)j0];
      f16x4 q1 = *(const f16x4*)&ea4[4 * (size_t)j1];
      if (quad == 0) {
        a0[0] = (f16)na[r0*3];  a0[1] = (f16)na[r0*3+1];  a0[2] = (f16)na[r0*3+2];
        a0[3] = (f16)na[c0*3];  a0[4] = (f16)na[c0*3+1];  a0[5] = (f16)na[c0*3+2];
        a0[6] = q0[0];          a0[7] = q0[1];
        a1[0] = (f16)na[r1*3];  a1[1] = (f16)na[r1*3+1];  a1[2] = (f16)na[r1*3+2];
        a1[3] = (f16)na[c1*3];  a1[4] = (f16)na[c1*3+1];  a1[5] = (f16)na[c1*3+2];
        a1[6] = q1[0];          a1[7] = q1[1];
      } else if (quad == 1) {
        a0[0] = q0[2];
        a1[0] = q1[2];
      }
      f32x4 acc[2][4];
#pragma unroll
      for (int s = 0; s < 2; ++s)
#pragma unroll
        for (int t = 0; t < 4; ++t) acc[s][t] = (f32x4){0.f, 0.f, 0.f, 0.f};
#pragma unroll
      for (int t = 0; t < 4; ++t) {
        f16x8 b = *(const f16x8*)&w1s[(t * 64 + lane) * 8];
        acc[0][t] = __builtin_amdgcn_mfma_f32_16x16x32_f16(a0, b, acc[0][t], 0, 0, 0);
        acc[1][t] = __builtin_amdgcn_mfma_f32_16x16x32_f16(a1, b, acc[1][t], 0, 0, 0);
      }
      epilogue(acc, jb, r0, r1);
    }
  } else {
    constexpr int NREG = (CONV == 2) ? 3 : 4;
    constexpr int ERCH = 2;   // chunks >= ERCH are e-prev (relu on load)

    int jt = gw;
    int pr0 = 0, pr1 = 0, pc0 = 0, pc1 = 0;     // current tile's indices
    if (jt < NTILE) {
      const int jb = jt * 32;
      pr0 = srow[jb + l15];  pr1 = srow[jb + 16 + l15];
      pc0 = scol[jb + l15];  pc1 = scol[jb + 16 + l15];
    }

    for (; jt < NTILE; jt += stride) {
      const int jb = jt * 32;
      const int j0 = jb + l15, j1 = j0 + 16;

      // prefetch NEXT tile's indices (4 VGPRs; hides idx->gather serial link)
      const int jn = jt + stride;
      int nr0 = 0, nr1 = 0, nc0 = 0, nc1 = 0;
      if (jn < NTILE) {
        const int njb = jn * 32;
        nr0 = srow[njb + l15];  nr1 = srow[njb + 16 + l15];
        nc0 = scol[njb + l15];  nc1 = scol[njb + 16 + l15];
      }

      const int r0 = pr0, r1 = pr1, c0 = pc0, c1 = pc1;
      const f16* p0[NREG]; const f16* p1[NREG];
      if constexpr (CONV == 2) {
        p0[0] = xA + (size_t)r0 * 64;  p1[0] = xA + (size_t)r1 * 64;
        p0[1] = xA + (size_t)c0 * 64;  p1[1] = xA + (size_t)c1 * 64;
        p0[2] = eA + (size_t)j0 * 64;  p1[2] = eA + (size_t)j1 * 64;
      } else {
        p0[0] = xA + (size_t)r0 * 64;  p1[0] = xA + (size_t)r1 * 64;   // f[r]
        p0[1] = xB + (size_t)c0 * 64;  p1[1] = xB + (size_t)c1 * 64;   // g[c]
        p0[2] = eA + (size_t)j0 * 64;  p1[2] = eA + (size_t)j1 * 64;
        p0[3] = eB + (size_t)j0 * 64;  p1[3] = eB + (size_t)j1 * 64;
      }

      f32x4 acc[2][4];
#pragma unroll
      for (int s = 0; s < 2; ++s)
#pragma unroll
        for (int t = 0; t < 4; ++t) acc[s][t] = (f32x4){0.f, 0.f, 0.f, 0.f};

#pragma unroll
      for (int ks = 0; ks < NREG * 2; ++ks) {
        const int c = ks >> 1, kk = ks & 1;
        f16x8 a0 = *(const f16x8*)(p0[c] + kk * 32 + quad * 8);
        f16x8 a1 = *(const f16x8*)(p1[c] + kk * 32 + quad * 8);
        if (c >= ERCH) {            // e-prev stored raw -> relu on load
#pragma unroll
          for (int j = 0; j < 8; ++j) {
            a0[j] = (a0[j] > (f16)0.0f) ? a0[j] : (f16)0.0f;
            a1[j] = (a1[j] > (f16)0.0f) ? a1[j] : (f16)0.0f;
          }
        }
#pragma unroll
        for (int t = 0; t < 4; ++t) {
          // identity ksteps (CONV>=3, ks<4): B-block zero for half the t's
          if constexpr (CONV >= 3) {
            if (ks < 4 && ((ks & 1) ? (t < 2) : (t >= 2))) continue;
          }
          f16x8 b = *(const f16x8*)&w1s[((ks * 4 + t) * 64 + lane) * 8];
          acc[0][t] = __builtin_amdgcn_mfma_f32_16x16x32_f16(a0, b, acc[0][t], 0, 0, 0);
          acc[1][t] = __builtin_amdgcn_mfma_f32_16x16x32_f16(a1, b, acc[1][t], 0, 0, 0);
        }
      }
      if constexpr (CONV == 2) {    // tail ks 6: ea at cols 192..194
        f16x8 a0, a1;
#pragma unroll
        for (int j = 0; j < 8; ++j) { a0[j] = (f16)0.0f; a1[j] = (f16)0.0f; }
        f16x4 q0 = *(const f16x4*)&ea4[4 * (size_t)j0];
        f16x4 q1 = *(const f16x4*)&ea4[4 * (size_t)j1];
        if (quad == 0) {
          a0[0] = q0[0]; a0[1] = q0[1]; a0[2] = q0[2];
          a1[0] = q1[0]; a1[1] = q1[1]; a1[2] = q1[2];
        }
#pragma unroll
        for (int t = 0; t < 4; ++t) {
          f16x8 b = *(const f16x8*)&w1s[((6 * 4 + t) * 64 + lane) * 8];
          acc[0][t] = __builtin_amdgcn_mfma_f32_16x16x32_f16(a0, b, acc[0][t], 0, 0, 0);
          acc[1][t] = __builtin_amdgcn_mfma_f32_16x16x32_f16(a1, b, acc[1][t], 0, 0, 0);
        }
      }

      epilogue(acc, jb, r0, r1);

      pr0 = nr0; pr1 = nr1; pc0 = nc0; pc1 = nc1;
    }
  }
}

// ---------------------------------------------------------------- head MLP
__global__ void head_kernel(const float* __restrict__ x4,
                            const float* __restrict__ W1, const float* __restrict__ b1,
                            const float* __restrict__ W2, const float* __restrict__ b2,
                            float* __restrict__ out) {
  __shared__ float xs[4][64];
  __shared__ float hs[4][64];
  int tid = threadIdx.x;
  int i = tid >> 6, f = tid & 63;
  int nb = blockIdx.x * 4;
  xs[i][f] = x4[(size_t)(nb + i) * 64 + f];
  __syncthreads();
  float h = b1[f];
#pragma unroll
  for (int k = 0; k < 64; ++k) h += xs[i][k] * W1[k * 64 + f];
  hs[i][f] = fmaxf(h, 0.0f);
  __syncthreads();
  if (tid < 12) {
    int ii = tid / 3, j = tid % 3;
    float o = b2[j];
#pragma unroll
    for (int k = 0; k < 64; ++k) o += hs[ii][k] * W2[k * 3 + j];
    out[(size_t)(nb + ii) * 3 + j] = o;
  }
}

// ---------------------------------------------------------------- launch
extern "C" void kernel_launch(void* const* d_in, const int* in_sizes, int n_in,
                              void* d_out, int out_size, void* d_ws, size_t ws_size,
                              hipStream_t stream) {
  const float* na   = (const float*)d_in[0];
  const float* ea   = (const float*)d_in[1];
  const int*   eidx = (const int*)d_in[2];
  const float* c1W1 = (const float*)d_in[3];
  const float* c1b1 = (const float*)d_in[4];
  const float* c1W2 = (const float*)d_in[5];
  const float* c1b2 = (const float*)d_in[6];
  const float* c2W1 = (const float*)d_in[7];
  const float* c2b1 = (const float*)d_in[8];
  const float* c2W2 = (const float*)d_in[9];
  const float* c2b2 = (const float*)d_in[10];
  const float* c3W1 = (const float*)d_in[11];
  const float* c3b1 = (const float*)d_in[12];
  const float* c3W2 = (const float*)d_in[13];
  const float* c3b2 = (const float*)d_in[14];
  const float* c4W1 = (const float*)d_in[15];
  const float* c4b1 = (const float*)d_in[16];
  const float* c4W2 = (const float*)d_in[17];
  const float* c4b2 = (const float*)d_in[18];
  const float* mW1  = (const float*)d_in[19];
  const float* mb1  = (const float*)d_in[20];
  const float* mW2  = (const float*)d_in[21];
  const float* mb2  = (const float*)d_in[22];

  char* ws = (char*)d_ws;
  size_t off = 0;
  auto alloc = [&](size_t b) -> void* {
    void* p = ws + off;
    off += (b + 255) & ~(size_t)255;
    return p;
  };
  int*   cnt    = (int*)alloc((size_t)NN * 4);
  int*   bsum   = (int*)alloc(256 * 4);
  int*   boff   = (int*)alloc(256 * 4);
  int*   start  = (int*)alloc((size_t)(NN + 1) * 4);
  int*   cursor = (int*)alloc((size_t)NN * 4);
  int*   srow   = (int*)alloc((size_t)NE * 4);
  int*   scol   = (int*)alloc((size_t)NE * 4);
  int*   perm   = (int*)alloc((size_t)NE * 4);
  f16*   ea4    = (f16*)alloc((size_t)NE * 4 * 2);
  f16*   x1     = (f16*)alloc((size_t)NN * 64 * 2);
  f16*   x2     = (f16*)alloc((size_t)NN * 64 * 2);
  f16*   x3     = (f16*)alloc((size_t)NN * 64 * 2);
  float* x4     = (float*)alloc((size_t)NN * 64 * 4);
  f16*   fN3    = (f16*)alloc((size_t)NN * 64 * 2);
  f16*   gN3    = (f16*)alloc((size_t)NN * 64 * 2);
  f16*   fN4    = (f16*)alloc((size_t)NN * 64 * 2);
  f16*   gN4    = (f16*)alloc((size_t)NN * 64 * 2);
  f16*   se1    = (f16*)alloc((size_t)NE * 64 * 2);
  f16*   se2    = (f16*)alloc((size_t)NE * 64 * 2);
  f16*   se3    = (f16*)alloc((size_t)NE * 64 * 2);
  f16*   w1f1 = (f16*)alloc((size_t) 1 * 2048 * 2);
  f16*   w1f2 = (f16*)alloc((size_t) 7 * 2048 * 2);
  f16*   w1f3 = (f16*)alloc((size_t) 8 * 2048 * 2);
  f16*   w1f4 = (f16*)alloc((size_t) 8 * 2048 * 2);
  f16*   w1p3 = (f16*)alloc((size_t) 8 * 2048 * 2);
  f16*   w1p4 = (f16*)alloc((size_t) 8 * 2048 * 2);
  f16*   w2f1 = (f16*)alloc((size_t)4096 * 2);
  f16*   w2f2 = (f16*)alloc((size_t)4096 * 2);
  f16*   w2f3 = (f16*)alloc((size_t)4096 * 2);
  f16*   w2f4 = (f16*)alloc((size_t)4096 * 2);

  float* out_x = (float*)d_out;
  float* out_e = out_x + (size_t)NN * 3;

  constexpr int NBS = (NN + 255) / 256;   // 196
  constexpr int GRID_EC = 1024;           // 256-thr blocks; 4 blocks/CU resident
  constexpr int GRID_NP = 391;            // node_proj: ceil(1563/4)

  hipMemsetAsync(cnt, 0, (size_t)NN * 4, stream);
  hipMemsetAsync(x4, 0, (size_t)NN * 64 * 4, stream);   // conv4 atomic accum
  count_kernel<<<NE / 256, 256, 0, stream>>>(eidx, cnt);
  scan_a<<<NBS, 256, 0, stream>>>(cnt, bsum);
  scan_b<<<1, 256, 0, stream>>>(bsum, boff, NBS);
  scan_c<<<NBS, 256, 0, stream>>>(cnt, boff, start, cursor);
  scatter_kernel<<<NE / 256, 256, 0, stream>>>(eidx, ea, cursor, srow, scol, perm, ea4);

  prep_kernel<<< 3, 256, 0, stream>>>(c1W1,   9, 1, 0,   0, c1W2, w1f1, w2f1);
  prep_kernel<<< 9, 256, 0, stream>>>(c2W1, 195, 7, 0,   0, c2W2, w1f2, w2f2);
  prep_kernel<<<10, 256, 0, stream>>>(c3W1, 384, 8, 4, 256, c3W2, w1f3, w2f3);
  prep_kernel<<<10, 256, 0, stream>>>(c4W1, 384, 8, 4, 256, c4W2, w1f4, w2f4);
  prep_kernel<<<10, 256, 0, stream>>>(c3W1, 384, 8, 0,   0, c3W2, w1p3, w2f3);
  prep_kernel<<<10, 256, 0, stream>>>(c4W1, 384, 8, 0,   0, c4W2, w1p4, w2f4);

  edge_conv_kernel<1><<<GRID_EC, 256, 0, stream>>>(srow, scol, nullptr, na,
      nullptr, nullptr, nullptr, nullptr, ea4, w1f1, w2f1, c1b1, c1b2, se1, nullptr,
      nullptr);
  node_sum_kernel<0><<<NN / 4, 256, 0, stream>>>(se1, start, x1);

  edge_conv_kernel<2><<<GRID_EC, 256, 0, stream>>>(srow, scol, nullptr, nullptr,
      x1, nullptr, se1, nullptr, ea4, w1f2, w2f2, c2b1, c2b2, se2, nullptr,
      nullptr);
  node_sum_kernel<0><<<NN / 4, 256, 0, stream>>>(se2, start, x2);

  node_proj_kernel<<<GRID_NP, 256, 0, stream>>>(x2, x1, w1p3, fN3, gN3);
  edge_conv_kernel<3><<<GRID_EC, 256, 0, stream>>>(srow, scol, nullptr, nullptr,
      fN3, gN3, se2, se1, nullptr, w1f3, w2f3, c3b1, c3b2, se3, nullptr,
      nullptr);
  node_sum_kernel<0><<<NN / 4, 256, 0, stream>>>(se3, start, x3);

  node_proj_kernel<<<GRID_NP, 256, 0, stream>>>(x3, x2, w1p4, fN4, gN4);
  edge_conv_kernel<4><<<GRID_EC, 256, 0, stream>>>(srow, scol, perm, nullptr,
      fN4, gN4, se3, se2, nullptr, w1f4, w2f4, c4b1, c4b2, nullptr, out_e,
      x4);
  finalize_x_kernel<<<NN / 4, 256, 0, stream>>>(x4, start);

  head_kernel<<<NN / 4, 256, 0, stream>>>(x4, mW1, mb1, mW2, mb2, out_x);
}